// Round 19
// baseline (454.377 us; speedup 1.0000x reference)
//
#include <hip/hip_runtime.h>

#define N_NODES 8192
#define F_IN 128
#define HID 64
#define HEADS 8
#define REP 512
#define NCLS 32
#define E_EDGES 2048
#define NSYN 4096
#define LMAX 8
#define DM 512
#define DI 1024
#define DSTATE 16
#define DCONV 4
#define DTR 32
#define TOT_EDGES (E_EDGES + N_NODES) /* 10240 */
#define ROWS (E_EDGES * LMAX)         /* 16384 */
#define MC_CAP 6144                   /* >= sum(min(max(cnt,1),8)) */

typedef short bf16x8 __attribute__((ext_vector_type(8)));
typedef float f32x4 __attribute__((ext_vector_type(4)));

// ---------- helpers ----------
__device__ __forceinline__ unsigned mapf(float f) {
  unsigned u = __float_as_uint(f);
  return (u & 0x80000000u) ? ~u : (u | 0x80000000u);
}
__device__ __forceinline__ float unmapf(unsigned u) {
  return __uint_as_float((u & 0x80000000u) ? (u ^ 0x80000000u) : ~u);
}
__device__ __forceinline__ float fsig(float x) {
  return __builtin_amdgcn_rcpf(1.0f + __expf(-x));
}
__device__ __forceinline__ float fsoftplus(float x) {
  return fmaxf(x, 0.0f) + __logf(1.0f + __expf(-fabsf(x)));
}
__device__ __forceinline__ unsigned short f2bf(float f) {
  unsigned u = __float_as_uint(f);
  unsigned r = (u + 0x7FFFu + ((u >> 16) & 1u)) >> 16;
  return (unsigned short)r;
}
__device__ __forceinline__ float bf2f(unsigned short h) {
  return __uint_as_float(((unsigned)h) << 16);
}
__device__ __forceinline__ void split2(float x, unsigned short* hh, unsigned short* ll) {
  unsigned short h = f2bf(x);
  *hh = h;
  *ll = f2bf(x - bf2f(h));
}
__device__ __forceinline__ int lower_bound_dev(const int* __restrict__ arr, int n, int v) {
  int lo = 0, hi = n;
  while (lo < hi) { int mid = (lo + hi) >> 1; if (arr[mid] < v) lo = mid + 1; else hi = mid; }
  return lo;
}
__device__ __forceinline__ int src_of(const int* __restrict__ ei, int i) {
  return i < E_EDGES ? ei[i] : i - E_EDGES;
}
__device__ __forceinline__ int dst_of(const int* __restrict__ ei, int i) {
  return i < E_EDGES ? ei[E_EDGES + i] : i - E_EDGES;
}
__device__ __forceinline__ int clip_cnt(int c) { return c < 1 ? 1 : (c > LMAX ? LMAX : c); }

// ---------- MFMA split-bf16 GEMM, 128x128 tile, 512 threads (8 waves, 2/SIMD) ----------
// band-major remap + 1-deep reg prefetch. grid 1-D: (N/128)*(M/128).
__global__ __launch_bounds__(512) void gemm_mfma2(
    const unsigned short* __restrict__ Ah, const unsigned short* __restrict__ Al,
    const unsigned short* __restrict__ Bth, const unsigned short* __restrict__ Btl,
    float* __restrict__ C, int M, int N, int K,
    const float* __restrict__ bias, int act) {
  __shared__ __align__(16) unsigned short As[2][128][40];
  __shared__ __align__(16) unsigned short Bs[2][128][40];
  const int tid = threadIdx.x;
  const int w = tid >> 6;
  const int lane = tid & 63;
  const int wr = w >> 2, wc = w & 3;  // 2x4 wave grid; wave tile 64x32
  const int mb = M >> 7;
  const int lin = blockIdx.x;
  const int bx = lin / mb;
  const int by = lin % mb;
  const int brow = by * 128;
  const int bcol = bx * 128;
  const int r0 = lane & 15;
  const int kg = lane >> 4;
  const int row0 = tid >> 2, kc0 = tid & 3;
  const size_t a0 = (size_t)(brow + row0) * K + kc0 * 8;
  const size_t b0 = (size_t)(bcol + row0) * K + kc0 * 8;
  f32x4 acc[4][2] = {};
  {
    bf16x8 t0 = *(const bf16x8*)(Ah + a0), t1 = *(const bf16x8*)(Al + a0);
    bf16x8 t2 = *(const bf16x8*)(Bth + b0), t3 = *(const bf16x8*)(Btl + b0);
    *(bf16x8*)(&As[0][row0][kc0 * 8]) = t0;
    *(bf16x8*)(&As[1][row0][kc0 * 8]) = t1;
    *(bf16x8*)(&Bs[0][row0][kc0 * 8]) = t2;
    *(bf16x8*)(&Bs[1][row0][kc0 * 8]) = t3;
  }
  __syncthreads();
  for (int kt = 0; kt < K; kt += 32) {
    const bool more = (kt + 32) < K;
    bf16x8 p0, p1, p2, p3;
    if (more) {
      p0 = *(const bf16x8*)(Ah + a0 + kt + 32);
      p1 = *(const bf16x8*)(Al + a0 + kt + 32);
      p2 = *(const bf16x8*)(Bth + b0 + kt + 32);
      p3 = *(const bf16x8*)(Btl + b0 + kt + 32);
    }
    bf16x8 bhv[2], blv[2];
#pragma unroll
    for (int cf = 0; cf < 2; ++cf) {
      bhv[cf] = *(const bf16x8*)(&Bs[0][wc * 32 + cf * 16 + r0][kg * 8]);
      blv[cf] = *(const bf16x8*)(&Bs[1][wc * 32 + cf * 16 + r0][kg * 8]);
    }
#pragma unroll
    for (int rf = 0; rf < 4; ++rf) {
      bf16x8 ah = *(const bf16x8*)(&As[0][wr * 64 + rf * 16 + r0][kg * 8]);
      bf16x8 al = *(const bf16x8*)(&As[1][wr * 64 + rf * 16 + r0][kg * 8]);
#pragma unroll
      for (int cf = 0; cf < 2; ++cf) {
        acc[rf][cf] = __builtin_amdgcn_mfma_f32_16x16x32_bf16(ah, bhv[cf], acc[rf][cf], 0, 0, 0);
        acc[rf][cf] = __builtin_amdgcn_mfma_f32_16x16x32_bf16(ah, blv[cf], acc[rf][cf], 0, 0, 0);
        acc[rf][cf] = __builtin_amdgcn_mfma_f32_16x16x32_bf16(al, bhv[cf], acc[rf][cf], 0, 0, 0);
      }
    }
    __syncthreads();
    if (more) {
      *(bf16x8*)(&As[0][row0][kc0 * 8]) = p0;
      *(bf16x8*)(&As[1][row0][kc0 * 8]) = p1;
      *(bf16x8*)(&Bs[0][row0][kc0 * 8]) = p2;
      *(bf16x8*)(&Bs[1][row0][kc0 * 8]) = p3;
    }
    __syncthreads();
  }
#pragma unroll
  for (int rf = 0; rf < 4; ++rf)
#pragma unroll
    for (int cf = 0; cf < 2; ++cf) {
      int col = bcol + wc * 32 + cf * 16 + r0;
      float bb = bias ? bias[col] : 0.0f;
#pragma unroll
      for (int j = 0; j < 4; ++j) {
        int row = brow + wr * 64 + rf * 16 + kg * 4 + j;
        float v = acc[rf][cf][j] + bb;
        if (act == 1) v = fmaxf(v, 0.0f);
        C[(size_t)row * N + col] = v;
      }
    }
}

// ---------- split-K version of the 128x128 GEMM: grid (nblk, SK); atomicAdd epilogue ----------
__global__ __launch_bounds__(512) void gemm_mfma2_sk(
    const unsigned short* __restrict__ Ah, const unsigned short* __restrict__ Al,
    const unsigned short* __restrict__ Bth, const unsigned short* __restrict__ Btl,
    float* __restrict__ C, int M, int N, int K) {
  __shared__ __align__(16) unsigned short As[2][128][40];
  __shared__ __align__(16) unsigned short Bs[2][128][40];
  const int tid = threadIdx.x;
  const int w = tid >> 6;
  const int lane = tid & 63;
  const int wr = w >> 2, wc = w & 3;
  const int mb = M >> 7;
  const int lin = blockIdx.x;
  const int bx = lin / mb;
  const int by = lin % mb;
  const int brow = by * 128;
  const int bcol = bx * 128;
  const int kchunk = K / gridDim.y;
  const int k0 = blockIdx.y * kchunk;
  const int r0 = lane & 15;
  const int kg = lane >> 4;
  const int row0 = tid >> 2, kc0 = tid & 3;
  const size_t a0 = (size_t)(brow + row0) * K + k0 + kc0 * 8;
  const size_t b0 = (size_t)(bcol + row0) * K + k0 + kc0 * 8;
  f32x4 acc[4][2] = {};
  {
    bf16x8 t0 = *(const bf16x8*)(Ah + a0), t1 = *(const bf16x8*)(Al + a0);
    bf16x8 t2 = *(const bf16x8*)(Bth + b0), t3 = *(const bf16x8*)(Btl + b0);
    *(bf16x8*)(&As[0][row0][kc0 * 8]) = t0;
    *(bf16x8*)(&As[1][row0][kc0 * 8]) = t1;
    *(bf16x8*)(&Bs[0][row0][kc0 * 8]) = t2;
    *(bf16x8*)(&Bs[1][row0][kc0 * 8]) = t3;
  }
  __syncthreads();
  for (int kt = 0; kt < kchunk; kt += 32) {
    const bool more = (kt + 32) < kchunk;
    bf16x8 p0, p1, p2, p3;
    if (more) {
      p0 = *(const bf16x8*)(Ah + a0 + kt + 32);
      p1 = *(const bf16x8*)(Al + a0 + kt + 32);
      p2 = *(const bf16x8*)(Bth + b0 + kt + 32);
      p3 = *(const bf16x8*)(Btl + b0 + kt + 32);
    }
    bf16x8 bhv[2], blv[2];
#pragma unroll
    for (int cf = 0; cf < 2; ++cf) {
      bhv[cf] = *(const bf16x8*)(&Bs[0][wc * 32 + cf * 16 + r0][kg * 8]);
      blv[cf] = *(const bf16x8*)(&Bs[1][wc * 32 + cf * 16 + r0][kg * 8]);
    }
#pragma unroll
    for (int rf = 0; rf < 4; ++rf) {
      bf16x8 ah = *(const bf16x8*)(&As[0][wr * 64 + rf * 16 + r0][kg * 8]);
      bf16x8 al = *(const bf16x8*)(&As[1][wr * 64 + rf * 16 + r0][kg * 8]);
#pragma unroll
      for (int cf = 0; cf < 2; ++cf) {
        acc[rf][cf] = __builtin_amdgcn_mfma_f32_16x16x32_bf16(ah, bhv[cf], acc[rf][cf], 0, 0, 0);
        acc[rf][cf] = __builtin_amdgcn_mfma_f32_16x16x32_bf16(ah, blv[cf], acc[rf][cf], 0, 0, 0);
        acc[rf][cf] = __builtin_amdgcn_mfma_f32_16x16x32_bf16(al, bhv[cf], acc[rf][cf], 0, 0, 0);
      }
    }
    __syncthreads();
    if (more) {
      *(bf16x8*)(&As[0][row0][kc0 * 8]) = p0;
      *(bf16x8*)(&As[1][row0][kc0 * 8]) = p1;
      *(bf16x8*)(&Bs[0][row0][kc0 * 8]) = p2;
      *(bf16x8*)(&Bs[1][row0][kc0 * 8]) = p3;
    }
    __syncthreads();
  }
#pragma unroll
  for (int rf = 0; rf < 4; ++rf)
#pragma unroll
    for (int cf = 0; cf < 2; ++cf) {
      int col = bcol + wc * 32 + cf * 16 + r0;
#pragma unroll
      for (int j = 0; j < 4; ++j) {
        int row = brow + wr * 64 + rf * 16 + kg * 4 + j;
        atomicAdd(&C[(size_t)row * N + col], acc[rf][cf][j]);
      }
    }
}

// ---------- split-K variant (64x64): partial K range per blockIdx.z, atomicAdd output ----------
__global__ __launch_bounds__(256) void gemm_mfma_sk(
    const unsigned short* __restrict__ Ah, const unsigned short* __restrict__ Al,
    const unsigned short* __restrict__ Bth, const unsigned short* __restrict__ Btl,
    float* __restrict__ C, int M, int N, int K) {
  __shared__ __align__(16) unsigned short As[2][64][40];
  const int tid = threadIdx.x;
  const int w = tid >> 6;
  const int lane = tid & 63;
  const int brow = blockIdx.y * 64;
  const int bcol = blockIdx.x * 64;
  const int srow = tid >> 2;
  const int skc = tid & 3;
  const int r0 = lane & 15;
  const int kg = lane >> 4;
  const int kchunk = K / gridDim.z;
  const int k0 = blockIdx.z * kchunk;
  f32x4 acc[4] = {};
  const size_t aoff = (size_t)(brow + srow) * K;
  const size_t boff = (size_t)(bcol + w * 16 + r0) * K + kg * 8;
  for (int kt = k0; kt < k0 + kchunk; kt += 32) {
    bf16x8 bh = *(const bf16x8*)(Bth + boff + kt);
    bf16x8 bl = *(const bf16x8*)(Btl + boff + kt);
    *(bf16x8*)(&As[0][srow][skc * 8]) = *(const bf16x8*)(Ah + aoff + kt + skc * 8);
    *(bf16x8*)(&As[1][srow][skc * 8]) = *(const bf16x8*)(Al + aoff + kt + skc * 8);
    __syncthreads();
#pragma unroll
    for (int r = 0; r < 4; ++r) {
      bf16x8 ah = *(const bf16x8*)(&As[0][r * 16 + r0][kg * 8]);
      bf16x8 al = *(const bf16x8*)(&As[1][r * 16 + r0][kg * 8]);
      acc[r] = __builtin_amdgcn_mfma_f32_16x16x32_bf16(ah, bh, acc[r], 0, 0, 0);
      acc[r] = __builtin_amdgcn_mfma_f32_16x16x32_bf16(ah, bl, acc[r], 0, 0, 0);
      acc[r] = __builtin_amdgcn_mfma_f32_16x16x32_bf16(al, bh, acc[r], 0, 0, 0);
    }
    __syncthreads();
  }
  const int col = bcol + w * 16 + r0;
#pragma unroll
  for (int r = 0; r < 4; ++r) {
#pragma unroll
    for (int j = 0; j < 4; ++j) {
      int row = brow + r * 16 + kg * 4 + j;
      atomicAdd(&C[(size_t)row * N + col], acc[r][j]);
    }
  }
}

// ---------- thin MFMA GEMM: C(Mx32) = relu(A32)(Mx512) @ Bt(32x512)^T + bias ----------
// APPLY_RELU: applies relu to A on load (used when A holds pre-activation values).
template <int APPLY_RELU>
__global__ __launch_bounds__(256) void gemm_thin32(
    const float* __restrict__ A32,
    const unsigned short* __restrict__ Bth, const unsigned short* __restrict__ Btl,
    float* __restrict__ C, int M, const float* __restrict__ bias) {
  const int tid = threadIdx.x;
  const int w = tid >> 6;
  const int lane = tid & 63;
  const int r0 = lane & 15;
  const int kg = lane >> 4;
  const int rowbase = blockIdx.x * 64 + w * 16;
  f32x4 acc[2] = {};
  const float* arow = A32 + (size_t)(rowbase + r0) * 512 + kg * 8;
  for (int kt = 0; kt < 512; kt += 32) {
    float4 f0 = *(const float4*)(arow + kt);
    float4 f1 = *(const float4*)(arow + kt + 4);
    float v[8] = {f0.x, f0.y, f0.z, f0.w, f1.x, f1.y, f1.z, f1.w};
    bf16x8 ah, al;
#pragma unroll
    for (int j = 0; j < 8; ++j) {
      float vv = APPLY_RELU ? fmaxf(v[j], 0.0f) : v[j];
      unsigned short hh, ll;
      split2(vv, &hh, &ll);
      ah[j] = (short)hh;
      al[j] = (short)ll;
    }
#pragma unroll
    for (int cf = 0; cf < 2; ++cf) {
      bf16x8 bh = *(const bf16x8*)(Bth + (size_t)(cf * 16 + r0) * 512 + kt + kg * 8);
      bf16x8 bl = *(const bf16x8*)(Btl + (size_t)(cf * 16 + r0) * 512 + kt + kg * 8);
      acc[cf] = __builtin_amdgcn_mfma_f32_16x16x32_bf16(ah, bh, acc[cf], 0, 0, 0);
      acc[cf] = __builtin_amdgcn_mfma_f32_16x16x32_bf16(ah, bl, acc[cf], 0, 0, 0);
      acc[cf] = __builtin_amdgcn_mfma_f32_16x16x32_bf16(al, bh, acc[cf], 0, 0, 0);
    }
  }
#pragma unroll
  for (int cf = 0; cf < 2; ++cf) {
    int col = cf * 16 + r0;
    float bb = bias[col];
#pragma unroll
    for (int j = 0; j < 4; ++j) {
      int row = rowbase + kg * 4 + j;
      C[(size_t)row * 32 + col] = acc[cf][j] + bb;
    }
  }
}

// ---------- split / transpose-split / bias-broadcast init ----------
__global__ void split_kernel(const float* __restrict__ x, unsigned short* __restrict__ h,
                             unsigned short* __restrict__ l, int n) {
  int i = blockIdx.x * 256 + threadIdx.x;
  if (i >= n) return;
  split2(x[i], &h[i], &l[i]);
}

__global__ void tsplit_kernel(const float* __restrict__ W, unsigned short* __restrict__ Wth,
                              unsigned short* __restrict__ Wtl, int K, int N) {
  int i = blockIdx.x * 256 + threadIdx.x;
  if (i >= K * N) return;
  int k = i / N, n = i - k * N;
  float v = W[i];
  unsigned short h = f2bf(v);
  Wth[(size_t)n * K + k] = h;
  Wtl[(size_t)n * K + k] = f2bf(v - bf2f(h));
}

__global__ void bias_init_kernel(float* __restrict__ C, const float* __restrict__ bias,
                                 int ncol) {
  int i = blockIdx.x * 256 + threadIdx.x;
  C[i] = bias[i & (ncol - 1)];
}

// ---------- negA table ----------
__global__ void negA_kernel(const float* __restrict__ A_log, float* __restrict__ negA) {
  int i = blockIdx.x * 256 + threadIdx.x;  // DI*DSTATE
  negA[i] = -__expf(A_log[i]);
}

// ---------- tiled f32 GEMM (small shapes) ----------
template <int BM, int BN>
__global__ __launch_bounds__(256) void gemm_t(
    const float* __restrict__ A, int lda,
    const float* __restrict__ B, int ldb,
    float* __restrict__ C, int ldc,
    int M, int N, int K,
    const float* __restrict__ bias, int act) {
  constexpr int RR = BM / 64;
  constexpr int CR = BN / 64;
  __shared__ float As[16][BM + 4];
  __shared__ float Bs[16][BN + 4];
  const int tid = threadIdx.x;
  const int tx = tid & 15;
  const int ty = tid >> 4;
  const int brow = blockIdx.y * BM;
  const int bcol = blockIdx.x * BN;
  float acc[RR][CR][4][4] = {};
  for (int kt = 0; kt < K; kt += 16) {
#pragma unroll
    for (int p = 0; p < RR; ++p) {
      int c = tid + p * 256;
      int row = c >> 2, kc = c & 3;
      int gr = brow + row;
      float4 v = make_float4(0.f, 0.f, 0.f, 0.f);
      if (gr < M) v = *reinterpret_cast<const float4*>(A + (size_t)gr * lda + kt + kc * 4);
      As[kc * 4 + 0][row] = v.x;
      As[kc * 4 + 1][row] = v.y;
      As[kc * 4 + 2][row] = v.z;
      As[kc * 4 + 3][row] = v.w;
    }
#pragma unroll
    for (int p = 0; p < CR; ++p) {
      int c = tid + p * 256;
      int k = c / (BN / 4), c4 = c % (BN / 4);
      int gc = bcol + c4 * 4;
      float4 v = make_float4(0.f, 0.f, 0.f, 0.f);
      if (gc < N) v = *reinterpret_cast<const float4*>(B + (size_t)(kt + k) * ldb + gc);
      *reinterpret_cast<float4*>(&Bs[k][c4 * 4]) = v;
    }
    __syncthreads();
#pragma unroll
    for (int k = 0; k < 16; ++k) {
      float av[RR * 4], bv[CR * 4];
#pragma unroll
      for (int r = 0; r < RR; ++r) {
        float4 t = *reinterpret_cast<const float4*>(&As[k][r * 64 + ty * 4]);
        av[r * 4 + 0] = t.x; av[r * 4 + 1] = t.y; av[r * 4 + 2] = t.z; av[r * 4 + 3] = t.w;
      }
#pragma unroll
      for (int cq = 0; cq < CR; ++cq) {
        float4 t = *reinterpret_cast<const float4*>(&Bs[k][cq * 64 + tx * 4]);
        bv[cq * 4 + 0] = t.x; bv[cq * 4 + 1] = t.y; bv[cq * 4 + 2] = t.z; bv[cq * 4 + 3] = t.w;
      }
#pragma unroll
      for (int r = 0; r < RR; ++r)
#pragma unroll
        for (int cq = 0; cq < CR; ++cq)
#pragma unroll
          for (int i = 0; i < 4; ++i)
#pragma unroll
            for (int j = 0; j < 4; ++j)
              acc[r][cq][i][j] = fmaf(av[r * 4 + i], bv[cq * 4 + j], acc[r][cq][i][j]);
    }
    __syncthreads();
  }
#pragma unroll
  for (int r = 0; r < RR; ++r)
#pragma unroll
    for (int i = 0; i < 4; ++i) {
      int row = brow + r * 64 + ty * 4 + i;
      if (row >= M) continue;
#pragma unroll
      for (int cq = 0; cq < CR; ++cq) {
        int col = bcol + cq * 64 + tx * 4;
        if (col >= N) continue;
        float4 v;
        v.x = acc[r][cq][i][0]; v.y = acc[r][cq][i][1];
        v.z = acc[r][cq][i][2]; v.w = acc[r][cq][i][3];
        if (bias) {
          float4 bb = *reinterpret_cast<const float4*>(bias + col);
          v.x += bb.x; v.y += bb.y; v.z += bb.z; v.w += bb.w;
        }
        if (act == 1) {
          v.x = fmaxf(v.x, 0.f); v.y = fmaxf(v.y, 0.f);
          v.z = fmaxf(v.z, 0.f); v.w = fmaxf(v.w, 0.f);
        }
        *reinterpret_cast<float4*>(C + (size_t)row * ldc + col) = v;
      }
    }
}

// ---------- mamba: pad/scatter + counts + compaction ----------
__global__ void counts_kernel(const int* __restrict__ sidx, int* __restrict__ counts) {
  int e = blockIdx.x * 256 + threadIdx.x;
  if (e >= E_EDGES) return;
  int lo = lower_bound_dev(sidx, NSYN, e);
  int hi = lower_bound_dev(sidx, NSYN, e + 1);
  counts[e] = hi - lo;
}

__global__ void scatter_padded_kernel(const float* __restrict__ synapse,
                                      const int* __restrict__ sidx,
                                      float* __restrict__ padded) {
  int i = blockIdx.x * 256 + threadIdx.x;
  if (i >= NSYN) return;
  int e = sidx[i];
  int lo = lower_bound_dev(sidx, NSYN, e);
  int pos = i - lo;
  if (pos < LMAX) {
#pragma unroll
    for (int c = 0; c < 6; ++c) padded[((size_t)e * LMAX + pos) * 6 + c] = synapse[(size_t)i * 6 + c];
  }
}

// exclusive prefix over clipped counts -> starts_c (one block, 256 threads x 8)
__global__ __launch_bounds__(256) void prefix_kernel(const int* __restrict__ counts,
                                                     int* __restrict__ starts_c) {
  __shared__ int part[256];
  int t = threadIdx.x;
  int loc[8];
  int s = 0;
#pragma unroll
  for (int i = 0; i < 8; ++i) {
    int c = clip_cnt(counts[t * 8 + i]);
    loc[i] = s;
    s += c;
  }
  part[t] = s;
  __syncthreads();
  int mytot = s;
  for (int o = 1; o < 256; o <<= 1) {
    int add = (t >= o) ? part[t - o] : 0;
    __syncthreads();
    part[t] += add;
    __syncthreads();
  }
  int off = part[t] - mytot;
#pragma unroll
  for (int i = 0; i < 8; ++i) starts_c[t * 8 + i] = off + loc[i];
}

// ---------- mamba: compact xc = silu(conv(padded@W_eff)) -> bf16 h/l ----------
__global__ __launch_bounds__(256) void xc_compact_kernel(
    const float* __restrict__ padded,
    const float* __restrict__ W_eff, const float* __restrict__ b_eff,
    const float* __restrict__ conv_w, const float* __restrict__ conv_b,
    const int* __restrict__ counts, const int* __restrict__ starts_c,
    unsigned short* __restrict__ xch, unsigned short* __restrict__ xcl) {
  __shared__ float pads[LMAX * 6];
  int t = threadIdx.x;
  int d = blockIdx.x * 256 + t;
  int e = blockIdx.y;
  if (t < LMAX * 6) pads[t] = padded[(size_t)e * LMAX * 6 + t];
  __syncthreads();
  int cnt = clip_cnt(counts[e]);
  int sc = starts_c[e];
  float wef[6];
#pragma unroll
  for (int c = 0; c < 6; ++c) wef[c] = W_eff[c * 2048 + d];
  float cw0 = conv_w[d * 4 + 0], cw1 = conv_w[d * 4 + 1];
  float cw2 = conv_w[d * 4 + 2], cw3 = conv_w[d * 4 + 3];
  float cb = conv_b[d], be = b_eff[d];
  float x0 = 0.f, x1 = 0.f, x2 = 0.f;
  for (int l = 0; l < cnt; ++l) {
    float xm = be;
#pragma unroll
    for (int c = 0; c < 6; ++c) xm += pads[l * 6 + c] * wef[c];
    float s0 = cb + xm * cw3;
    if (l >= 1) s0 += x2 * cw2;
    if (l >= 2) s0 += x1 * cw1;
    if (l >= 3) s0 += x0 * cw0;
    float v = s0 * fsig(s0);
    size_t o = (size_t)(sc + l) * DI + d;
    split2(v, &xch[o], &xcl[o]);
    x0 = x1; x1 = x2; x2 = xm;
  }
}

// ---------- mamba: scan with LDS-staged xdb rows (broadcast reads) ----------
__global__ __launch_bounds__(256) void mamba_scan_pool_kernel(
    const float* __restrict__ xdb_c, const float* __restrict__ padded,
    const float* __restrict__ W_eff, const float* __restrict__ b_eff,
    const float* __restrict__ W_dt, const float* __restrict__ b_dt,
    const float* __restrict__ negA, const float* __restrict__ Dv,
    const float* __restrict__ conv_w, const float* __restrict__ conv_b,
    const int* __restrict__ counts, const int* __restrict__ starts_c,
    unsigned short* __restrict__ pooledh, unsigned short* __restrict__ pooledl) {
  __shared__ float pads[LMAX * 6];
  __shared__ float rows[LMAX * 64];  // staged xdb rows (2KB)
  int t = threadIdx.x;
  int d = blockIdx.x * 256 + t;
  int e = blockIdx.y;
  int cnt = clip_cnt(counts[e]);
  int sc = starts_c[e];
  if (t < LMAX * 6) pads[t] = padded[(size_t)e * LMAX * 6 + t];
  for (int i = t; i < cnt * 64; i += 256) rows[i] = xdb_c[(size_t)sc * 64 + i];
  float wdt[DTR];
#pragma unroll
  for (int k = 0; k < DTR; ++k) wdt[k] = W_dt[k * DI + d];
  float a[DSTATE];
#pragma unroll
  for (int n = 0; n < DSTATE; ++n) a[n] = negA[d * DSTATE + n];
  float h[DSTATE];
#pragma unroll
  for (int n = 0; n < DSTATE; ++n) h[n] = 0.0f;
  float wef[6], wez[6];
#pragma unroll
  for (int c = 0; c < 6; ++c) {
    wef[c] = W_eff[c * 2048 + d];
    wez[c] = W_eff[c * 2048 + DI + d];
  }
  float cw0 = conv_w[d * 4 + 0], cw1 = conv_w[d * 4 + 1];
  float cw2 = conv_w[d * 4 + 2], cw3 = conv_w[d * 4 + 3];
  float cb = conv_b[d];
  float bdt = b_dt[d], Dd = Dv[d], be = b_eff[d], bez = b_eff[DI + d];
  __syncthreads();
  float x0 = 0.f, x1 = 0.f, x2 = 0.f;
  float ssum = 0.0f;
  for (int l = 0; l < cnt; ++l) {
    float xm = be;
#pragma unroll
    for (int c = 0; c < 6; ++c) xm += pads[l * 6 + c] * wef[c];
    float s0 = cb + xm * cw3;
    if (l >= 1) s0 += x2 * cw2;
    if (l >= 2) s0 += x1 * cw1;
    if (l >= 3) s0 += x0 * cw0;
    float xt = s0 * fsig(s0);
    const float* __restrict__ xrow = &rows[l * 64];
    float acc = bdt;
#pragma unroll
    for (int k = 0; k < DTR; ++k) acc += xrow[k] * wdt[k];
    float dt = fsoftplus(acc);
    float dtx = dt * xt;
    float y = 0.0f;
#pragma unroll
    for (int n = 0; n < DSTATE; ++n) {
      float en = __expf(dt * a[n]);
      h[n] = en * h[n] + dtx * xrow[32 + n];
      y += h[n] * xrow[48 + n];
    }
    y += Dd * xt;
    float z = bez;
#pragma unroll
    for (int c = 0; c < 6; ++c) z += pads[l * 6 + c] * wez[c];
    ssum += y * z * fsig(z);
    x0 = x1; x1 = x2; x2 = xm;
  }
  float pv = ssum / (float)cnt;
  split2(pv, &pooledh[(size_t)e * DI + d], &pooledl[(size_t)e * DI + d]);
}

// ---------- GAT layer 1 ----------
__global__ void esed1_kernel(const float* __restrict__ xw1, const float* __restrict__ as1,
                             const float* __restrict__ ad1, float* __restrict__ es1,
                             float* __restrict__ ed1) {
  int idx = blockIdx.x * 256 + threadIdx.x;  // N_NODES*HEADS
  int n = idx >> 3, h = idx & 7;
  const float* xr = xw1 + (size_t)n * 512 + h * 64;
  const float* sr = as1 + h * 64;
  const float* dr = ad1 + h * 64;
  float es = 0.0f, ed = 0.0f;
#pragma unroll
  for (int c = 0; c < 64; ++c) { float v = xr[c]; es += v * sr[c]; ed += v * dr[c]; }
  es1[idx] = es; ed1[idx] = ed;
}

__global__ void edge1_kernel(const int* __restrict__ ei, const float* __restrict__ es1,
                             const float* __restrict__ ed1, float* __restrict__ e1,
                             unsigned* __restrict__ m1u) {
  int idx = blockIdx.x * 256 + threadIdx.x;
  if (idx >= TOT_EDGES * HEADS) return;
  int i = idx >> 3, h = idx & 7;
  int s = src_of(ei, i), d = dst_of(ei, i);
  float v = es1[s * 8 + h] + ed1[d * 8 + h];
  v = v >= 0.0f ? v : 0.2f * v;
  e1[idx] = v;
  atomicMax(m1u + d * 8 + h, mapf(v));
}

__global__ void ex1_kernel(const int* __restrict__ ei, float* __restrict__ e1,
                           const unsigned* __restrict__ m1u, float* __restrict__ denom1) {
  int idx = blockIdx.x * 256 + threadIdx.x;
  if (idx >= TOT_EDGES * HEADS) return;
  int i = idx >> 3, h = idx & 7;
  int d = dst_of(ei, i);
  float ex = expf(e1[idx] - unmapf(m1u[d * 8 + h]));
  e1[idx] = ex;
  atomicAdd(denom1 + d * 8 + h, ex);
}

// init g1 with the self-loop contribution (replaces memset; self edge id = E_EDGES + n)
__global__ void selfinit1_kernel(const float* __restrict__ e1, const float* __restrict__ denom1,
                                 const float* __restrict__ xw1, float* __restrict__ g1) {
  int idx = blockIdx.x * 256 + threadIdx.x;  // N_NODES*512
  int n = idx >> 9, j = idx & 511;
  int h = j >> 6;
  float alpha = e1[(size_t)(E_EDGES + n) * 8 + h] / denom1[n * 8 + h];
  g1[idx] = alpha * xw1[idx];
}

__global__ __launch_bounds__(256) void agg1_kernel(const int* __restrict__ ei,
                                                   const float* __restrict__ e1,
                                                   const float* __restrict__ denom1,
                                                   const float* __restrict__ xw1,
                                                   float* __restrict__ g1) {
  int i = blockIdx.x;  // real edges only
  int s = ei[i], d = ei[E_EDGES + i];
  for (int j = threadIdx.x; j < 512; j += 256) {
    int h = j >> 6;
    float alpha = e1[i * 8 + h] / denom1[d * 8 + h];
    atomicAdd(g1 + (size_t)d * 512 + j, alpha * xw1[(size_t)s * 512 + j]);
  }
}

__global__ void elu_bias_split_kernel(const float* __restrict__ g1, const float* __restrict__ b1,
                                      unsigned short* __restrict__ g1h,
                                      unsigned short* __restrict__ g1l) {
  int idx = blockIdx.x * 256 + threadIdx.x;  // N_NODES*512
  int j = idx & 511;
  float v = g1[idx] + b1[j];
  v = v > 0.0f ? v : expm1f(v);
  split2(v, &g1h[idx], &g1l[idx]);
}

// ---------- GAT layer 2 ----------
__global__ __launch_bounds__(64) void esed2_kernel(const float* __restrict__ xw2,
                                                   const float* __restrict__ as2,
                                                   const float* __restrict__ ad2,
                                                   float* __restrict__ es2,
                                                   float* __restrict__ ed2) {
  int n = blockIdx.x, t = threadIdx.x;
  float es = 0.0f, ed = 0.0f;
  for (int c = t; c < 512; c += 64) {
    float v = xw2[(size_t)n * 512 + c];
    es += v * as2[c]; ed += v * ad2[c];
  }
#pragma unroll
  for (int o = 32; o > 0; o >>= 1) { es += __shfl_down(es, o, 64); ed += __shfl_down(ed, o, 64); }
  if (t == 0) { es2[n] = es; ed2[n] = ed; }
}

__global__ void edge2_kernel(const int* __restrict__ ei, const float* __restrict__ es2,
                             const float* __restrict__ ed2, float* __restrict__ e2,
                             unsigned* __restrict__ m2u) {
  int i = blockIdx.x * 256 + threadIdx.x;
  if (i >= TOT_EDGES) return;
  int s = src_of(ei, i), d = dst_of(ei, i);
  float v = es2[s] + ed2[d];
  v = v >= 0.0f ? v : 0.2f * v;
  e2[i] = v;
  atomicMax(m2u + d, mapf(v));
}

__global__ void ex2_kernel(const int* __restrict__ ei, float* __restrict__ e2,
                           const unsigned* __restrict__ m2u, float* __restrict__ denom2) {
  int i = blockIdx.x * 256 + threadIdx.x;
  if (i >= TOT_EDGES) return;
  int d = dst_of(ei, i);
  float ex = expf(e2[i] - unmapf(m2u[d]));
  e2[i] = ex;
  atomicAdd(denom2 + d, ex);
}

__global__ void selfinit2_kernel(const float* __restrict__ e2, const float* __restrict__ denom2,
                                 const float* __restrict__ xw2, float* __restrict__ g2) {
  int idx = blockIdx.x * 256 + threadIdx.x;  // N_NODES*512
  int n = idx >> 9;
  float alpha = e2[E_EDGES + n] / denom2[n];
  g2[idx] = alpha * xw2[idx];
}

__global__ __launch_bounds__(256) void agg2_kernel(const int* __restrict__ ei,
                                                   const float* __restrict__ e2,
                                                   const float* __restrict__ denom2,
                                                   const float* __restrict__ xw2,
                                                   float* __restrict__ g2) {
  int i = blockIdx.x;  // real edges only
  int s = ei[i], d = ei[E_EDGES + i];
  float alpha = e2[i] / denom2[d];
  for (int j = threadIdx.x; j < 512; j += 256) {
    atomicAdd(g2 + (size_t)d * 512 + j, alpha * xw2[(size_t)s * 512 + j]);
  }
}

// ---------- scatter segment-max (adds b_lout bias on the fly) ----------
__global__ __launch_bounds__(256) void leftright_kernel(const int* __restrict__ ei,
                                                        const float* __restrict__ xp,
                                                        const float* __restrict__ b_lout,
                                                        unsigned* __restrict__ leftU,
                                                        unsigned* __restrict__ rightU,
                                                        int* __restrict__ flagL,
                                                        int* __restrict__ flagR) {
  int i = blockIdx.x;  // E_EDGES
  int s = ei[i], d = ei[E_EDGES + i];
  if (threadIdx.x == 0) { flagL[s] = 1; flagR[d] = 1; }
  for (int j = threadIdx.x; j < 512; j += 256) {
    unsigned v = mapf(xp[(size_t)i * 512 + j] + b_lout[j]);
    atomicMax(leftU + (size_t)s * 512 + j, v);
    atomicMax(rightU + (size_t)d * 512 + j, v);
  }
}

// ---------- feats = [g2+b2, left, right] -> bf16 h/l ----------
__global__ void concat_split_kernel(const float* __restrict__ g2, const float* __restrict__ b2,
                                    const unsigned* __restrict__ leftU,
                                    const unsigned* __restrict__ rightU,
                                    const int* __restrict__ flagL, const int* __restrict__ flagR,
                                    unsigned short* __restrict__ fh,
                                    unsigned short* __restrict__ fl) {
  int idx = blockIdx.x * 256 + threadIdx.x;  // N_NODES*512
  int n = idx >> 9, j = idx & 511;
  size_t base = (size_t)n * 1536 + j;
  split2(g2[idx] + b2[j], &fh[base], &fl[base]);
  split2(flagL[n] ? unmapf(leftU[idx]) : 0.0f, &fh[base + 512], &fl[base + 512]);
  split2(flagR[n] ? unmapf(rightU[idx]) : 0.0f, &fh[base + 1024], &fl[base + 1024]);
}

// ---------- launch ----------
extern "C" void kernel_launch(void* const* d_in, const int* in_sizes, int n_in,
                              void* d_out, int out_size, void* d_ws, size_t ws_size,
                              hipStream_t stream) {
  const float* synapse = (const float*)d_in[1];
  const float* x_param = (const float*)d_in[2];
  const float* W1 = (const float*)d_in[3];
  const float* as1 = (const float*)d_in[4];
  const float* ad1 = (const float*)d_in[5];
  const float* b1 = (const float*)d_in[6];
  const float* W2 = (const float*)d_in[7];
  const float* as2 = (const float*)d_in[8];
  const float* ad2 = (const float*)d_in[9];
  const float* b2 = (const float*)d_in[10];
  const float* W_in = (const float*)d_in[11];
  const float* b_in = (const float*)d_in[12];
  const float* W_inproj = (const float*)d_in[13];
  const float* conv_w = (const float*)d_in[14];
  const float* conv_b = (const float*)d_in[15];
  const float* W_xproj = (const float*)d_in[16];
  const float* W_dt = (const float*)d_in[17];
  const float* b_dt = (const float*)d_in[18];
  const float* A_log = (const float*)d_in[19];
  const float* Dv = (const float*)d_in[20];
  const float* W_outproj = (const float*)d_in[21];
  const float* W_lout = (const float*)d_in[22];
  const float* b_lout = (const float*)d_in[23];
  const float* Wc1 = (const float*)d_in[24];
  const float* bc1 = (const float*)d_in[25];
  const float* Wc2 = (const float*)d_in[26];
  const float* bc2 = (const float*)d_in[27];
  const int* edge_index = (const int*)d_in[28];
  const int* sidx = (const int*)d_in[29];
  float* out = (float*)d_out;

  // ----- static arena (phase-disjoint aliasing; ~107 MiB peak) -----
  const size_t MB = (size_t)1 << 20;
  const size_t KB = (size_t)1 << 10;
  char* ws = (char*)d_ws;
  unsigned short* xc_ch = (unsigned short*)(ws + 0);      // 12.6MB (mamba only)
  unsigned short* xc_cl = (unsigned short*)(ws + 16 * MB);// 12.6MB
  float* xw1 = (float*)(ws + 0);                          // 16MB
  float* g1 = (float*)(ws + 16 * MB);                     // 16MB
  unsigned short* g1h = (unsigned short*)(ws + 32 * MB);  // 8MB
  unsigned short* g1l = (unsigned short*)(ws + 40 * MB);  // 8MB
  unsigned short* xph = (unsigned short*)(ws + 48 * MB);  // 2MB
  unsigned short* xpl = (unsigned short*)(ws + 50 * MB);  // 2MB
  unsigned short* W1th = (unsigned short*)(ws + 52 * MB);            // 128KB
  unsigned short* W1tl = (unsigned short*)(ws + 52 * MB + 128 * KB); // 128KB
  float* xw2 = (float*)(ws + 48 * MB);                    // 16MB
  unsigned short* W2th = (unsigned short*)(ws + 0);               // 512KB (xw1 dead)
  unsigned short* W2tl = (unsigned short*)(ws + 512 * KB);        // 512KB
  float* g2 = (float*)(ws + 0);                           // 16MB
  unsigned short* featsh = (unsigned short*)(ws + 16 * MB);  // 24MB
  unsigned short* featsl = (unsigned short*)(ws + 40 * MB);  // 24MB
  float* hidden = (float*)(ws + 0);                       // 16MB (g2 dead after concat)
  float* xdb_c = (float*)(ws + 64 * MB);                  // 1.5MB (MC_CAP x 64)
  unsigned short* pooledh = (unsigned short*)(ws + 68 * MB);  // 4MB
  unsigned short* pooledl = (unsigned short*)(ws + 72 * MB);  // 4MB
  unsigned short* Wxth = (unsigned short*)(ws + 76 * MB);            // 128KB
  unsigned short* Wxtl = (unsigned short*)(ws + 76 * MB + 128 * KB); // 128KB
  float* WmixT = (float*)(ws + 77 * MB);                  // 2MB (512x1024 f32)
  unsigned short* Wmixth = (unsigned short*)(ws + 80 * MB);  // 1MB
  unsigned short* Wmixtl = (unsigned short*)(ws + 81 * MB);  // 1MB
  unsigned short* Wlth = (unsigned short*)(ws + 82 * MB);            // 512KB
  unsigned short* Wltl = (unsigned short*)(ws + 82 * MB + 512 * KB); // 512KB
  unsigned short* Woph = (unsigned short*)(ws + 83 * MB);            // 1MB
  unsigned short* Wopl = (unsigned short*)(ws + 84 * MB);            // 1MB
  float* negA = (float*)(ws + 85 * MB);                   // 64KB
  unsigned* leftU = (unsigned*)(ws + 64 * MB);            // 16MB (mamba dead)
  unsigned* rightU = (unsigned*)(ws + 80 * MB);           // 16MB
  float* x_point = (float*)(ws + 96 * MB);                // 4MB
  unsigned short* Wc1th = (unsigned short*)(ws + 96 * MB);             // 1.5MB (x_point dead)
  unsigned short* Wc1tl = (unsigned short*)(ws + 96 * MB + 1536 * KB); // 1.5MB
  unsigned short* Wc2th = (unsigned short*)(ws + 99 * MB);             // 32KB
  unsigned short* Wc2tl = (unsigned short*)(ws + 99 * MB + 64 * KB);   // 32KB
  char* sm = ws + 100 * MB;
  float* es1 = (float*)(sm + 0);                 // 256KB
  float* ed1 = (float*)(sm + 256 * KB);          // 256KB
  float* e1 = (float*)(sm + 512 * KB);           // 320KB
  unsigned* m1u = (unsigned*)(sm + 832 * KB);    // 256KB (one memset with denom1)
  float* denom1 = (float*)(sm + 1088 * KB);      // 256KB
  float* es2 = (float*)(sm + 1344 * KB);         // 32KB
  float* ed2 = (float*)(sm + 1376 * KB);         // 32KB
  float* e2 = (float*)(sm + 1408 * KB);          // 40KB
  unsigned* m2u = (unsigned*)(sm + 1448 * KB);   // 32KB (one memset m2u..flagR)
  float* denom2 = (float*)(sm + 1480 * KB);      // 32KB
  int* flagL = (int*)(sm + 1512 * KB);           // 32KB
  int* flagR = (int*)(sm + 1544 * KB);           // 32KB
  float* padded = (float*)(ws + 106 * MB);                   // 384KB
  int* counts = (int*)(ws + 106 * MB + 384 * KB);            // 8KB
  float* W_eff = (float*)(ws + 106 * MB + 400 * KB);         // 48KB
  float* b_eff = (float*)(ws + 106 * MB + 448 * KB);         // 8KB
  int* starts_c = (int*)(ws + 106 * MB + 456 * KB);          // 8KB

  auto g64 = [&](const float* A, int lda, const float* B, int ldb, float* C, int ldc,
                 int M, int N, int K, const float* bias, int act) {
    dim3 grid((N + 63) / 64, (M + 63) / 64);
    gemm_t<64, 64><<<grid, 256, 0, stream>>>(A, lda, B, ldb, C, ldc, M, N, K, bias, act);
  };
  auto gm2 = [&](const unsigned short* Ah, const unsigned short* Al,
                 const unsigned short* Bth, const unsigned short* Btl, float* C,
                 int M, int N, int K, const float* bias, int act) {
    gemm_mfma2<<<(N / 128) * (M / 128), 512, 0, stream>>>(Ah, Al, Bth, Btl, C, M, N, K, bias,
                                                          act);
  };
  auto gm2sk = [&](const unsigned short* Ah, const unsigned short* Al,
                   const unsigned short* Bth, const unsigned short* Btl, float* C,
                   int M, int N, int K, int SK) {
    gemm_mfma2_sk<<<dim3((N / 128) * (M / 128), SK), 512, 0, stream>>>(Ah, Al, Bth, Btl, C, M,
                                                                       N, K);
  };
  auto tsplit = [&](const float* W, unsigned short* th, unsigned short* tl, int K, int N) {
    tsplit_kernel<<<(K * N + 255) / 256, 256, 0, stream>>>(W, th, tl, K, N);
  };
  auto split = [&](const float* x, unsigned short* h, unsigned short* l, int n) {
    split_kernel<<<(n + 255) / 256, 256, 0, stream>>>(x, h, l, n);
  };

  // ===== PRE: effective weights =====
  g64(W_in, DM, W_inproj, 2 * DI, W_eff, 2 * DI, 6, 2 * DI, DM, nullptr, 0);
  g64(b_in, DM, W_inproj, 2 * DI, b_eff, 2 * DI, 1, 2 * DI, DM, nullptr, 0);
  tsplit(W_lout, Wlth, Wltl, DM, DM);
  split(W_outproj, Woph, Wopl, DI * DM);
  hipMemsetAsync(WmixT, 0, (size_t)DM * DI * 4, stream);
  gemm_mfma_sk<<<dim3(DI / 64, DM / 64, 4), 256, 0, stream>>>(Wlth, Wltl, Woph, Wopl, WmixT,
                                                              DM, DI, DM);
  split(WmixT, Wmixth, Wmixtl, DM * DI);
  negA_kernel<<<(DI * DSTATE) / 256, 256, 0, stream>>>(A_log, negA);

  // ===== Mamba encoder =====
  hipMemsetAsync(padded, 0, (size_t)ROWS * 6 * 4, stream);
  scatter_padded_kernel<<<(NSYN + 255) / 256, 256, 0, stream>>>(synapse, sidx, padded);
  counts_kernel<<<(E_EDGES + 255) / 256, 256, 0, stream>>>(sidx, counts);
  prefix_kernel<<<1, 256, 0, stream>>>(counts, starts_c);
  xc_compact_kernel<<<dim3(DI / 256, E_EDGES), 256, 0, stream>>>(
      padded, W_eff, b_eff, conv_w, conv_b, counts, starts_c, xc_ch, xc_cl);
  tsplit(W_xproj, Wxth, Wxtl, DI, 64);
  hipMemsetAsync(xdb_c, 0, (size_t)MC_CAP * 64 * 4, stream);
  gemm_mfma_sk<<<dim3(1, MC_CAP / 64, 8), 256, 0, stream>>>(xc_ch, xc_cl, Wxth, Wxtl, xdb_c,
                                                            MC_CAP, 64, DI);
  mamba_scan_pool_kernel<<<dim3(DI / 256, E_EDGES), 256, 0, stream>>>(
      xdb_c, padded, W_eff, b_eff, W_dt, b_dt, negA, Dv, conv_w, conv_b, counts, starts_c,
      pooledh, pooledl);
  hipMemsetAsync(x_point, 0, (size_t)E_EDGES * DM * 4, stream);
  gemm_mfma_sk<<<dim3(DM / 64, E_EDGES / 64, 4), 256, 0, stream>>>(pooledh, pooledl, Wmixth,
                                                                   Wmixtl, x_point, E_EDGES,
                                                                   DM, DI);

  // ===== GAT layer 1 =====
  split(x_param, xph, xpl, N_NODES * F_IN);
  tsplit(W1, W1th, W1tl, F_IN, HEADS * HID);
  gm2(xph, xpl, W1th, W1tl, xw1, N_NODES, HEADS * HID, F_IN, nullptr, 0);
  esed1_kernel<<<(N_NODES * HEADS) / 256, 256, 0, stream>>>(xw1, as1, ad1, es1, ed1);
  hipMemsetAsync(m1u, 0, 512 * KB, stream);  // m1u + denom1
  edge1_kernel<<<(TOT_EDGES * HEADS + 255) / 256, 256, 0, stream>>>(edge_index, es1, ed1, e1, m1u);
  ex1_kernel<<<(TOT_EDGES * HEADS + 255) / 256, 256, 0, stream>>>(edge_index, e1, m1u, denom1);
  selfinit1_kernel<<<(N_NODES * 512) / 256, 256, 0, stream>>>(e1, denom1, xw1, g1);
  agg1_kernel<<<E_EDGES, 256, 0, stream>>>(edge_index, e1, denom1, xw1, g1);
  elu_bias_split_kernel<<<(N_NODES * 512) / 256, 256, 0, stream>>>(g1, b1, g1h, g1l);

  // ===== GAT layer 2 (xw2 via split-K=2) =====
  tsplit(W2, W2th, W2tl, HEADS * HID, REP);
  hipMemsetAsync(xw2, 0, (size_t)N_NODES * REP * 4, stream);
  gm2sk(g1h, g1l, W2th, W2tl, xw2, N_NODES, REP, HEADS * HID, 2);
  esed2_kernel<<<N_NODES, 64, 0, stream>>>(xw2, as2, ad2, es2, ed2);
  hipMemsetAsync(m2u, 0, 128 * KB, stream);  // m2u + denom2 + flagL + flagR
  edge2_kernel<<<(TOT_EDGES + 255) / 256, 256, 0, stream>>>(edge_index, es2, ed2, e2, m2u);
  ex2_kernel<<<(TOT_EDGES + 255) / 256, 256, 0, stream>>>(edge_index, e2, m2u, denom2);
  selfinit2_kernel<<<(N_NODES * 512) / 256, 256, 0, stream>>>(e2, denom2, xw2, g2);
  agg2_kernel<<<E_EDGES, 256, 0, stream>>>(edge_index, e2, denom2, xw2, g2);

  // ===== left/right segment max =====
  hipMemsetAsync(leftU, 0, 32 * MB, stream);  // leftU + rightU (contiguous)
  leftright_kernel<<<E_EDGES, 256, 0, stream>>>(edge_index, x_point, b_lout, leftU, rightU,
                                                flagL, flagR);

  // ===== classifier (Wc1 via split-K=2; bias pre-filled, relu deferred to thin32) =====
  concat_split_kernel<<<(N_NODES * 512) / 256, 256, 0, stream>>>(g2, b2, leftU, rightU, flagL,
                                                                 flagR, featsh, featsl);
  tsplit(Wc1, Wc1th, Wc1tl, REP + 2 * DM, 512);
  tsplit(Wc2, Wc2th, Wc2tl, 512, NCLS);
  bias_init_kernel<<<(N_NODES * 512) / 256, 256, 0, stream>>>(hidden, bc1, 512);
  gm2sk(featsh, featsl, Wc1th, Wc1tl, hidden, N_NODES, 512, REP + 2 * DM, 2);
  gemm_thin32<1><<<N_NODES / 64, 256, 0, stream>>>(hidden, Wc2th, Wc2tl, out, N_NODES, bc2);
}

// Round 20
// 418.534 us; speedup vs baseline: 1.0856x; 1.0856x over previous
//
#include <hip/hip_runtime.h>

#define N_NODES 8192
#define F_IN 128
#define HID 64
#define HEADS 8
#define REP 512
#define NCLS 32
#define E_EDGES 2048
#define NSYN 4096
#define LMAX 8
#define DM 512
#define DI 1024
#define DSTATE 16
#define DCONV 4
#define DTR 32
#define TOT_EDGES (E_EDGES + N_NODES) /* 10240 */
#define ROWS (E_EDGES * LMAX)         /* 16384 */
#define MC_CAP 6144                   /* >= sum(min(max(cnt,1),8)) */

typedef short bf16x8 __attribute__((ext_vector_type(8)));
typedef float f32x4 __attribute__((ext_vector_type(4)));

// ---------- helpers ----------
__device__ __forceinline__ unsigned mapf(float f) {
  unsigned u = __float_as_uint(f);
  return (u & 0x80000000u) ? ~u : (u | 0x80000000u);
}
__device__ __forceinline__ float unmapf(unsigned u) {
  return __uint_as_float((u & 0x80000000u) ? (u ^ 0x80000000u) : ~u);
}
__device__ __forceinline__ float fsig(float x) {
  return __builtin_amdgcn_rcpf(1.0f + __expf(-x));
}
__device__ __forceinline__ float fsoftplus(float x) {
  return fmaxf(x, 0.0f) + __logf(1.0f + __expf(-fabsf(x)));
}
__device__ __forceinline__ unsigned short f2bf(float f) {
  unsigned u = __float_as_uint(f);
  unsigned r = (u + 0x7FFFu + ((u >> 16) & 1u)) >> 16;
  return (unsigned short)r;
}
__device__ __forceinline__ float bf2f(unsigned short h) {
  return __uint_as_float(((unsigned)h) << 16);
}
__device__ __forceinline__ void split2(float x, unsigned short* hh, unsigned short* ll) {
  unsigned short h = f2bf(x);
  *hh = h;
  *ll = f2bf(x - bf2f(h));
}
__device__ __forceinline__ int lower_bound_dev(const int* __restrict__ arr, int n, int v) {
  int lo = 0, hi = n;
  while (lo < hi) { int mid = (lo + hi) >> 1; if (arr[mid] < v) lo = mid + 1; else hi = mid; }
  return lo;
}
__device__ __forceinline__ int src_of(const int* __restrict__ ei, int i) {
  return i < E_EDGES ? ei[i] : i - E_EDGES;
}
__device__ __forceinline__ int dst_of(const int* __restrict__ ei, int i) {
  return i < E_EDGES ? ei[E_EDGES + i] : i - E_EDGES;
}
__device__ __forceinline__ int clip_cnt(int c) { return c < 1 ? 1 : (c > LMAX ? LMAX : c); }

// ---------- MFMA split-bf16 GEMM, 128x128 tile, 512 threads (8 waves, 2/SIMD) ----------
// band-major remap + 1-deep reg prefetch. grid 1-D: (N/128)*(M/128).
__global__ __launch_bounds__(512) void gemm_mfma2(
    const unsigned short* __restrict__ Ah, const unsigned short* __restrict__ Al,
    const unsigned short* __restrict__ Bth, const unsigned short* __restrict__ Btl,
    float* __restrict__ C, int M, int N, int K,
    const float* __restrict__ bias, int act) {
  __shared__ __align__(16) unsigned short As[2][128][40];
  __shared__ __align__(16) unsigned short Bs[2][128][40];
  const int tid = threadIdx.x;
  const int w = tid >> 6;
  const int lane = tid & 63;
  const int wr = w >> 2, wc = w & 3;  // 2x4 wave grid; wave tile 64x32
  const int mb = M >> 7;
  const int lin = blockIdx.x;
  const int bx = lin / mb;
  const int by = lin % mb;
  const int brow = by * 128;
  const int bcol = bx * 128;
  const int r0 = lane & 15;
  const int kg = lane >> 4;
  const int row0 = tid >> 2, kc0 = tid & 3;
  const size_t a0 = (size_t)(brow + row0) * K + kc0 * 8;
  const size_t b0 = (size_t)(bcol + row0) * K + kc0 * 8;
  f32x4 acc[4][2] = {};
  {
    bf16x8 t0 = *(const bf16x8*)(Ah + a0), t1 = *(const bf16x8*)(Al + a0);
    bf16x8 t2 = *(const bf16x8*)(Bth + b0), t3 = *(const bf16x8*)(Btl + b0);
    *(bf16x8*)(&As[0][row0][kc0 * 8]) = t0;
    *(bf16x8*)(&As[1][row0][kc0 * 8]) = t1;
    *(bf16x8*)(&Bs[0][row0][kc0 * 8]) = t2;
    *(bf16x8*)(&Bs[1][row0][kc0 * 8]) = t3;
  }
  __syncthreads();
  for (int kt = 0; kt < K; kt += 32) {
    const bool more = (kt + 32) < K;
    bf16x8 p0, p1, p2, p3;
    if (more) {
      p0 = *(const bf16x8*)(Ah + a0 + kt + 32);
      p1 = *(const bf16x8*)(Al + a0 + kt + 32);
      p2 = *(const bf16x8*)(Bth + b0 + kt + 32);
      p3 = *(const bf16x8*)(Btl + b0 + kt + 32);
    }
    bf16x8 bhv[2], blv[2];
#pragma unroll
    for (int cf = 0; cf < 2; ++cf) {
      bhv[cf] = *(const bf16x8*)(&Bs[0][wc * 32 + cf * 16 + r0][kg * 8]);
      blv[cf] = *(const bf16x8*)(&Bs[1][wc * 32 + cf * 16 + r0][kg * 8]);
    }
#pragma unroll
    for (int rf = 0; rf < 4; ++rf) {
      bf16x8 ah = *(const bf16x8*)(&As[0][wr * 64 + rf * 16 + r0][kg * 8]);
      bf16x8 al = *(const bf16x8*)(&As[1][wr * 64 + rf * 16 + r0][kg * 8]);
#pragma unroll
      for (int cf = 0; cf < 2; ++cf) {
        acc[rf][cf] = __builtin_amdgcn_mfma_f32_16x16x32_bf16(ah, bhv[cf], acc[rf][cf], 0, 0, 0);
        acc[rf][cf] = __builtin_amdgcn_mfma_f32_16x16x32_bf16(ah, blv[cf], acc[rf][cf], 0, 0, 0);
        acc[rf][cf] = __builtin_amdgcn_mfma_f32_16x16x32_bf16(al, bhv[cf], acc[rf][cf], 0, 0, 0);
      }
    }
    __syncthreads();
    if (more) {
      *(bf16x8*)(&As[0][row0][kc0 * 8]) = p0;
      *(bf16x8*)(&As[1][row0][kc0 * 8]) = p1;
      *(bf16x8*)(&Bs[0][row0][kc0 * 8]) = p2;
      *(bf16x8*)(&Bs[1][row0][kc0 * 8]) = p3;
    }
    __syncthreads();
  }
#pragma unroll
  for (int rf = 0; rf < 4; ++rf)
#pragma unroll
    for (int cf = 0; cf < 2; ++cf) {
      int col = bcol + wc * 32 + cf * 16 + r0;
      float bb = bias ? bias[col] : 0.0f;
#pragma unroll
      for (int j = 0; j < 4; ++j) {
        int row = brow + wr * 64 + rf * 16 + kg * 4 + j;
        float v = acc[rf][cf][j] + bb;
        if (act == 1) v = fmaxf(v, 0.0f);
        C[(size_t)row * N + col] = v;
      }
    }
}

// ---------- split-K variant (64x64): partial K range per blockIdx.z, atomicAdd output ----------
__global__ __launch_bounds__(256) void gemm_mfma_sk(
    const unsigned short* __restrict__ Ah, const unsigned short* __restrict__ Al,
    const unsigned short* __restrict__ Bth, const unsigned short* __restrict__ Btl,
    float* __restrict__ C, int M, int N, int K) {
  __shared__ __align__(16) unsigned short As[2][64][40];
  const int tid = threadIdx.x;
  const int w = tid >> 6;
  const int lane = tid & 63;
  const int brow = blockIdx.y * 64;
  const int bcol = blockIdx.x * 64;
  const int srow = tid >> 2;
  const int skc = tid & 3;
  const int r0 = lane & 15;
  const int kg = lane >> 4;
  const int kchunk = K / gridDim.z;
  const int k0 = blockIdx.z * kchunk;
  f32x4 acc[4] = {};
  const size_t aoff = (size_t)(brow + srow) * K;
  const size_t boff = (size_t)(bcol + w * 16 + r0) * K + kg * 8;
  for (int kt = k0; kt < k0 + kchunk; kt += 32) {
    bf16x8 bh = *(const bf16x8*)(Bth + boff + kt);
    bf16x8 bl = *(const bf16x8*)(Btl + boff + kt);
    *(bf16x8*)(&As[0][srow][skc * 8]) = *(const bf16x8*)(Ah + aoff + kt + skc * 8);
    *(bf16x8*)(&As[1][srow][skc * 8]) = *(const bf16x8*)(Al + aoff + kt + skc * 8);
    __syncthreads();
#pragma unroll
    for (int r = 0; r < 4; ++r) {
      bf16x8 ah = *(const bf16x8*)(&As[0][r * 16 + r0][kg * 8]);
      bf16x8 al = *(const bf16x8*)(&As[1][r * 16 + r0][kg * 8]);
      acc[r] = __builtin_amdgcn_mfma_f32_16x16x32_bf16(ah, bh, acc[r], 0, 0, 0);
      acc[r] = __builtin_amdgcn_mfma_f32_16x16x32_bf16(ah, bl, acc[r], 0, 0, 0);
      acc[r] = __builtin_amdgcn_mfma_f32_16x16x32_bf16(al, bh, acc[r], 0, 0, 0);
    }
    __syncthreads();
  }
  const int col = bcol + w * 16 + r0;
#pragma unroll
  for (int r = 0; r < 4; ++r) {
#pragma unroll
    for (int j = 0; j < 4; ++j) {
      int row = brow + r * 16 + kg * 4 + j;
      atomicAdd(&C[(size_t)row * N + col], acc[r][j]);
    }
  }
}

// ---------- thin MFMA GEMM: C(Mx32) = relu(A32)(Mx512) @ Bt(32x512)^T + bias ----------
template <int APPLY_RELU>
__global__ __launch_bounds__(256) void gemm_thin32(
    const float* __restrict__ A32,
    const unsigned short* __restrict__ Bth, const unsigned short* __restrict__ Btl,
    float* __restrict__ C, int M, const float* __restrict__ bias) {
  const int tid = threadIdx.x;
  const int w = tid >> 6;
  const int lane = tid & 63;
  const int r0 = lane & 15;
  const int kg = lane >> 4;
  const int rowbase = blockIdx.x * 64 + w * 16;
  f32x4 acc[2] = {};
  const float* arow = A32 + (size_t)(rowbase + r0) * 512 + kg * 8;
  for (int kt = 0; kt < 512; kt += 32) {
    float4 f0 = *(const float4*)(arow + kt);
    float4 f1 = *(const float4*)(arow + kt + 4);
    float v[8] = {f0.x, f0.y, f0.z, f0.w, f1.x, f1.y, f1.z, f1.w};
    bf16x8 ah, al;
#pragma unroll
    for (int j = 0; j < 8; ++j) {
      float vv = APPLY_RELU ? fmaxf(v[j], 0.0f) : v[j];
      unsigned short hh, ll;
      split2(vv, &hh, &ll);
      ah[j] = (short)hh;
      al[j] = (short)ll;
    }
#pragma unroll
    for (int cf = 0; cf < 2; ++cf) {
      bf16x8 bh = *(const bf16x8*)(Bth + (size_t)(cf * 16 + r0) * 512 + kt + kg * 8);
      bf16x8 bl = *(const bf16x8*)(Btl + (size_t)(cf * 16 + r0) * 512 + kt + kg * 8);
      acc[cf] = __builtin_amdgcn_mfma_f32_16x16x32_bf16(ah, bh, acc[cf], 0, 0, 0);
      acc[cf] = __builtin_amdgcn_mfma_f32_16x16x32_bf16(ah, bl, acc[cf], 0, 0, 0);
      acc[cf] = __builtin_amdgcn_mfma_f32_16x16x32_bf16(al, bh, acc[cf], 0, 0, 0);
    }
  }
#pragma unroll
  for (int cf = 0; cf < 2; ++cf) {
    int col = cf * 16 + r0;
    float bb = bias[col];
#pragma unroll
    for (int j = 0; j < 4; ++j) {
      int row = rowbase + kg * 4 + j;
      C[(size_t)row * 32 + col] = acc[cf][j] + bb;
    }
  }
}

// ---------- split / transpose-split ----------
__global__ void split_kernel(const float* __restrict__ x, unsigned short* __restrict__ h,
                             unsigned short* __restrict__ l, int n) {
  int i = blockIdx.x * 256 + threadIdx.x;
  if (i >= n) return;
  split2(x[i], &h[i], &l[i]);
}

__global__ void tsplit_kernel(const float* __restrict__ W, unsigned short* __restrict__ Wth,
                              unsigned short* __restrict__ Wtl, int K, int N) {
  int i = blockIdx.x * 256 + threadIdx.x;
  if (i >= K * N) return;
  int k = i / N, n = i - k * N;
  float v = W[i];
  unsigned short h = f2bf(v);
  Wth[(size_t)n * K + k] = h;
  Wtl[(size_t)n * K + k] = f2bf(v - bf2f(h));
}

// ---------- negA table ----------
__global__ void negA_kernel(const float* __restrict__ A_log, float* __restrict__ negA) {
  int i = blockIdx.x * 256 + threadIdx.x;  // DI*DSTATE
  negA[i] = -__expf(A_log[i]);
}

// ---------- tiled f32 GEMM (small shapes) ----------
template <int BM, int BN>
__global__ __launch_bounds__(256) void gemm_t(
    const float* __restrict__ A, int lda,
    const float* __restrict__ B, int ldb,
    float* __restrict__ C, int ldc,
    int M, int N, int K,
    const float* __restrict__ bias, int act) {
  constexpr int RR = BM / 64;
  constexpr int CR = BN / 64;
  __shared__ float As[16][BM + 4];
  __shared__ float Bs[16][BN + 4];
  const int tid = threadIdx.x;
  const int tx = tid & 15;
  const int ty = tid >> 4;
  const int brow = blockIdx.y * BM;
  const int bcol = blockIdx.x * BN;
  float acc[RR][CR][4][4] = {};
  for (int kt = 0; kt < K; kt += 16) {
#pragma unroll
    for (int p = 0; p < RR; ++p) {
      int c = tid + p * 256;
      int row = c >> 2, kc = c & 3;
      int gr = brow + row;
      float4 v = make_float4(0.f, 0.f, 0.f, 0.f);
      if (gr < M) v = *reinterpret_cast<const float4*>(A + (size_t)gr * lda + kt + kc * 4);
      As[kc * 4 + 0][row] = v.x;
      As[kc * 4 + 1][row] = v.y;
      As[kc * 4 + 2][row] = v.z;
      As[kc * 4 + 3][row] = v.w;
    }
#pragma unroll
    for (int p = 0; p < CR; ++p) {
      int c = tid + p * 256;
      int k = c / (BN / 4), c4 = c % (BN / 4);
      int gc = bcol + c4 * 4;
      float4 v = make_float4(0.f, 0.f, 0.f, 0.f);
      if (gc < N) v = *reinterpret_cast<const float4*>(B + (size_t)(kt + k) * ldb + gc);
      *reinterpret_cast<float4*>(&Bs[k][c4 * 4]) = v;
    }
    __syncthreads();
#pragma unroll
    for (int k = 0; k < 16; ++k) {
      float av[RR * 4], bv[CR * 4];
#pragma unroll
      for (int r = 0; r < RR; ++r) {
        float4 t = *reinterpret_cast<const float4*>(&As[k][r * 64 + ty * 4]);
        av[r * 4 + 0] = t.x; av[r * 4 + 1] = t.y; av[r * 4 + 2] = t.z; av[r * 4 + 3] = t.w;
      }
#pragma unroll
      for (int cq = 0; cq < CR; ++cq) {
        float4 t = *reinterpret_cast<const float4*>(&Bs[k][cq * 64 + tx * 4]);
        bv[cq * 4 + 0] = t.x; bv[cq * 4 + 1] = t.y; bv[cq * 4 + 2] = t.z; bv[cq * 4 + 3] = t.w;
      }
#pragma unroll
      for (int r = 0; r < RR; ++r)
#pragma unroll
        for (int cq = 0; cq < CR; ++cq)
#pragma unroll
          for (int i = 0; i < 4; ++i)
#pragma unroll
            for (int j = 0; j < 4; ++j)
              acc[r][cq][i][j] = fmaf(av[r * 4 + i], bv[cq * 4 + j], acc[r][cq][i][j]);
    }
    __syncthreads();
  }
#pragma unroll
  for (int r = 0; r < RR; ++r)
#pragma unroll
    for (int i = 0; i < 4; ++i) {
      int row = brow + r * 64 + ty * 4 + i;
      if (row >= M) continue;
#pragma unroll
      for (int cq = 0; cq < CR; ++cq) {
        int col = bcol + cq * 64 + tx * 4;
        if (col >= N) continue;
        float4 v;
        v.x = acc[r][cq][i][0]; v.y = acc[r][cq][i][1];
        v.z = acc[r][cq][i][2]; v.w = acc[r][cq][i][3];
        if (bias) {
          float4 bb = *reinterpret_cast<const float4*>(bias + col);
          v.x += bb.x; v.y += bb.y; v.z += bb.z; v.w += bb.w;
        }
        if (act == 1) {
          v.x = fmaxf(v.x, 0.f); v.y = fmaxf(v.y, 0.f);
          v.z = fmaxf(v.z, 0.f); v.w = fmaxf(v.w, 0.f);
        }
        *reinterpret_cast<float4*>(C + (size_t)row * ldc + col) = v;
      }
    }
}

// ---------- mamba: pad/scatter + counts + compaction ----------
__global__ void counts_kernel(const int* __restrict__ sidx, int* __restrict__ counts) {
  int e = blockIdx.x * 256 + threadIdx.x;
  if (e >= E_EDGES) return;
  int lo = lower_bound_dev(sidx, NSYN, e);
  int hi = lower_bound_dev(sidx, NSYN, e + 1);
  counts[e] = hi - lo;
}

__global__ void scatter_padded_kernel(const float* __restrict__ synapse,
                                      const int* __restrict__ sidx,
                                      float* __restrict__ padded) {
  int i = blockIdx.x * 256 + threadIdx.x;
  if (i >= NSYN) return;
  int e = sidx[i];
  int lo = lower_bound_dev(sidx, NSYN, e);
  int pos = i - lo;
  if (pos < LMAX) {
#pragma unroll
    for (int c = 0; c < 6; ++c) padded[((size_t)e * LMAX + pos) * 6 + c] = synapse[(size_t)i * 6 + c];
  }
}

// exclusive prefix over clipped counts -> starts_c (one block, 256 threads x 8)
__global__ __launch_bounds__(256) void prefix_kernel(const int* __restrict__ counts,
                                                     int* __restrict__ starts_c) {
  __shared__ int part[256];
  int t = threadIdx.x;
  int loc[8];
  int s = 0;
#pragma unroll
  for (int i = 0; i < 8; ++i) {
    int c = clip_cnt(counts[t * 8 + i]);
    loc[i] = s;
    s += c;
  }
  part[t] = s;
  __syncthreads();
  int mytot = s;
  for (int o = 1; o < 256; o <<= 1) {
    int add = (t >= o) ? part[t - o] : 0;
    __syncthreads();
    part[t] += add;
    __syncthreads();
  }
  int off = part[t] - mytot;
#pragma unroll
  for (int i = 0; i < 8; ++i) starts_c[t * 8 + i] = off + loc[i];
}

// ---------- mamba: compact xc = silu(conv(padded@W_eff)) -> bf16 h/l ----------
__global__ __launch_bounds__(256) void xc_compact_kernel(
    const float* __restrict__ padded,
    const float* __restrict__ W_eff, const float* __restrict__ b_eff,
    const float* __restrict__ conv_w, const float* __restrict__ conv_b,
    const int* __restrict__ counts, const int* __restrict__ starts_c,
    unsigned short* __restrict__ xch, unsigned short* __restrict__ xcl) {
  __shared__ float pads[LMAX * 6];
  int t = threadIdx.x;
  int d = blockIdx.x * 256 + t;
  int e = blockIdx.y;
  if (t < LMAX * 6) pads[t] = padded[(size_t)e * LMAX * 6 + t];
  __syncthreads();
  int cnt = clip_cnt(counts[e]);
  int sc = starts_c[e];
  float wef[6];
#pragma unroll
  for (int c = 0; c < 6; ++c) wef[c] = W_eff[c * 2048 + d];
  float cw0 = conv_w[d * 4 + 0], cw1 = conv_w[d * 4 + 1];
  float cw2 = conv_w[d * 4 + 2], cw3 = conv_w[d * 4 + 3];
  float cb = conv_b[d], be = b_eff[d];
  float x0 = 0.f, x1 = 0.f, x2 = 0.f;
  for (int l = 0; l < cnt; ++l) {
    float xm = be;
#pragma unroll
    for (int c = 0; c < 6; ++c) xm += pads[l * 6 + c] * wef[c];
    float s0 = cb + xm * cw3;
    if (l >= 1) s0 += x2 * cw2;
    if (l >= 2) s0 += x1 * cw1;
    if (l >= 3) s0 += x0 * cw0;
    float v = s0 * fsig(s0);
    size_t o = (size_t)(sc + l) * DI + d;
    split2(v, &xch[o], &xcl[o]);
    x0 = x1; x1 = x2; x2 = xm;
  }
}

// ---------- mamba: scan with LDS-staged xdb rows (broadcast reads) ----------
__global__ __launch_bounds__(256) void mamba_scan_pool_kernel(
    const float* __restrict__ xdb_c, const float* __restrict__ padded,
    const float* __restrict__ W_eff, const float* __restrict__ b_eff,
    const float* __restrict__ W_dt, const float* __restrict__ b_dt,
    const float* __restrict__ negA, const float* __restrict__ Dv,
    const float* __restrict__ conv_w, const float* __restrict__ conv_b,
    const int* __restrict__ counts, const int* __restrict__ starts_c,
    unsigned short* __restrict__ pooledh, unsigned short* __restrict__ pooledl) {
  __shared__ float pads[LMAX * 6];
  __shared__ float rows[LMAX * 64];  // staged xdb rows (2KB)
  int t = threadIdx.x;
  int d = blockIdx.x * 256 + t;
  int e = blockIdx.y;
  int cnt = clip_cnt(counts[e]);
  int sc = starts_c[e];
  if (t < LMAX * 6) pads[t] = padded[(size_t)e * LMAX * 6 + t];
  for (int i = t; i < cnt * 64; i += 256) rows[i] = xdb_c[(size_t)sc * 64 + i];
  float wdt[DTR];
#pragma unroll
  for (int k = 0; k < DTR; ++k) wdt[k] = W_dt[k * DI + d];
  float a[DSTATE];
#pragma unroll
  for (int n = 0; n < DSTATE; ++n) a[n] = negA[d * DSTATE + n];
  float h[DSTATE];
#pragma unroll
  for (int n = 0; n < DSTATE; ++n) h[n] = 0.0f;
  float wef[6], wez[6];
#pragma unroll
  for (int c = 0; c < 6; ++c) {
    wef[c] = W_eff[c * 2048 + d];
    wez[c] = W_eff[c * 2048 + DI + d];
  }
  float cw0 = conv_w[d * 4 + 0], cw1 = conv_w[d * 4 + 1];
  float cw2 = conv_w[d * 4 + 2], cw3 = conv_w[d * 4 + 3];
  float cb = conv_b[d];
  float bdt = b_dt[d], Dd = Dv[d], be = b_eff[d], bez = b_eff[DI + d];
  __syncthreads();
  float x0 = 0.f, x1 = 0.f, x2 = 0.f;
  float ssum = 0.0f;
  for (int l = 0; l < cnt; ++l) {
    float xm = be;
#pragma unroll
    for (int c = 0; c < 6; ++c) xm += pads[l * 6 + c] * wef[c];
    float s0 = cb + xm * cw3;
    if (l >= 1) s0 += x2 * cw2;
    if (l >= 2) s0 += x1 * cw1;
    if (l >= 3) s0 += x0 * cw0;
    float xt = s0 * fsig(s0);
    const float* __restrict__ xrow = &rows[l * 64];
    float acc = bdt;
#pragma unroll
    for (int k = 0; k < DTR; ++k) acc += xrow[k] * wdt[k];
    float dt = fsoftplus(acc);
    float dtx = dt * xt;
    float y = 0.0f;
#pragma unroll
    for (int n = 0; n < DSTATE; ++n) {
      float en = __expf(dt * a[n]);
      h[n] = en * h[n] + dtx * xrow[32 + n];
      y += h[n] * xrow[48 + n];
    }
    y += Dd * xt;
    float z = bez;
#pragma unroll
    for (int c = 0; c < 6; ++c) z += pads[l * 6 + c] * wez[c];
    ssum += y * z * fsig(z);
    x0 = x1; x1 = x2; x2 = xm;
  }
  float pv = ssum / (float)cnt;
  split2(pv, &pooledh[(size_t)e * DI + d], &pooledl[(size_t)e * DI + d]);
}

// ---------- GAT layer 1 ----------
__global__ void esed1_kernel(const float* __restrict__ xw1, const float* __restrict__ as1,
                             const float* __restrict__ ad1, float* __restrict__ es1,
                             float* __restrict__ ed1) {
  int idx = blockIdx.x * 256 + threadIdx.x;  // N_NODES*HEADS
  int n = idx >> 3, h = idx & 7;
  const float* xr = xw1 + (size_t)n * 512 + h * 64;
  const float* sr = as1 + h * 64;
  const float* dr = ad1 + h * 64;
  float es = 0.0f, ed = 0.0f;
#pragma unroll
  for (int c = 0; c < 64; ++c) { float v = xr[c]; es += v * sr[c]; ed += v * dr[c]; }
  es1[idx] = es; ed1[idx] = ed;
}

__global__ void edge1_kernel(const int* __restrict__ ei, const float* __restrict__ es1,
                             const float* __restrict__ ed1, float* __restrict__ e1,
                             unsigned* __restrict__ m1u) {
  int idx = blockIdx.x * 256 + threadIdx.x;
  if (idx >= TOT_EDGES * HEADS) return;
  int i = idx >> 3, h = idx & 7;
  int s = src_of(ei, i), d = dst_of(ei, i);
  float v = es1[s * 8 + h] + ed1[d * 8 + h];
  v = v >= 0.0f ? v : 0.2f * v;
  e1[idx] = v;
  atomicMax(m1u + d * 8 + h, mapf(v));
}

__global__ void ex1_kernel(const int* __restrict__ ei, float* __restrict__ e1,
                           const unsigned* __restrict__ m1u, float* __restrict__ denom1) {
  int idx = blockIdx.x * 256 + threadIdx.x;
  if (idx >= TOT_EDGES * HEADS) return;
  int i = idx >> 3, h = idx & 7;
  int d = dst_of(ei, i);
  float ex = expf(e1[idx] - unmapf(m1u[d * 8 + h]));
  e1[idx] = ex;
  atomicAdd(denom1 + d * 8 + h, ex);
}

// init g1 with the self-loop contribution (replaces memset; self edge id = E_EDGES + n)
__global__ void selfinit1_kernel(const float* __restrict__ e1, const float* __restrict__ denom1,
                                 const float* __restrict__ xw1, float* __restrict__ g1) {
  int idx = blockIdx.x * 256 + threadIdx.x;  // N_NODES*512
  int n = idx >> 9, j = idx & 511;
  int h = j >> 6;
  float alpha = e1[(size_t)(E_EDGES + n) * 8 + h] / denom1[n * 8 + h];
  g1[idx] = alpha * xw1[idx];
}

__global__ __launch_bounds__(256) void agg1_kernel(const int* __restrict__ ei,
                                                   const float* __restrict__ e1,
                                                   const float* __restrict__ denom1,
                                                   const float* __restrict__ xw1,
                                                   float* __restrict__ g1) {
  int i = blockIdx.x;  // real edges only
  int s = ei[i], d = ei[E_EDGES + i];
  for (int j = threadIdx.x; j < 512; j += 256) {
    int h = j >> 6;
    float alpha = e1[i * 8 + h] / denom1[d * 8 + h];
    atomicAdd(g1 + (size_t)d * 512 + j, alpha * xw1[(size_t)s * 512 + j]);
  }
}

__global__ void elu_bias_split_kernel(const float* __restrict__ g1, const float* __restrict__ b1,
                                      unsigned short* __restrict__ g1h,
                                      unsigned short* __restrict__ g1l) {
  int idx = blockIdx.x * 256 + threadIdx.x;  // N_NODES*512
  int j = idx & 511;
  float v = g1[idx] + b1[j];
  v = v > 0.0f ? v : expm1f(v);
  split2(v, &g1h[idx], &g1l[idx]);
}

// ---------- GAT layer 2 ----------
__global__ __launch_bounds__(64) void esed2_kernel(const float* __restrict__ xw2,
                                                   const float* __restrict__ as2,
                                                   const float* __restrict__ ad2,
                                                   float* __restrict__ es2,
                                                   float* __restrict__ ed2) {
  int n = blockIdx.x, t = threadIdx.x;
  float es = 0.0f, ed = 0.0f;
  for (int c = t; c < 512; c += 64) {
    float v = xw2[(size_t)n * 512 + c];
    es += v * as2[c]; ed += v * ad2[c];
  }
#pragma unroll
  for (int o = 32; o > 0; o >>= 1) { es += __shfl_down(es, o, 64); ed += __shfl_down(ed, o, 64); }
  if (t == 0) { es2[n] = es; ed2[n] = ed; }
}

__global__ void edge2_kernel(const int* __restrict__ ei, const float* __restrict__ es2,
                             const float* __restrict__ ed2, float* __restrict__ e2,
                             unsigned* __restrict__ m2u) {
  int i = blockIdx.x * 256 + threadIdx.x;
  if (i >= TOT_EDGES) return;
  int s = src_of(ei, i), d = dst_of(ei, i);
  float v = es2[s] + ed2[d];
  v = v >= 0.0f ? v : 0.2f * v;
  e2[i] = v;
  atomicMax(m2u + d, mapf(v));
}

__global__ void ex2_kernel(const int* __restrict__ ei, float* __restrict__ e2,
                           const unsigned* __restrict__ m2u, float* __restrict__ denom2) {
  int i = blockIdx.x * 256 + threadIdx.x;
  if (i >= TOT_EDGES) return;
  int d = dst_of(ei, i);
  float ex = expf(e2[i] - unmapf(m2u[d]));
  e2[i] = ex;
  atomicAdd(denom2 + d, ex);
}

__global__ void selfinit2_kernel(const float* __restrict__ e2, const float* __restrict__ denom2,
                                 const float* __restrict__ xw2, float* __restrict__ g2) {
  int idx = blockIdx.x * 256 + threadIdx.x;  // N_NODES*512
  int n = idx >> 9;
  float alpha = e2[E_EDGES + n] / denom2[n];
  g2[idx] = alpha * xw2[idx];
}

__global__ __launch_bounds__(256) void agg2_kernel(const int* __restrict__ ei,
                                                   const float* __restrict__ e2,
                                                   const float* __restrict__ denom2,
                                                   const float* __restrict__ xw2,
                                                   float* __restrict__ g2) {
  int i = blockIdx.x;  // real edges only
  int s = ei[i], d = ei[E_EDGES + i];
  float alpha = e2[i] / denom2[d];
  for (int j = threadIdx.x; j < 512; j += 256) {
    atomicAdd(g2 + (size_t)d * 512 + j, alpha * xw2[(size_t)s * 512 + j]);
  }
}

// ---------- scatter segment-max (adds b_lout bias on the fly) ----------
__global__ __launch_bounds__(256) void leftright_kernel(const int* __restrict__ ei,
                                                        const float* __restrict__ xp,
                                                        const float* __restrict__ b_lout,
                                                        unsigned* __restrict__ leftU,
                                                        unsigned* __restrict__ rightU,
                                                        int* __restrict__ flagL,
                                                        int* __restrict__ flagR) {
  int i = blockIdx.x;  // E_EDGES
  int s = ei[i], d = ei[E_EDGES + i];
  if (threadIdx.x == 0) { flagL[s] = 1; flagR[d] = 1; }
  for (int j = threadIdx.x; j < 512; j += 256) {
    unsigned v = mapf(xp[(size_t)i * 512 + j] + b_lout[j]);
    atomicMax(leftU + (size_t)s * 512 + j, v);
    atomicMax(rightU + (size_t)d * 512 + j, v);
  }
}

// ---------- feats = [g2+b2, left, right] -> bf16 h/l ----------
__global__ void concat_split_kernel(const float* __restrict__ g2, const float* __restrict__ b2,
                                    const unsigned* __restrict__ leftU,
                                    const unsigned* __restrict__ rightU,
                                    const int* __restrict__ flagL, const int* __restrict__ flagR,
                                    unsigned short* __restrict__ fh,
                                    unsigned short* __restrict__ fl) {
  int idx = blockIdx.x * 256 + threadIdx.x;  // N_NODES*512
  int n = idx >> 9, j = idx & 511;
  size_t base = (size_t)n * 1536 + j;
  split2(g2[idx] + b2[j], &fh[base], &fl[base]);
  split2(flagL[n] ? unmapf(leftU[idx]) : 0.0f, &fh[base + 512], &fl[base + 512]);
  split2(flagR[n] ? unmapf(rightU[idx]) : 0.0f, &fh[base + 1024], &fl[base + 1024]);
}

// ---------- launch ----------
extern "C" void kernel_launch(void* const* d_in, const int* in_sizes, int n_in,
                              void* d_out, int out_size, void* d_ws, size_t ws_size,
                              hipStream_t stream) {
  const float* synapse = (const float*)d_in[1];
  const float* x_param = (const float*)d_in[2];
  const float* W1 = (const float*)d_in[3];
  const float* as1 = (const float*)d_in[4];
  const float* ad1 = (const float*)d_in[5];
  const float* b1 = (const float*)d_in[6];
  const float* W2 = (const float*)d_in[7];
  const float* as2 = (const float*)d_in[8];
  const float* ad2 = (const float*)d_in[9];
  const float* b2 = (const float*)d_in[10];
  const float* W_in = (const float*)d_in[11];
  const float* b_in = (const float*)d_in[12];
  const float* W_inproj = (const float*)d_in[13];
  const float* conv_w = (const float*)d_in[14];
  const float* conv_b = (const float*)d_in[15];
  const float* W_xproj = (const float*)d_in[16];
  const float* W_dt = (const float*)d_in[17];
  const float* b_dt = (const float*)d_in[18];
  const float* A_log = (const float*)d_in[19];
  const float* Dv = (const float*)d_in[20];
  const float* W_outproj = (const float*)d_in[21];
  const float* W_lout = (const float*)d_in[22];
  const float* b_lout = (const float*)d_in[23];
  const float* Wc1 = (const float*)d_in[24];
  const float* bc1 = (const float*)d_in[25];
  const float* Wc2 = (const float*)d_in[26];
  const float* bc2 = (const float*)d_in[27];
  const int* edge_index = (const int*)d_in[28];
  const int* sidx = (const int*)d_in[29];
  float* out = (float*)d_out;

  // ----- static arena (phase-disjoint aliasing; ~107 MiB peak) -----
  const size_t MB = (size_t)1 << 20;
  const size_t KB = (size_t)1 << 10;
  char* ws = (char*)d_ws;
  unsigned short* xc_ch = (unsigned short*)(ws + 0);      // 12.6MB (mamba only)
  unsigned short* xc_cl = (unsigned short*)(ws + 16 * MB);// 12.6MB
  float* xw1 = (float*)(ws + 0);                          // 16MB
  float* g1 = (float*)(ws + 16 * MB);                     // 16MB
  unsigned short* g1h = (unsigned short*)(ws + 32 * MB);  // 8MB
  unsigned short* g1l = (unsigned short*)(ws + 40 * MB);  // 8MB
  unsigned short* xph = (unsigned short*)(ws + 48 * MB);  // 2MB
  unsigned short* xpl = (unsigned short*)(ws + 50 * MB);  // 2MB
  unsigned short* W1th = (unsigned short*)(ws + 52 * MB);            // 128KB
  unsigned short* W1tl = (unsigned short*)(ws + 52 * MB + 128 * KB); // 128KB
  float* xw2 = (float*)(ws + 48 * MB);                    // 16MB
  unsigned short* W2th = (unsigned short*)(ws + 0);               // 512KB (xw1 dead)
  unsigned short* W2tl = (unsigned short*)(ws + 512 * KB);        // 512KB
  float* g2 = (float*)(ws + 0);                           // 16MB
  unsigned short* featsh = (unsigned short*)(ws + 16 * MB);  // 24MB
  unsigned short* featsl = (unsigned short*)(ws + 40 * MB);  // 24MB
  float* hidden = (float*)(ws + 0);                       // 16MB (g2 dead after concat)
  float* xdb_c = (float*)(ws + 64 * MB);                  // 1.5MB (MC_CAP x 64)
  unsigned short* pooledh = (unsigned short*)(ws + 68 * MB);  // 4MB
  unsigned short* pooledl = (unsigned short*)(ws + 72 * MB);  // 4MB
  unsigned short* Wxth = (unsigned short*)(ws + 76 * MB);            // 128KB
  unsigned short* Wxtl = (unsigned short*)(ws + 76 * MB + 128 * KB); // 128KB
  float* WmixT = (float*)(ws + 77 * MB);                  // 2MB (512x1024 f32)
  unsigned short* Wmixth = (unsigned short*)(ws + 80 * MB);  // 1MB
  unsigned short* Wmixtl = (unsigned short*)(ws + 81 * MB);  // 1MB
  unsigned short* Wlth = (unsigned short*)(ws + 82 * MB);            // 512KB
  unsigned short* Wltl = (unsigned short*)(ws + 82 * MB + 512 * KB); // 512KB
  unsigned short* Woph = (unsigned short*)(ws + 83 * MB);            // 1MB
  unsigned short* Wopl = (unsigned short*)(ws + 84 * MB);            // 1MB
  float* negA = (float*)(ws + 85 * MB);                   // 64KB
  unsigned* leftU = (unsigned*)(ws + 64 * MB);            // 16MB (mamba dead)
  unsigned* rightU = (unsigned*)(ws + 80 * MB);           // 16MB
  float* x_point = (float*)(ws + 96 * MB);                // 4MB
  unsigned short* Wc1th = (unsigned short*)(ws + 96 * MB);             // 1.5MB (x_point dead)
  unsigned short* Wc1tl = (unsigned short*)(ws + 96 * MB + 1536 * KB); // 1.5MB
  unsigned short* Wc2th = (unsigned short*)(ws + 99 * MB);             // 32KB
  unsigned short* Wc2tl = (unsigned short*)(ws + 99 * MB + 64 * KB);   // 32KB
  char* sm = ws + 100 * MB;
  float* es1 = (float*)(sm + 0);                 // 256KB
  float* ed1 = (float*)(sm + 256 * KB);          // 256KB
  float* e1 = (float*)(sm + 512 * KB);           // 320KB
  unsigned* m1u = (unsigned*)(sm + 832 * KB);    // 256KB (one memset with denom1)
  float* denom1 = (float*)(sm + 1088 * KB);      // 256KB
  float* es2 = (float*)(sm + 1344 * KB);         // 32KB
  float* ed2 = (float*)(sm + 1376 * KB);         // 32KB
  float* e2 = (float*)(sm + 1408 * KB);          // 40KB
  unsigned* m2u = (unsigned*)(sm + 1448 * KB);   // 32KB (one memset m2u..flagR)
  float* denom2 = (float*)(sm + 1480 * KB);      // 32KB
  int* flagL = (int*)(sm + 1512 * KB);           // 32KB
  int* flagR = (int*)(sm + 1544 * KB);           // 32KB
  float* padded = (float*)(ws + 106 * MB);                   // 384KB
  int* counts = (int*)(ws + 106 * MB + 384 * KB);            // 8KB
  float* W_eff = (float*)(ws + 106 * MB + 400 * KB);         // 48KB
  float* b_eff = (float*)(ws + 106 * MB + 448 * KB);         // 8KB
  int* starts_c = (int*)(ws + 106 * MB + 456 * KB);          // 8KB

  auto g64 = [&](const float* A, int lda, const float* B, int ldb, float* C, int ldc,
                 int M, int N, int K, const float* bias, int act) {
    dim3 grid((N + 63) / 64, (M + 63) / 64);
    gemm_t<64, 64><<<grid, 256, 0, stream>>>(A, lda, B, ldb, C, ldc, M, N, K, bias, act);
  };
  auto gm2 = [&](const unsigned short* Ah, const unsigned short* Al,
                 const unsigned short* Bth, const unsigned short* Btl, float* C,
                 int M, int N, int K, const float* bias, int act) {
    gemm_mfma2<<<(N / 128) * (M / 128), 512, 0, stream>>>(Ah, Al, Bth, Btl, C, M, N, K, bias,
                                                          act);
  };
  auto tsplit = [&](const float* W, unsigned short* th, unsigned short* tl, int K, int N) {
    tsplit_kernel<<<(K * N + 255) / 256, 256, 0, stream>>>(W, th, tl, K, N);
  };
  auto split = [&](const float* x, unsigned short* h, unsigned short* l, int n) {
    split_kernel<<<(n + 255) / 256, 256, 0, stream>>>(x, h, l, n);
  };

  // ===== PRE: effective weights =====
  g64(W_in, DM, W_inproj, 2 * DI, W_eff, 2 * DI, 6, 2 * DI, DM, nullptr, 0);
  g64(b_in, DM, W_inproj, 2 * DI, b_eff, 2 * DI, 1, 2 * DI, DM, nullptr, 0);
  tsplit(W_lout, Wlth, Wltl, DM, DM);
  split(W_outproj, Woph, Wopl, DI * DM);
  hipMemsetAsync(WmixT, 0, (size_t)DM * DI * 4, stream);
  gemm_mfma_sk<<<dim3(DI / 64, DM / 64, 4), 256, 0, stream>>>(Wlth, Wltl, Woph, Wopl, WmixT,
                                                              DM, DI, DM);
  split(WmixT, Wmixth, Wmixtl, DM * DI);
  negA_kernel<<<(DI * DSTATE) / 256, 256, 0, stream>>>(A_log, negA);

  // ===== Mamba encoder =====
  hipMemsetAsync(padded, 0, (size_t)ROWS * 6 * 4, stream);
  scatter_padded_kernel<<<(NSYN + 255) / 256, 256, 0, stream>>>(synapse, sidx, padded);
  counts_kernel<<<(E_EDGES + 255) / 256, 256, 0, stream>>>(sidx, counts);
  prefix_kernel<<<1, 256, 0, stream>>>(counts, starts_c);
  xc_compact_kernel<<<dim3(DI / 256, E_EDGES), 256, 0, stream>>>(
      padded, W_eff, b_eff, conv_w, conv_b, counts, starts_c, xc_ch, xc_cl);
  tsplit(W_xproj, Wxth, Wxtl, DI, 64);
  hipMemsetAsync(xdb_c, 0, (size_t)MC_CAP * 64 * 4, stream);
  gemm_mfma_sk<<<dim3(1, MC_CAP / 64, 8), 256, 0, stream>>>(xc_ch, xc_cl, Wxth, Wxtl, xdb_c,
                                                            MC_CAP, 64, DI);
  mamba_scan_pool_kernel<<<dim3(DI / 256, E_EDGES), 256, 0, stream>>>(
      xdb_c, padded, W_eff, b_eff, W_dt, b_dt, negA, Dv, conv_w, conv_b, counts, starts_c,
      pooledh, pooledl);
  hipMemsetAsync(x_point, 0, (size_t)E_EDGES * DM * 4, stream);
  gemm_mfma_sk<<<dim3(DM / 64, E_EDGES / 64, 4), 256, 0, stream>>>(pooledh, pooledl, Wmixth,
                                                                   Wmixtl, x_point, E_EDGES,
                                                                   DM, DI);

  // ===== GAT layer 1 =====
  split(x_param, xph, xpl, N_NODES * F_IN);
  tsplit(W1, W1th, W1tl, F_IN, HEADS * HID);
  gm2(xph, xpl, W1th, W1tl, xw1, N_NODES, HEADS * HID, F_IN, nullptr, 0);
  esed1_kernel<<<(N_NODES * HEADS) / 256, 256, 0, stream>>>(xw1, as1, ad1, es1, ed1);
  hipMemsetAsync(m1u, 0, 512 * KB, stream);  // m1u + denom1
  edge1_kernel<<<(TOT_EDGES * HEADS + 255) / 256, 256, 0, stream>>>(edge_index, es1, ed1, e1, m1u);
  ex1_kernel<<<(TOT_EDGES * HEADS + 255) / 256, 256, 0, stream>>>(edge_index, e1, m1u, denom1);
  selfinit1_kernel<<<(N_NODES * 512) / 256, 256, 0, stream>>>(e1, denom1, xw1, g1);
  agg1_kernel<<<E_EDGES, 256, 0, stream>>>(edge_index, e1, denom1, xw1, g1);
  elu_bias_split_kernel<<<(N_NODES * 512) / 256, 256, 0, stream>>>(g1, b1, g1h, g1l);

  // ===== GAT layer 2 =====
  tsplit(W2, W2th, W2tl, HEADS * HID, REP);
  gm2(g1h, g1l, W2th, W2tl, xw2, N_NODES, REP, HEADS * HID, nullptr, 0);
  esed2_kernel<<<N_NODES, 64, 0, stream>>>(xw2, as2, ad2, es2, ed2);
  hipMemsetAsync(m2u, 0, 128 * KB, stream);  // m2u + denom2 + flagL + flagR
  edge2_kernel<<<(TOT_EDGES + 255) / 256, 256, 0, stream>>>(edge_index, es2, ed2, e2, m2u);
  ex2_kernel<<<(TOT_EDGES + 255) / 256, 256, 0, stream>>>(edge_index, e2, m2u, denom2);
  selfinit2_kernel<<<(N_NODES * 512) / 256, 256, 0, stream>>>(e2, denom2, xw2, g2);
  agg2_kernel<<<E_EDGES, 256, 0, stream>>>(edge_index, e2, denom2, xw2, g2);

  // ===== left/right segment max =====
  hipMemsetAsync(leftU, 0, 32 * MB, stream);  // leftU + rightU (contiguous)
  leftright_kernel<<<E_EDGES, 256, 0, stream>>>(edge_index, x_point, b_lout, leftU, rightU,
                                                flagL, flagR);

  // ===== classifier =====
  concat_split_kernel<<<(N_NODES * 512) / 256, 256, 0, stream>>>(g2, b2, leftU, rightU, flagL,
                                                                 flagR, featsh, featsl);
  tsplit(Wc1, Wc1th, Wc1tl, REP + 2 * DM, 512);
  tsplit(Wc2, Wc2th, Wc2tl, 512, NCLS);
  gm2(featsh, featsl, Wc1th, Wc1tl, hidden, N_NODES, 512, REP + 2 * DM, bc1, 1);
  gemm_thin32<0><<<N_NODES / 64, 256, 0, stream>>>(hidden, Wc2th, Wc2tl, out, N_NODES, bc2);
}

// Round 21
// 415.535 us; speedup vs baseline: 1.0935x; 1.0072x over previous
//
#include <hip/hip_runtime.h>

#define N_NODES 8192
#define F_IN 128
#define HID 64
#define HEADS 8
#define REP 512
#define NCLS 32
#define E_EDGES 2048
#define NSYN 4096
#define LMAX 8
#define DM 512
#define DI 1024
#define DSTATE 16
#define DCONV 4
#define DTR 32
#define TOT_EDGES (E_EDGES + N_NODES) /* 10240 */
#define ROWS (E_EDGES * LMAX)         /* 16384 */
#define MC_CAP 6144                   /* >= sum(min(max(cnt,1),8)) */

typedef short bf16x8 __attribute__((ext_vector_type(8)));
typedef float f32x4 __attribute__((ext_vector_type(4)));

// ---------- helpers ----------
__device__ __forceinline__ unsigned mapf(float f) {
  unsigned u = __float_as_uint(f);
  return (u & 0x80000000u) ? ~u : (u | 0x80000000u);
}
__device__ __forceinline__ float unmapf(unsigned u) {
  return __uint_as_float((u & 0x80000000u) ? (u ^ 0x80000000u) : ~u);
}
__device__ __forceinline__ float fsig(float x) {
  return __builtin_amdgcn_rcpf(1.0f + __expf(-x));
}
__device__ __forceinline__ float fsoftplus(float x) {
  return fmaxf(x, 0.0f) + __logf(1.0f + __expf(-fabsf(x)));
}
__device__ __forceinline__ unsigned short f2bf(float f) {
  unsigned u = __float_as_uint(f);
  unsigned r = (u + 0x7FFFu + ((u >> 16) & 1u)) >> 16;
  return (unsigned short)r;
}
__device__ __forceinline__ float bf2f(unsigned short h) {
  return __uint_as_float(((unsigned)h) << 16);
}
__device__ __forceinline__ void split2(float x, unsigned short* hh, unsigned short* ll) {
  unsigned short h = f2bf(x);
  *hh = h;
  *ll = f2bf(x - bf2f(h));
}
__device__ __forceinline__ int lower_bound_dev(const int* __restrict__ arr, int n, int v) {
  int lo = 0, hi = n;
  while (lo < hi) { int mid = (lo + hi) >> 1; if (arr[mid] < v) lo = mid + 1; else hi = mid; }
  return lo;
}
__device__ __forceinline__ int src_of(const int* __restrict__ ei, int i) {
  return i < E_EDGES ? ei[i] : i - E_EDGES;
}
__device__ __forceinline__ int dst_of(const int* __restrict__ ei, int i) {
  return i < E_EDGES ? ei[E_EDGES + i] : i - E_EDGES;
}
__device__ __forceinline__ int clip_cnt(int c) { return c < 1 ? 1 : (c > LMAX ? LMAX : c); }

// ---------- MFMA split-bf16 GEMM, 128x128 tile, 512 threads (8 waves, 2/SIMD) ----------
// 2-deep register prefetch (ping-pong pa/pb): loads for k+64 issue ~2 compute windows
// before their vmcnt wait, hiding L2 latency at 1 block/CU. Requires K % 64 == 0, K >= 128.
__global__ __launch_bounds__(512) void gemm_mfma2(
    const unsigned short* __restrict__ Ah, const unsigned short* __restrict__ Al,
    const unsigned short* __restrict__ Bth, const unsigned short* __restrict__ Btl,
    float* __restrict__ C, int M, int N, int K,
    const float* __restrict__ bias, int act) {
  __shared__ __align__(16) unsigned short As[2][128][40];
  __shared__ __align__(16) unsigned short Bs[2][128][40];
  const int tid = threadIdx.x;
  const int w = tid >> 6;
  const int lane = tid & 63;
  const int wr = w >> 2, wc = w & 3;  // 2x4 wave grid; wave tile 64x32
  const int mb = M >> 7;
  const int lin = blockIdx.x;
  const int bx = lin / mb;
  const int by = lin % mb;
  const int brow = by * 128;
  const int bcol = bx * 128;
  const int r0 = lane & 15;
  const int kg = lane >> 4;
  const int row0 = tid >> 2, kc0 = tid & 3;
  const size_t a0 = (size_t)(brow + row0) * K + kc0 * 8;
  const size_t b0 = (size_t)(bcol + row0) * K + kc0 * 8;
  f32x4 acc[4][2] = {};
  {
    bf16x8 t0 = *(const bf16x8*)(Ah + a0), t1 = *(const bf16x8*)(Al + a0);
    bf16x8 t2 = *(const bf16x8*)(Bth + b0), t3 = *(const bf16x8*)(Btl + b0);
    *(bf16x8*)(&As[0][row0][kc0 * 8]) = t0;
    *(bf16x8*)(&As[1][row0][kc0 * 8]) = t1;
    *(bf16x8*)(&Bs[0][row0][kc0 * 8]) = t2;
    *(bf16x8*)(&Bs[1][row0][kc0 * 8]) = t3;
  }
  bf16x8 pa[4], pb[4];
  pa[0] = *(const bf16x8*)(Ah + a0 + 32);
  pa[1] = *(const bf16x8*)(Al + a0 + 32);
  pa[2] = *(const bf16x8*)(Bth + b0 + 32);
  pa[3] = *(const bf16x8*)(Btl + b0 + 32);
  __syncthreads();

  auto mma_step = [&]() {
    bf16x8 bhv[2], blv[2];
#pragma unroll
    for (int cf = 0; cf < 2; ++cf) {
      bhv[cf] = *(const bf16x8*)(&Bs[0][wc * 32 + cf * 16 + r0][kg * 8]);
      blv[cf] = *(const bf16x8*)(&Bs[1][wc * 32 + cf * 16 + r0][kg * 8]);
    }
#pragma unroll
    for (int rf = 0; rf < 4; ++rf) {
      bf16x8 ah = *(const bf16x8*)(&As[0][wr * 64 + rf * 16 + r0][kg * 8]);
      bf16x8 al = *(const bf16x8*)(&As[1][wr * 64 + rf * 16 + r0][kg * 8]);
#pragma unroll
      for (int cf = 0; cf < 2; ++cf) {
        acc[rf][cf] = __builtin_amdgcn_mfma_f32_16x16x32_bf16(ah, bhv[cf], acc[rf][cf], 0, 0, 0);
        acc[rf][cf] = __builtin_amdgcn_mfma_f32_16x16x32_bf16(ah, blv[cf], acc[rf][cf], 0, 0, 0);
        acc[rf][cf] = __builtin_amdgcn_mfma_f32_16x16x32_bf16(al, bhv[cf], acc[rf][cf], 0, 0, 0);
      }
    }
  };
  auto load_regs = [&](bf16x8 (&p)[4], int kt) {
    p[0] = *(const bf16x8*)(Ah + a0 + kt);
    p[1] = *(const bf16x8*)(Al + a0 + kt);
    p[2] = *(const bf16x8*)(Bth + b0 + kt);
    p[3] = *(const bf16x8*)(Btl + b0 + kt);
  };
  auto store_lds = [&](bf16x8 (&p)[4]) {
    *(bf16x8*)(&As[0][row0][kc0 * 8]) = p[0];
    *(bf16x8*)(&As[1][row0][kc0 * 8]) = p[1];
    *(bf16x8*)(&Bs[0][row0][kc0 * 8]) = p[2];
    *(bf16x8*)(&Bs[1][row0][kc0 * 8]) = p[3];
  };

  for (int kt = 0; kt < K; kt += 64) {
    if (kt + 64 < K) load_regs(pb, kt + 64);
    mma_step();                     // LDS holds kt
    __syncthreads();
    store_lds(pa);                  // pa holds kt+32 (K%64==0 -> always valid)
    __syncthreads();
    if (kt + 96 < K) load_regs(pa, kt + 96);
    mma_step();                     // LDS holds kt+32
    __syncthreads();
    if (kt + 64 < K) {
      store_lds(pb);
      __syncthreads();
    }
  }
#pragma unroll
  for (int rf = 0; rf < 4; ++rf)
#pragma unroll
    for (int cf = 0; cf < 2; ++cf) {
      int col = bcol + wc * 32 + cf * 16 + r0;
      float bb = bias ? bias[col] : 0.0f;
#pragma unroll
      for (int j = 0; j < 4; ++j) {
        int row = brow + wr * 64 + rf * 16 + kg * 4 + j;
        float v = acc[rf][cf][j] + bb;
        if (act == 1) v = fmaxf(v, 0.0f);
        C[(size_t)row * N + col] = v;
      }
    }
}

// ---------- split-K variant (64x64): partial K range per blockIdx.z, atomicAdd output ----------
__global__ __launch_bounds__(256) void gemm_mfma_sk(
    const unsigned short* __restrict__ Ah, const unsigned short* __restrict__ Al,
    const unsigned short* __restrict__ Bth, const unsigned short* __restrict__ Btl,
    float* __restrict__ C, int M, int N, int K) {
  __shared__ __align__(16) unsigned short As[2][64][40];
  const int tid = threadIdx.x;
  const int w = tid >> 6;
  const int lane = tid & 63;
  const int brow = blockIdx.y * 64;
  const int bcol = blockIdx.x * 64;
  const int srow = tid >> 2;
  const int skc = tid & 3;
  const int r0 = lane & 15;
  const int kg = lane >> 4;
  const int kchunk = K / gridDim.z;
  const int k0 = blockIdx.z * kchunk;
  f32x4 acc[4] = {};
  const size_t aoff = (size_t)(brow + srow) * K;
  const size_t boff = (size_t)(bcol + w * 16 + r0) * K + kg * 8;
  for (int kt = k0; kt < k0 + kchunk; kt += 32) {
    bf16x8 bh = *(const bf16x8*)(Bth + boff + kt);
    bf16x8 bl = *(const bf16x8*)(Btl + boff + kt);
    *(bf16x8*)(&As[0][srow][skc * 8]) = *(const bf16x8*)(Ah + aoff + kt + skc * 8);
    *(bf16x8*)(&As[1][srow][skc * 8]) = *(const bf16x8*)(Al + aoff + kt + skc * 8);
    __syncthreads();
#pragma unroll
    for (int r = 0; r < 4; ++r) {
      bf16x8 ah = *(const bf16x8*)(&As[0][r * 16 + r0][kg * 8]);
      bf16x8 al = *(const bf16x8*)(&As[1][r * 16 + r0][kg * 8]);
      acc[r] = __builtin_amdgcn_mfma_f32_16x16x32_bf16(ah, bh, acc[r], 0, 0, 0);
      acc[r] = __builtin_amdgcn_mfma_f32_16x16x32_bf16(ah, bl, acc[r], 0, 0, 0);
      acc[r] = __builtin_amdgcn_mfma_f32_16x16x32_bf16(al, bh, acc[r], 0, 0, 0);
    }
    __syncthreads();
  }
  const int col = bcol + w * 16 + r0;
#pragma unroll
  for (int r = 0; r < 4; ++r) {
#pragma unroll
    for (int j = 0; j < 4; ++j) {
      int row = brow + r * 16 + kg * 4 + j;
      atomicAdd(&C[(size_t)row * N + col], acc[r][j]);
    }
  }
}

// ---------- thin MFMA GEMM: C(Mx32) = relu(A32)(Mx512) @ Bt(32x512)^T + bias ----------
template <int APPLY_RELU>
__global__ __launch_bounds__(256) void gemm_thin32(
    const float* __restrict__ A32,
    const unsigned short* __restrict__ Bth, const unsigned short* __restrict__ Btl,
    float* __restrict__ C, int M, const float* __restrict__ bias) {
  const int tid = threadIdx.x;
  const int w = tid >> 6;
  const int lane = tid & 63;
  const int r0 = lane & 15;
  const int kg = lane >> 4;
  const int rowbase = blockIdx.x * 64 + w * 16;
  f32x4 acc[2] = {};
  const float* arow = A32 + (size_t)(rowbase + r0) * 512 + kg * 8;
  for (int kt = 0; kt < 512; kt += 32) {
    float4 f0 = *(const float4*)(arow + kt);
    float4 f1 = *(const float4*)(arow + kt + 4);
    float v[8] = {f0.x, f0.y, f0.z, f0.w, f1.x, f1.y, f1.z, f1.w};
    bf16x8 ah, al;
#pragma unroll
    for (int j = 0; j < 8; ++j) {
      float vv = APPLY_RELU ? fmaxf(v[j], 0.0f) : v[j];
      unsigned short hh, ll;
      split2(vv, &hh, &ll);
      ah[j] = (short)hh;
      al[j] = (short)ll;
    }
#pragma unroll
    for (int cf = 0; cf < 2; ++cf) {
      bf16x8 bh = *(const bf16x8*)(Bth + (size_t)(cf * 16 + r0) * 512 + kt + kg * 8);
      bf16x8 bl = *(const bf16x8*)(Btl + (size_t)(cf * 16 + r0) * 512 + kt + kg * 8);
      acc[cf] = __builtin_amdgcn_mfma_f32_16x16x32_bf16(ah, bh, acc[cf], 0, 0, 0);
      acc[cf] = __builtin_amdgcn_mfma_f32_16x16x32_bf16(ah, bl, acc[cf], 0, 0, 0);
      acc[cf] = __builtin_amdgcn_mfma_f32_16x16x32_bf16(al, bh, acc[cf], 0, 0, 0);
    }
  }
#pragma unroll
  for (int cf = 0; cf < 2; ++cf) {
    int col = cf * 16 + r0;
    float bb = bias[col];
#pragma unroll
    for (int j = 0; j < 4; ++j) {
      int row = rowbase + kg * 4 + j;
      C[(size_t)row * 32 + col] = acc[cf][j] + bb;
    }
  }
}

// ---------- split / transpose-split ----------
__global__ void split_kernel(const float* __restrict__ x, unsigned short* __restrict__ h,
                             unsigned short* __restrict__ l, int n) {
  int i = blockIdx.x * 256 + threadIdx.x;
  if (i >= n) return;
  split2(x[i], &h[i], &l[i]);
}

__global__ void tsplit_kernel(const float* __restrict__ W, unsigned short* __restrict__ Wth,
                              unsigned short* __restrict__ Wtl, int K, int N) {
  int i = blockIdx.x * 256 + threadIdx.x;
  if (i >= K * N) return;
  int k = i / N, n = i - k * N;
  float v = W[i];
  unsigned short h = f2bf(v);
  Wth[(size_t)n * K + k] = h;
  Wtl[(size_t)n * K + k] = f2bf(v - bf2f(h));
}

// ---------- fused weight-prep: tsplit Wl / split Wop / negA / tsplit Wx / tsplit W1 / split xp ----------
#define PREP_SEG0 262144   /* tsplit W_lout 512x512 */
#define PREP_SEG1 524288   /* split W_outproj */
#define PREP_SEG2 16384    /* negA */
#define PREP_SEG3 65536    /* tsplit W_xproj 1024x64 */
#define PREP_SEG4 65536    /* tsplit W1 128x512 */
#define PREP_SEG5 1048576  /* split x_param */
#define PREP_TOT (PREP_SEG0 + PREP_SEG1 + PREP_SEG2 + PREP_SEG3 + PREP_SEG4 + PREP_SEG5)
__global__ void prep1_kernel(
    const float* __restrict__ W_lout, const float* __restrict__ W_outproj,
    const float* __restrict__ A_log, const float* __restrict__ W_xproj,
    const float* __restrict__ W1, const float* __restrict__ x_param,
    unsigned short* __restrict__ Wlth, unsigned short* __restrict__ Wltl,
    unsigned short* __restrict__ Woph, unsigned short* __restrict__ Wopl,
    float* __restrict__ negA,
    unsigned short* __restrict__ Wxth, unsigned short* __restrict__ Wxtl,
    unsigned short* __restrict__ W1th, unsigned short* __restrict__ W1tl,
    unsigned short* __restrict__ xph, unsigned short* __restrict__ xpl) {
  int i = blockIdx.x * 256 + threadIdx.x;
  if (i < PREP_SEG0) {
    int k = i >> 9, n = i & 511;
    float v = W_lout[i];
    unsigned short h = f2bf(v);
    Wlth[(size_t)n * 512 + k] = h;
    Wltl[(size_t)n * 512 + k] = f2bf(v - bf2f(h));
    return;
  }
  i -= PREP_SEG0;
  if (i < PREP_SEG1) { split2(W_outproj[i], &Woph[i], &Wopl[i]); return; }
  i -= PREP_SEG1;
  if (i < PREP_SEG2) { negA[i] = -__expf(A_log[i]); return; }
  i -= PREP_SEG2;
  if (i < PREP_SEG3) {
    int k = i >> 6, n = i & 63;
    float v = W_xproj[i];
    unsigned short h = f2bf(v);
    Wxth[(size_t)n * 1024 + k] = h;
    Wxtl[(size_t)n * 1024 + k] = f2bf(v - bf2f(h));
    return;
  }
  i -= PREP_SEG3;
  if (i < PREP_SEG4) {
    int k = i >> 9, n = i & 511;
    float v = W1[i];
    unsigned short h = f2bf(v);
    W1th[(size_t)n * 128 + k] = h;
    W1tl[(size_t)n * 128 + k] = f2bf(v - bf2f(h));
    return;
  }
  i -= PREP_SEG4;
  if (i < PREP_SEG5) { split2(x_param[i], &xph[i], &xpl[i]); }
}

// ---------- tiled f32 GEMM (small shapes) ----------
template <int BM, int BN>
__global__ __launch_bounds__(256) void gemm_t(
    const float* __restrict__ A, int lda,
    const float* __restrict__ B, int ldb,
    float* __restrict__ C, int ldc,
    int M, int N, int K,
    const float* __restrict__ bias, int act) {
  constexpr int RR = BM / 64;
  constexpr int CR = BN / 64;
  __shared__ float As[16][BM + 4];
  __shared__ float Bs[16][BN + 4];
  const int tid = threadIdx.x;
  const int tx = tid & 15;
  const int ty = tid >> 4;
  const int brow = blockIdx.y * BM;
  const int bcol = blockIdx.x * BN;
  float acc[RR][CR][4][4] = {};
  for (int kt = 0; kt < K; kt += 16) {
#pragma unroll
    for (int p = 0; p < RR; ++p) {
      int c = tid + p * 256;
      int row = c >> 2, kc = c & 3;
      int gr = brow + row;
      float4 v = make_float4(0.f, 0.f, 0.f, 0.f);
      if (gr < M) v = *reinterpret_cast<const float4*>(A + (size_t)gr * lda + kt + kc * 4);
      As[kc * 4 + 0][row] = v.x;
      As[kc * 4 + 1][row] = v.y;
      As[kc * 4 + 2][row] = v.z;
      As[kc * 4 + 3][row] = v.w;
    }
#pragma unroll
    for (int p = 0; p < CR; ++p) {
      int c = tid + p * 256;
      int k = c / (BN / 4), c4 = c % (BN / 4);
      int gc = bcol + c4 * 4;
      float4 v = make_float4(0.f, 0.f, 0.f, 0.f);
      if (gc < N) v = *reinterpret_cast<const float4*>(B + (size_t)(kt + k) * ldb + gc);
      *reinterpret_cast<float4*>(&Bs[k][c4 * 4]) = v;
    }
    __syncthreads();
#pragma unroll
    for (int k = 0; k < 16; ++k) {
      float av[RR * 4], bv[CR * 4];
#pragma unroll
      for (int r = 0; r < RR; ++r) {
        float4 t = *reinterpret_cast<const float4*>(&As[k][r * 64 + ty * 4]);
        av[r * 4 + 0] = t.x; av[r * 4 + 1] = t.y; av[r * 4 + 2] = t.z; av[r * 4 + 3] = t.w;
      }
#pragma unroll
      for (int cq = 0; cq < CR; ++cq) {
        float4 t = *reinterpret_cast<const float4*>(&Bs[k][cq * 64 + tx * 4]);
        bv[cq * 4 + 0] = t.x; bv[cq * 4 + 1] = t.y; bv[cq * 4 + 2] = t.z; bv[cq * 4 + 3] = t.w;
      }
#pragma unroll
      for (int r = 0; r < RR; ++r)
#pragma unroll
        for (int cq = 0; cq < CR; ++cq)
#pragma unroll
          for (int i = 0; i < 4; ++i)
#pragma unroll
            for (int j = 0; j < 4; ++j)
              acc[r][cq][i][j] = fmaf(av[r * 4 + i], bv[cq * 4 + j], acc[r][cq][i][j]);
    }
    __syncthreads();
  }
#pragma unroll
  for (int r = 0; r < RR; ++r)
#pragma unroll
    for (int i = 0; i < 4; ++i) {
      int row = brow + r * 64 + ty * 4 + i;
      if (row >= M) continue;
#pragma unroll
      for (int cq = 0; cq < CR; ++cq) {
        int col = bcol + cq * 64 + tx * 4;
        if (col >= N) continue;
        float4 v;
        v.x = acc[r][cq][i][0]; v.y = acc[r][cq][i][1];
        v.z = acc[r][cq][i][2]; v.w = acc[r][cq][i][3];
        if (bias) {
          float4 bb = *reinterpret_cast<const float4*>(bias + col);
          v.x += bb.x; v.y += bb.y; v.z += bb.z; v.w += bb.w;
        }
        if (act == 1) {
          v.x = fmaxf(v.x, 0.f); v.y = fmaxf(v.y, 0.f);
          v.z = fmaxf(v.z, 0.f); v.w = fmaxf(v.w, 0.f);
        }
        *reinterpret_cast<float4*>(C + (size_t)row * ldc + col) = v;
      }
    }
}

// ---------- mamba: pad/scatter + fused counts+prefix ----------
__global__ void scatter_padded_kernel(const float* __restrict__ synapse,
                                      const int* __restrict__ sidx,
                                      float* __restrict__ padded) {
  int i = blockIdx.x * 256 + threadIdx.x;
  if (i >= NSYN) return;
  int e = sidx[i];
  int lo = lower_bound_dev(sidx, NSYN, e);
  int pos = i - lo;
  if (pos < LMAX) {
#pragma unroll
    for (int c = 0; c < 6; ++c) padded[((size_t)e * LMAX + pos) * 6 + c] = synapse[(size_t)i * 6 + c];
  }
}

// counts + exclusive prefix over clipped counts -> starts_c (one block, 256 threads x 8)
__global__ __launch_bounds__(256) void prefix_kernel(const int* __restrict__ sidx,
                                                     int* __restrict__ counts,
                                                     int* __restrict__ starts_c) {
  __shared__ int part[256];
  int t = threadIdx.x;
  int loc[8];
  int s = 0;
  int lo = lower_bound_dev(sidx, NSYN, t * 8);
#pragma unroll
  for (int i = 0; i < 8; ++i) {
    int hi = lower_bound_dev(sidx, NSYN, t * 8 + i + 1);
    int c = hi - lo;
    counts[t * 8 + i] = c;
    lo = hi;
    c = clip_cnt(c);
    loc[i] = s;
    s += c;
  }
  part[t] = s;
  __syncthreads();
  int mytot = s;
  for (int o = 1; o < 256; o <<= 1) {
    int add = (t >= o) ? part[t - o] : 0;
    __syncthreads();
    part[t] += add;
    __syncthreads();
  }
  int off = part[t] - mytot;
#pragma unroll
  for (int i = 0; i < 8; ++i) starts_c[t * 8 + i] = off + loc[i];
}

// ---------- mamba: compact xc = silu(conv(padded@W_eff)) -> bf16 h/l ----------
__global__ __launch_bounds__(256) void xc_compact_kernel(
    const float* __restrict__ padded,
    const float* __restrict__ W_eff, const float* __restrict__ b_eff,
    const float* __restrict__ conv_w, const float* __restrict__ conv_b,
    const int* __restrict__ counts, const int* __restrict__ starts_c,
    unsigned short* __restrict__ xch, unsigned short* __restrict__ xcl) {
  __shared__ float pads[LMAX * 6];
  int t = threadIdx.x;
  int d = blockIdx.x * 256 + t;
  int e = blockIdx.y;
  if (t < LMAX * 6) pads[t] = padded[(size_t)e * LMAX * 6 + t];
  __syncthreads();
  int cnt = clip_cnt(counts[e]);
  int sc = starts_c[e];
  float wef[6];
#pragma unroll
  for (int c = 0; c < 6; ++c) wef[c] = W_eff[c * 2048 + d];
  float cw0 = conv_w[d * 4 + 0], cw1 = conv_w[d * 4 + 1];
  float cw2 = conv_w[d * 4 + 2], cw3 = conv_w[d * 4 + 3];
  float cb = conv_b[d], be = b_eff[d];
  float x0 = 0.f, x1 = 0.f, x2 = 0.f;
  for (int l = 0; l < cnt; ++l) {
    float xm = be;
#pragma unroll
    for (int c = 0; c < 6; ++c) xm += pads[l * 6 + c] * wef[c];
    float s0 = cb + xm * cw3;
    if (l >= 1) s0 += x2 * cw2;
    if (l >= 2) s0 += x1 * cw1;
    if (l >= 3) s0 += x0 * cw0;
    float v = s0 * fsig(s0);
    size_t o = (size_t)(sc + l) * DI + d;
    split2(v, &xch[o], &xcl[o]);
    x0 = x1; x1 = x2; x2 = xm;
  }
}

// ---------- mamba: scan with LDS-staged xdb rows (broadcast reads) ----------
__global__ __launch_bounds__(256) void mamba_scan_pool_kernel(
    const float* __restrict__ xdb_c, const float* __restrict__ padded,
    const float* __restrict__ W_eff, const float* __restrict__ b_eff,
    const float* __restrict__ W_dt, const float* __restrict__ b_dt,
    const float* __restrict__ negA, const float* __restrict__ Dv,
    const float* __restrict__ conv_w, const float* __restrict__ conv_b,
    const int* __restrict__ counts, const int* __restrict__ starts_c,
    unsigned short* __restrict__ pooledh, unsigned short* __restrict__ pooledl) {
  __shared__ float pads[LMAX * 6];
  __shared__ float rows[LMAX * 64];  // staged xdb rows (2KB)
  int t = threadIdx.x;
  int d = blockIdx.x * 256 + t;
  int e = blockIdx.y;
  int cnt = clip_cnt(counts[e]);
  int sc = starts_c[e];
  if (t < LMAX * 6) pads[t] = padded[(size_t)e * LMAX * 6 + t];
  for (int i = t; i < cnt * 64; i += 256) rows[i] = xdb_c[(size_t)sc * 64 + i];
  float wdt[DTR];
#pragma unroll
  for (int k = 0; k < DTR; ++k) wdt[k] = W_dt[k * DI + d];
  float a[DSTATE];
#pragma unroll
  for (int n = 0; n < DSTATE; ++n) a[n] = negA[d * DSTATE + n];
  float h[DSTATE];
#pragma unroll
  for (int n = 0; n < DSTATE; ++n) h[n] = 0.0f;
  float wef[6], wez[6];
#pragma unroll
  for (int c = 0; c < 6; ++c) {
    wef[c] = W_eff[c * 2048 + d];
    wez[c] = W_eff[c * 2048 + DI + d];
  }
  float cw0 = conv_w[d * 4 + 0], cw1 = conv_w[d * 4 + 1];
  float cw2 = conv_w[d * 4 + 2], cw3 = conv_w[d * 4 + 3];
  float cb = conv_b[d];
  float bdt = b_dt[d], Dd = Dv[d], be = b_eff[d], bez = b_eff[DI + d];
  __syncthreads();
  float x0 = 0.f, x1 = 0.f, x2 = 0.f;
  float ssum = 0.0f;
  for (int l = 0; l < cnt; ++l) {
    float xm = be;
#pragma unroll
    for (int c = 0; c < 6; ++c) xm += pads[l * 6 + c] * wef[c];
    float s0 = cb + xm * cw3;
    if (l >= 1) s0 += x2 * cw2;
    if (l >= 2) s0 += x1 * cw1;
    if (l >= 3) s0 += x0 * cw0;
    float xt = s0 * fsig(s0);
    const float* __restrict__ xrow = &rows[l * 64];
    float acc = bdt;
#pragma unroll
    for (int k = 0; k < DTR; ++k) acc += xrow[k] * wdt[k];
    float dt = fsoftplus(acc);
    float dtx = dt * xt;
    float y = 0.0f;
#pragma unroll
    for (int n = 0; n < DSTATE; ++n) {
      float en = __expf(dt * a[n]);
      h[n] = en * h[n] + dtx * xrow[32 + n];
      y += h[n] * xrow[48 + n];
    }
    y += Dd * xt;
    float z = bez;
#pragma unroll
    for (int c = 0; c < 6; ++c) z += pads[l * 6 + c] * wez[c];
    ssum += y * z * fsig(z);
    x0 = x1; x1 = x2; x2 = xm;
  }
  float pv = ssum / (float)cnt;
  split2(pv, &pooledh[(size_t)e * DI + d], &pooledl[(size_t)e * DI + d]);
}

// ---------- GAT layer 1 ----------
__global__ void esed1_kernel(const float* __restrict__ xw1, const float* __restrict__ as1,
                             const float* __restrict__ ad1, float* __restrict__ es1,
                             float* __restrict__ ed1) {
  int idx = blockIdx.x * 256 + threadIdx.x;  // N_NODES*HEADS
  int n = idx >> 3, h = idx & 7;
  const float* xr = xw1 + (size_t)n * 512 + h * 64;
  const float* sr = as1 + h * 64;
  const float* dr = ad1 + h * 64;
  float es = 0.0f, ed = 0.0f;
#pragma unroll
  for (int c = 0; c < 64; ++c) { float v = xr[c]; es += v * sr[c]; ed += v * dr[c]; }
  es1[idx] = es; ed1[idx] = ed;
}

// fused edge score + exp (no max-subtraction: |e| <~ 0.2, exp exact in fp32)
__global__ void edgeexp1_kernel(const int* __restrict__ ei, const float* __restrict__ es1,
                                const float* __restrict__ ed1, float* __restrict__ e1,
                                float* __restrict__ denom1) {
  int idx = blockIdx.x * 256 + threadIdx.x;
  if (idx >= TOT_EDGES * HEADS) return;
  int i = idx >> 3, h = idx & 7;
  int s = src_of(ei, i), d = dst_of(ei, i);
  float v = es1[s * 8 + h] + ed1[d * 8 + h];
  v = v >= 0.0f ? v : 0.2f * v;
  float ex = expf(v);
  e1[idx] = ex;
  atomicAdd(denom1 + d * 8 + h, ex);
}

// init g1 with the self-loop contribution (replaces memset; self edge id = E_EDGES + n)
__global__ void selfinit1_kernel(const float* __restrict__ e1, const float* __restrict__ denom1,
                                 const float* __restrict__ xw1, float* __restrict__ g1) {
  int idx = blockIdx.x * 256 + threadIdx.x;  // N_NODES*512
  int n = idx >> 9, j = idx & 511;
  int h = j >> 6;
  float alpha = e1[(size_t)(E_EDGES + n) * 8 + h] / denom1[n * 8 + h];
  g1[idx] = alpha * xw1[idx];
}

__global__ __launch_bounds__(256) void agg1_kernel(const int* __restrict__ ei,
                                                   const float* __restrict__ e1,
                                                   const float* __restrict__ denom1,
                                                   const float* __restrict__ xw1,
                                                   float* __restrict__ g1) {
  int i = blockIdx.x;  // real edges only
  int s = ei[i], d = ei[E_EDGES + i];
  for (int j = threadIdx.x; j < 512; j += 256) {
    int h = j >> 6;
    float alpha = e1[i * 8 + h] / denom1[d * 8 + h];
    atomicAdd(g1 + (size_t)d * 512 + j, alpha * xw1[(size_t)s * 512 + j]);
  }
}

__global__ void elu_bias_split_kernel(const float* __restrict__ g1, const float* __restrict__ b1,
                                      unsigned short* __restrict__ g1h,
                                      unsigned short* __restrict__ g1l) {
  int idx = blockIdx.x * 256 + threadIdx.x;  // N_NODES*512
  int j = idx & 511;
  float v = g1[idx] + b1[j];
  v = v > 0.0f ? v : expm1f(v);
  split2(v, &g1h[idx], &g1l[idx]);
}

// ---------- GAT layer 2 ----------
__global__ __launch_bounds__(64) void esed2_kernel(const float* __restrict__ xw2,
                                                   const float* __restrict__ as2,
                                                   const float* __restrict__ ad2,
                                                   float* __restrict__ es2,
                                                   float* __restrict__ ed2) {
  int n = blockIdx.x, t = threadIdx.x;
  float es = 0.0f, ed = 0.0f;
  for (int c = t; c < 512; c += 64) {
    float v = xw2[(size_t)n * 512 + c];
    es += v * as2[c]; ed += v * ad2[c];
  }
#pragma unroll
  for (int o = 32; o > 0; o >>= 1) { es += __shfl_down(es, o, 64); ed += __shfl_down(ed, o, 64); }
  if (t == 0) { es2[n] = es; ed2[n] = ed; }
}

__global__ void edgeexp2_kernel(const int* __restrict__ ei, const float* __restrict__ es2,
                                const float* __restrict__ ed2, float* __restrict__ e2,
                                float* __restrict__ denom2) {
  int i = blockIdx.x * 256 + threadIdx.x;
  if (i >= TOT_EDGES) return;
  int s = src_of(ei, i), d = dst_of(ei, i);
  float v = es2[s] + ed2[d];
  v = v >= 0.0f ? v : 0.2f * v;
  float ex = expf(v);
  e2[i] = ex;
  atomicAdd(denom2 + d, ex);
}

__global__ void selfinit2_kernel(const float* __restrict__ e2, const float* __restrict__ denom2,
                                 const float* __restrict__ xw2, float* __restrict__ g2) {
  int idx = blockIdx.x * 256 + threadIdx.x;  // N_NODES*512
  int n = idx >> 9;
  float alpha = e2[E_EDGES + n] / denom2[n];
  g2[idx] = alpha * xw2[idx];
}

__global__ __launch_bounds__(256) void agg2_kernel(const int* __restrict__ ei,
                                                   const float* __restrict__ e2,
                                                   const float* __restrict__ denom2,
                                                   const float* __restrict__ xw2,
                                                   float* __restrict__ g2) {
  int i = blockIdx.x;  // real edges only
  int s = ei[i], d = ei[E_EDGES + i];
  float alpha = e2[i] / denom2[d];
  for (int j = threadIdx.x; j < 512; j += 256) {
    atomicAdd(g2 + (size_t)d * 512 + j, alpha * xw2[(size_t)s * 512 + j]);
  }
}

// ---------- scatter segment-max (adds b_lout bias on the fly) ----------
__global__ __launch_bounds__(256) void leftright_kernel(const int* __restrict__ ei,
                                                        const float* __restrict__ xp,
                                                        const float* __restrict__ b_lout,
                                                        unsigned* __restrict__ leftU,
                                                        unsigned* __restrict__ rightU,
                                                        int* __restrict__ flagL,
                                                        int* __restrict__ flagR) {
  int i = blockIdx.x;  // E_EDGES
  int s = ei[i], d = ei[E_EDGES + i];
  if (threadIdx.x == 0) { flagL[s] = 1; flagR[d] = 1; }
  for (int j = threadIdx.x; j < 512; j += 256) {
    unsigned v = mapf(xp[(size_t)i * 512 + j] + b_lout[j]);
    atomicMax(leftU + (size_t)s * 512 + j, v);
    atomicMax(rightU + (size_t)d * 512 + j, v);
  }
}

// ---------- feats = [g2+b2, left, right] -> bf16 h/l ----------
__global__ void concat_split_kernel(const float* __restrict__ g2, const float* __restrict__ b2,
                                    const unsigned* __restrict__ leftU,
                                    const unsigned* __restrict__ rightU,
                                    const int* __restrict__ flagL, const int* __restrict__ flagR,
                                    unsigned short* __restrict__ fh,
                                    unsigned short* __restrict__ fl) {
  int idx = blockIdx.x * 256 + threadIdx.x;  // N_NODES*512
  int n = idx >> 9, j = idx & 511;
  size_t base = (size_t)n * 1536 + j;
  split2(g2[idx] + b2[j], &fh[base], &fl[base]);
  split2(flagL[n] ? unmapf(leftU[idx]) : 0.0f, &fh[base + 512], &fl[base + 512]);
  split2(flagR[n] ? unmapf(rightU[idx]) : 0.0f, &fh[base + 1024], &fl[base + 1024]);
}

// ---------- launch ----------
extern "C" void kernel_launch(void* const* d_in, const int* in_sizes, int n_in,
                              void* d_out, int out_size, void* d_ws, size_t ws_size,
                              hipStream_t stream) {
  const float* synapse = (const float*)d_in[1];
  const float* x_param = (const float*)d_in[2];
  const float* W1 = (const float*)d_in[3];
  const float* as1 = (const float*)d_in[4];
  const float* ad1 = (const float*)d_in[5];
  const float* b1 = (const float*)d_in[6];
  const float* W2 = (const float*)d_in[7];
  const float* as2 = (const float*)d_in[8];
  const float* ad2 = (const float*)d_in[9];
  const float* b2 = (const float*)d_in[10];
  const float* W_in = (const float*)d_in[11];
  const float* b_in = (const float*)d_in[12];
  const float* W_inproj = (const float*)d_in[13];
  const float* conv_w = (const float*)d_in[14];
  const float* conv_b = (const float*)d_in[15];
  const float* W_xproj = (const float*)d_in[16];
  const float* W_dt = (const float*)d_in[17];
  const float* b_dt = (const float*)d_in[18];
  const float* A_log = (const float*)d_in[19];
  const float* Dv = (const float*)d_in[20];
  const float* W_outproj = (const float*)d_in[21];
  const float* W_lout = (const float*)d_in[22];
  const float* b_lout = (const float*)d_in[23];
  const float* Wc1 = (const float*)d_in[24];
  const float* bc1 = (const float*)d_in[25];
  const float* Wc2 = (const float*)d_in[26];
  const float* bc2 = (const float*)d_in[27];
  const int* edge_index = (const int*)d_in[28];
  const int* sidx = (const int*)d_in[29];
  float* out = (float*)d_out;

  // ----- static arena (phase-disjoint aliasing; ~107 MiB peak) -----
  const size_t MB = (size_t)1 << 20;
  const size_t KB = (size_t)1 << 10;
  char* ws = (char*)d_ws;
  unsigned short* xc_ch = (unsigned short*)(ws + 0);      // 12.6MB (mamba only)
  unsigned short* xc_cl = (unsigned short*)(ws + 16 * MB);// 12.6MB
  float* xw1 = (float*)(ws + 0);                          // 16MB
  float* g1 = (float*)(ws + 16 * MB);                     // 16MB
  unsigned short* g1h = (unsigned short*)(ws + 32 * MB);  // 8MB
  unsigned short* g1l = (unsigned short*)(ws + 40 * MB);  // 8MB
  unsigned short* xph = (unsigned short*)(ws + 48 * MB);  // 2MB
  unsigned short* xpl = (unsigned short*)(ws + 50 * MB);  // 2MB
  unsigned short* W1th = (unsigned short*)(ws + 52 * MB);            // 128KB
  unsigned short* W1tl = (unsigned short*)(ws + 52 * MB + 128 * KB); // 128KB
  float* xw2 = (float*)(ws + 48 * MB);                    // 16MB
  unsigned short* W2th = (unsigned short*)(ws + 0);               // 512KB (xw1 dead)
  unsigned short* W2tl = (unsigned short*)(ws + 512 * KB);        // 512KB
  float* g2 = (float*)(ws + 0);                           // 16MB
  unsigned short* featsh = (unsigned short*)(ws + 16 * MB);  // 24MB
  unsigned short* featsl = (unsigned short*)(ws + 40 * MB);  // 24MB
  float* hidden = (float*)(ws + 0);                       // 16MB (g2 dead after concat)
  float* xdb_c = (float*)(ws + 64 * MB);                  // 1.5MB (MC_CAP x 64)
  unsigned short* pooledh = (unsigned short*)(ws + 68 * MB);  // 4MB
  unsigned short* pooledl = (unsigned short*)(ws + 72 * MB);  // 4MB
  unsigned short* Wxth = (unsigned short*)(ws + 76 * MB);            // 128KB
  unsigned short* Wxtl = (unsigned short*)(ws + 76 * MB + 128 * KB); // 128KB
  float* WmixT = (float*)(ws + 77 * MB);                  // 2MB (512x1024 f32)
  unsigned short* Wmixth = (unsigned short*)(ws + 80 * MB);  // 1MB
  unsigned short* Wmixtl = (unsigned short*)(ws + 81 * MB);  // 1MB
  unsigned short* Wlth = (unsigned short*)(ws + 82 * MB);            // 512KB
  unsigned short* Wltl = (unsigned short*)(ws + 82 * MB + 512 * KB); // 512KB
  unsigned short* Woph = (unsigned short*)(ws + 83 * MB);            // 1MB
  unsigned short* Wopl = (unsigned short*)(ws + 84 * MB);            // 1MB
  float* negA = (float*)(ws + 85 * MB);                   // 64KB
  unsigned* leftU = (unsigned*)(ws + 64 * MB);            // 16MB (mamba dead)
  unsigned* rightU = (unsigned*)(ws + 80 * MB);           // 16MB
  float* x_point = (float*)(ws + 96 * MB);                // 4MB
  unsigned short* Wc1th = (unsigned short*)(ws + 96 * MB);             // 1.5MB (x_point dead)
  unsigned short* Wc1tl = (unsigned short*)(ws + 96 * MB + 1536 * KB); // 1.5MB
  unsigned short* Wc2th = (unsigned short*)(ws + 99 * MB);             // 32KB
  unsigned short* Wc2tl = (unsigned short*)(ws + 99 * MB + 64 * KB);   // 32KB
  char* sm = ws + 100 * MB;
  float* es1 = (float*)(sm + 0);                 // 256KB
  float* ed1 = (float*)(sm + 256 * KB);          // 256KB
  float* e1 = (float*)(sm + 512 * KB);           // 320KB
  float* denom1 = (float*)(sm + 1088 * KB);      // 256KB
  float* es2 = (float*)(sm + 1344 * KB);         // 32KB
  float* ed2 = (float*)(sm + 1376 * KB);         // 32KB
  float* e2 = (float*)(sm + 1408 * KB);          // 40KB
  float* denom2 = (float*)(sm + 1480 * KB);      // 32KB
  int* flagL = (int*)(sm + 1512 * KB);           // 32KB
  int* flagR = (int*)(sm + 1544 * KB);           // 32KB
  float* padded = (float*)(ws + 106 * MB);                   // 384KB
  int* counts = (int*)(ws + 106 * MB + 384 * KB);            // 8KB
  float* W_eff = (float*)(ws + 106 * MB + 400 * KB);         // 48KB
  float* b_eff = (float*)(ws + 106 * MB + 448 * KB);         // 8KB
  int* starts_c = (int*)(ws + 106 * MB + 456 * KB);          // 8KB

  auto g64 = [&](const float* A, int lda, const float* B, int ldb, float* C, int ldc,
                 int M, int N, int K, const float* bias, int act) {
    dim3 grid((N + 63) / 64, (M + 63) / 64);
    gemm_t<64, 64><<<grid, 256, 0, stream>>>(A, lda, B, ldb, C, ldc, M, N, K, bias, act);
  };
  auto gm2 = [&](const unsigned short* Ah, const unsigned short* Al,
                 const unsigned short* Bth, const unsigned short* Btl, float* C,
                 int M, int N, int K, const float* bias, int act) {
    gemm_mfma2<<<(N / 128) * (M / 128), 512, 0, stream>>>(Ah, Al, Bth, Btl, C, M, N, K, bias,
                                                          act);
  };
  auto tsplit = [&](const float* W, unsigned short* th, unsigned short* tl, int K, int N) {
    tsplit_kernel<<<(K * N + 255) / 256, 256, 0, stream>>>(W, th, tl, K, N);
  };
  auto split = [&](const float* x, unsigned short* h, unsigned short* l, int n) {
    split_kernel<<<(n + 255) / 256, 256, 0, stream>>>(x, h, l, n);
  };

  // ===== PRE: effective weights (one fused prep kernel + W_eff GEMMs) =====
  g64(W_in, DM, W_inproj, 2 * DI, W_eff, 2 * DI, 6, 2 * DI, DM, nullptr, 0);
  g64(b_in, DM, W_inproj, 2 * DI, b_eff, 2 * DI, 1, 2 * DI, DM, nullptr, 0);
  prep1_kernel<<<PREP_TOT / 256, 256, 0, stream>>>(
      W_lout, W_outproj, A_log, W_xproj, W1, x_param,
      Wlth, Wltl, Woph, Wopl, negA, Wxth, Wxtl, W1th, W1tl, xph, xpl);
  hipMemsetAsync(WmixT, 0, (size_t)DM * DI * 4, stream);
  gemm_mfma_sk<<<dim3(DI / 64, DM / 64, 4), 256, 0, stream>>>(Wlth, Wltl, Woph, Wopl, WmixT,
                                                              DM, DI, DM);
  split(WmixT, Wmixth, Wmixtl, DM * DI);

  // ===== Mamba encoder =====
  hipMemsetAsync(padded, 0, (size_t)ROWS * 6 * 4, stream);
  scatter_padded_kernel<<<(NSYN + 255) / 256, 256, 0, stream>>>(synapse, sidx, padded);
  prefix_kernel<<<1, 256, 0, stream>>>(sidx, counts, starts_c);
  xc_compact_kernel<<<dim3(DI / 256, E_EDGES), 256, 0, stream>>>(
      padded, W_eff, b_eff, conv_w, conv_b, counts, starts_c, xc_ch, xc_cl);
  hipMemsetAsync(xdb_c, 0, (size_t)MC_CAP * 64 * 4, stream);
  gemm_mfma_sk<<<dim3(1, MC_CAP / 64, 8), 256, 0, stream>>>(xc_ch, xc_cl, Wxth, Wxtl, xdb_c,
                                                            MC_CAP, 64, DI);
  mamba_scan_pool_kernel<<<dim3(DI / 256, E_EDGES), 256, 0, stream>>>(
      xdb_c, padded, W_eff, b_eff, W_dt, b_dt, negA, Dv, conv_w, conv_b, counts, starts_c,
      pooledh, pooledl);
  hipMemsetAsync(x_point, 0, (size_t)E_EDGES * DM * 4, stream);
  gemm_mfma_sk<<<dim3(DM / 64, E_EDGES / 64, 4), 256, 0, stream>>>(pooledh, pooledl, Wmixth,
                                                                   Wmixtl, x_point, E_EDGES,
                                                                   DM, DI);

  // ===== GAT layer 1 =====
  gm2(xph, xpl, W1th, W1tl, xw1, N_NODES, HEADS * HID, F_IN, nullptr, 0);
  esed1_kernel<<<(N_NODES * HEADS) / 256, 256, 0, stream>>>(xw1, as1, ad1, es1, ed1);
  hipMemsetAsync(denom1, 0, 256 * KB, stream);
  edgeexp1_kernel<<<(TOT_EDGES * HEADS + 255) / 256, 256, 0, stream>>>(edge_index, es1, ed1,
                                                                       e1, denom1);
  selfinit1_kernel<<<(N_NODES * 512) / 256, 256, 0, stream>>>(e1, denom1, xw1, g1);
  agg1_kernel<<<E_EDGES, 256, 0, stream>>>(edge_index, e1, denom1, xw1, g1);
  elu_bias_split_kernel<<<(N_NODES * 512) / 256, 256, 0, stream>>>(g1, b1, g1h, g1l);

  // ===== GAT layer 2 =====
  tsplit(W2, W2th, W2tl, HEADS * HID, REP);  // stays here: W2th aliases xw1 (dead after agg1)
  gm2(g1h, g1l, W2th, W2tl, xw2, N_NODES, REP, HEADS * HID, nullptr, 0);
  esed2_kernel<<<N_NODES, 64, 0, stream>>>(xw2, as2, ad2, es2, ed2);
  hipMemsetAsync(denom2, 0, 96 * KB, stream);  // denom2 + flagL + flagR
  edgeexp2_kernel<<<(TOT_EDGES + 255) / 256, 256, 0, stream>>>(edge_index, es2, ed2, e2,
                                                               denom2);
  selfinit2_kernel<<<(N_NODES * 512) / 256, 256, 0, stream>>>(e2, denom2, xw2, g2);
  agg2_kernel<<<E_EDGES, 256, 0, stream>>>(edge_index, e2, denom2, xw2, g2);

  // ===== left/right segment max =====
  hipMemsetAsync(leftU, 0, 32 * MB, stream);  // leftU + rightU (contiguous)
  leftright_kernel<<<E_EDGES, 256, 0, stream>>>(edge_index, x_point, b_lout, leftU, rightU,
                                                flagL, flagR);

  // ===== classifier =====
  concat_split_kernel<<<(N_NODES * 512) / 256, 256, 0, stream>>>(g2, b2, leftU, rightU, flagL,
                                                                 flagR, featsh, featsl);
  tsplit(Wc1, Wc1th, Wc1tl, REP + 2 * DM, 512);  // stays: aliases x_point (dead after leftright)
  tsplit(Wc2, Wc2th, Wc2tl, 512, NCLS);
  gm2(featsh, featsl, Wc1th, Wc1tl, hidden, N_NODES, 512, REP + 2 * DM, bc1, 1);
  gemm_thin32<0><<<N_NODES / 64, 256, 0, stream>>>(hidden, Wc2th, Wc2tl, out, N_NODES, bc2);
}

// Round 22
// 412.379 us; speedup vs baseline: 1.1018x; 1.0077x over previous
//
#include <hip/hip_runtime.h>

#define N_NODES 8192
#define F_IN 128
#define HID 64
#define HEADS 8
#define REP 512
#define NCLS 32
#define E_EDGES 2048
#define NSYN 4096
#define LMAX 8
#define DM 512
#define DI 1024
#define DSTATE 16
#define DCONV 4
#define DTR 32
#define TOT_EDGES (E_EDGES + N_NODES) /* 10240 */
#define ROWS (E_EDGES * LMAX)         /* 16384 */
#define MC_CAP 6144                   /* >= sum(min(max(cnt,1),8)) */

typedef short bf16x8 __attribute__((ext_vector_type(8)));
typedef float f32x4 __attribute__((ext_vector_type(4)));

// ---------- helpers ----------
__device__ __forceinline__ unsigned mapf(float f) {
  unsigned u = __float_as_uint(f);
  return (u & 0x80000000u) ? ~u : (u | 0x80000000u);
}
__device__ __forceinline__ float unmapf(unsigned u) {
  return __uint_as_float((u & 0x80000000u) ? (u ^ 0x80000000u) : ~u);
}
__device__ __forceinline__ float fsig(float x) {
  return __builtin_amdgcn_rcpf(1.0f + __expf(-x));
}
__device__ __forceinline__ float fsoftplus(float x) {
  return fmaxf(x, 0.0f) + __logf(1.0f + __expf(-fabsf(x)));
}
__device__ __forceinline__ unsigned short f2bf(float f) {
  unsigned u = __float_as_uint(f);
  unsigned r = (u + 0x7FFFu + ((u >> 16) & 1u)) >> 16;
  return (unsigned short)r;
}
__device__ __forceinline__ float bf2f(unsigned short h) {
  return __uint_as_float(((unsigned)h) << 16);
}
__device__ __forceinline__ void split2(float x, unsigned short* hh, unsigned short* ll) {
  unsigned short h = f2bf(x);
  *hh = h;
  *ll = f2bf(x - bf2f(h));
}
__device__ __forceinline__ int lower_bound_dev(const int* __restrict__ arr, int n, int v) {
  int lo = 0, hi = n;
  while (lo < hi) { int mid = (lo + hi) >> 1; if (arr[mid] < v) lo = mid + 1; else hi = mid; }
  return lo;
}
__device__ __forceinline__ int src_of(const int* __restrict__ ei, int i) {
  return i < E_EDGES ? ei[i] : i - E_EDGES;
}
__device__ __forceinline__ int dst_of(const int* __restrict__ ei, int i) {
  return i < E_EDGES ? ei[E_EDGES + i] : i - E_EDGES;
}
__device__ __forceinline__ int clip_cnt(int c) { return c < 1 ? 1 : (c > LMAX ? LMAX : c); }

// ---------- MFMA split-bf16 GEMM, 128x128 tile, 512 threads (8 waves, 2/SIMD) ----------
// band-major remap + 1-deep reg prefetch (the measured optimum; 6 structural variants
// -- wave shape, tile size, remap, split-K x2, 2-deep prefetch -- all regressed).
__global__ __launch_bounds__(512) void gemm_mfma2(
    const unsigned short* __restrict__ Ah, const unsigned short* __restrict__ Al,
    const unsigned short* __restrict__ Bth, const unsigned short* __restrict__ Btl,
    float* __restrict__ C, int M, int N, int K,
    const float* __restrict__ bias, int act) {
  __shared__ __align__(16) unsigned short As[2][128][40];
  __shared__ __align__(16) unsigned short Bs[2][128][40];
  const int tid = threadIdx.x;
  const int w = tid >> 6;
  const int lane = tid & 63;
  const int wr = w >> 2, wc = w & 3;  // 2x4 wave grid; wave tile 64x32
  const int mb = M >> 7;
  const int lin = blockIdx.x;
  const int bx = lin / mb;
  const int by = lin % mb;
  const int brow = by * 128;
  const int bcol = bx * 128;
  const int r0 = lane & 15;
  const int kg = lane >> 4;
  const int row0 = tid >> 2, kc0 = tid & 3;
  const size_t a0 = (size_t)(brow + row0) * K + kc0 * 8;
  const size_t b0 = (size_t)(bcol + row0) * K + kc0 * 8;
  f32x4 acc[4][2] = {};
  {
    bf16x8 t0 = *(const bf16x8*)(Ah + a0), t1 = *(const bf16x8*)(Al + a0);
    bf16x8 t2 = *(const bf16x8*)(Bth + b0), t3 = *(const bf16x8*)(Btl + b0);
    *(bf16x8*)(&As[0][row0][kc0 * 8]) = t0;
    *(bf16x8*)(&As[1][row0][kc0 * 8]) = t1;
    *(bf16x8*)(&Bs[0][row0][kc0 * 8]) = t2;
    *(bf16x8*)(&Bs[1][row0][kc0 * 8]) = t3;
  }
  __syncthreads();
  for (int kt = 0; kt < K; kt += 32) {
    const bool more = (kt + 32) < K;
    bf16x8 p0, p1, p2, p3;
    if (more) {  // next-tile loads land during fragment reads + MFMA
      p0 = *(const bf16x8*)(Ah + a0 + kt + 32);
      p1 = *(const bf16x8*)(Al + a0 + kt + 32);
      p2 = *(const bf16x8*)(Bth + b0 + kt + 32);
      p3 = *(const bf16x8*)(Btl + b0 + kt + 32);
    }
    bf16x8 bhv[2], blv[2];
#pragma unroll
    for (int cf = 0; cf < 2; ++cf) {
      bhv[cf] = *(const bf16x8*)(&Bs[0][wc * 32 + cf * 16 + r0][kg * 8]);
      blv[cf] = *(const bf16x8*)(&Bs[1][wc * 32 + cf * 16 + r0][kg * 8]);
    }
#pragma unroll
    for (int rf = 0; rf < 4; ++rf) {
      bf16x8 ah = *(const bf16x8*)(&As[0][wr * 64 + rf * 16 + r0][kg * 8]);
      bf16x8 al = *(const bf16x8*)(&As[1][wr * 64 + rf * 16 + r0][kg * 8]);
#pragma unroll
      for (int cf = 0; cf < 2; ++cf) {
        acc[rf][cf] = __builtin_amdgcn_mfma_f32_16x16x32_bf16(ah, bhv[cf], acc[rf][cf], 0, 0, 0);
        acc[rf][cf] = __builtin_amdgcn_mfma_f32_16x16x32_bf16(ah, blv[cf], acc[rf][cf], 0, 0, 0);
        acc[rf][cf] = __builtin_amdgcn_mfma_f32_16x16x32_bf16(al, bhv[cf], acc[rf][cf], 0, 0, 0);
      }
    }
    __syncthreads();
    if (more) {
      *(bf16x8*)(&As[0][row0][kc0 * 8]) = p0;
      *(bf16x8*)(&As[1][row0][kc0 * 8]) = p1;
      *(bf16x8*)(&Bs[0][row0][kc0 * 8]) = p2;
      *(bf16x8*)(&Bs[1][row0][kc0 * 8]) = p3;
    }
    __syncthreads();
  }
#pragma unroll
  for (int rf = 0; rf < 4; ++rf)
#pragma unroll
    for (int cf = 0; cf < 2; ++cf) {
      int col = bcol + wc * 32 + cf * 16 + r0;
      float bb = bias ? bias[col] : 0.0f;
#pragma unroll
      for (int j = 0; j < 4; ++j) {
        int row = brow + wr * 64 + rf * 16 + kg * 4 + j;
        float v = acc[rf][cf][j] + bb;
        if (act == 1) v = fmaxf(v, 0.0f);
        C[(size_t)row * N + col] = v;
      }
    }
}

// ---------- split-K variant (64x64): partial K range per blockIdx.z, atomicAdd output ----------
__global__ __launch_bounds__(256) void gemm_mfma_sk(
    const unsigned short* __restrict__ Ah, const unsigned short* __restrict__ Al,
    const unsigned short* __restrict__ Bth, const unsigned short* __restrict__ Btl,
    float* __restrict__ C, int M, int N, int K) {
  __shared__ __align__(16) unsigned short As[2][64][40];
  const int tid = threadIdx.x;
  const int w = tid >> 6;
  const int lane = tid & 63;
  const int brow = blockIdx.y * 64;
  const int bcol = blockIdx.x * 64;
  const int srow = tid >> 2;
  const int skc = tid & 3;
  const int r0 = lane & 15;
  const int kg = lane >> 4;
  const int kchunk = K / gridDim.z;
  const int k0 = blockIdx.z * kchunk;
  f32x4 acc[4] = {};
  const size_t aoff = (size_t)(brow + srow) * K;
  const size_t boff = (size_t)(bcol + w * 16 + r0) * K + kg * 8;
  for (int kt = k0; kt < k0 + kchunk; kt += 32) {
    bf16x8 bh = *(const bf16x8*)(Bth + boff + kt);
    bf16x8 bl = *(const bf16x8*)(Btl + boff + kt);
    *(bf16x8*)(&As[0][srow][skc * 8]) = *(const bf16x8*)(Ah + aoff + kt + skc * 8);
    *(bf16x8*)(&As[1][srow][skc * 8]) = *(const bf16x8*)(Al + aoff + kt + skc * 8);
    __syncthreads();
#pragma unroll
    for (int r = 0; r < 4; ++r) {
      bf16x8 ah = *(const bf16x8*)(&As[0][r * 16 + r0][kg * 8]);
      bf16x8 al = *(const bf16x8*)(&As[1][r * 16 + r0][kg * 8]);
      acc[r] = __builtin_amdgcn_mfma_f32_16x16x32_bf16(ah, bh, acc[r], 0, 0, 0);
      acc[r] = __builtin_amdgcn_mfma_f32_16x16x32_bf16(ah, bl, acc[r], 0, 0, 0);
      acc[r] = __builtin_amdgcn_mfma_f32_16x16x32_bf16(al, bh, acc[r], 0, 0, 0);
    }
    __syncthreads();
  }
  const int col = bcol + w * 16 + r0;
#pragma unroll
  for (int r = 0; r < 4; ++r) {
#pragma unroll
    for (int j = 0; j < 4; ++j) {
      int row = brow + r * 16 + kg * 4 + j;
      atomicAdd(&C[(size_t)row * N + col], acc[r][j]);
    }
  }
}

// ---------- thin MFMA GEMM: C(Mx32) = relu(A32)(Mx512) @ Bt(32x512)^T + bias ----------
template <int APPLY_RELU>
__global__ __launch_bounds__(256) void gemm_thin32(
    const float* __restrict__ A32,
    const unsigned short* __restrict__ Bth, const unsigned short* __restrict__ Btl,
    float* __restrict__ C, int M, const float* __restrict__ bias) {
  const int tid = threadIdx.x;
  const int w = tid >> 6;
  const int lane = tid & 63;
  const int r0 = lane & 15;
  const int kg = lane >> 4;
  const int rowbase = blockIdx.x * 64 + w * 16;
  f32x4 acc[2] = {};
  const float* arow = A32 + (size_t)(rowbase + r0) * 512 + kg * 8;
  for (int kt = 0; kt < 512; kt += 32) {
    float4 f0 = *(const float4*)(arow + kt);
    float4 f1 = *(const float4*)(arow + kt + 4);
    float v[8] = {f0.x, f0.y, f0.z, f0.w, f1.x, f1.y, f1.z, f1.w};
    bf16x8 ah, al;
#pragma unroll
    for (int j = 0; j < 8; ++j) {
      float vv = APPLY_RELU ? fmaxf(v[j], 0.0f) : v[j];
      unsigned short hh, ll;
      split2(vv, &hh, &ll);
      ah[j] = (short)hh;
      al[j] = (short)ll;
    }
#pragma unroll
    for (int cf = 0; cf < 2; ++cf) {
      bf16x8 bh = *(const bf16x8*)(Bth + (size_t)(cf * 16 + r0) * 512 + kt + kg * 8);
      bf16x8 bl = *(const bf16x8*)(Btl + (size_t)(cf * 16 + r0) * 512 + kt + kg * 8);
      acc[cf] = __builtin_amdgcn_mfma_f32_16x16x32_bf16(ah, bh, acc[cf], 0, 0, 0);
      acc[cf] = __builtin_amdgcn_mfma_f32_16x16x32_bf16(ah, bl, acc[cf], 0, 0, 0);
      acc[cf] = __builtin_amdgcn_mfma_f32_16x16x32_bf16(al, bh, acc[cf], 0, 0, 0);
    }
  }
#pragma unroll
  for (int cf = 0; cf < 2; ++cf) {
    int col = cf * 16 + r0;
    float bb = bias[col];
#pragma unroll
    for (int j = 0; j < 4; ++j) {
      int row = rowbase + kg * 4 + j;
      C[(size_t)row * 32 + col] = acc[cf][j] + bb;
    }
  }
}

// ---------- split / transpose-split ----------
__global__ void split_kernel(const float* __restrict__ x, unsigned short* __restrict__ h,
                             unsigned short* __restrict__ l, int n) {
  int i = blockIdx.x * 256 + threadIdx.x;
  if (i >= n) return;
  split2(x[i], &h[i], &l[i]);
}

__global__ void tsplit_kernel(const float* __restrict__ W, unsigned short* __restrict__ Wth,
                              unsigned short* __restrict__ Wtl, int K, int N) {
  int i = blockIdx.x * 256 + threadIdx.x;
  if (i >= K * N) return;
  int k = i / N, n = i - k * N;
  float v = W[i];
  unsigned short h = f2bf(v);
  Wth[(size_t)n * K + k] = h;
  Wtl[(size_t)n * K + k] = f2bf(v - bf2f(h));
}

// ---------- fused weight-prep: tsplit Wl / split Wop / negA / tsplit Wx / tsplit W1 / split xp ----------
#define PREP_SEG0 262144   /* tsplit W_lout 512x512 */
#define PREP_SEG1 524288   /* split W_outproj */
#define PREP_SEG2 16384    /* negA */
#define PREP_SEG3 65536    /* tsplit W_xproj 1024x64 */
#define PREP_SEG4 65536    /* tsplit W1 128x512 */
#define PREP_SEG5 1048576  /* split x_param */
#define PREP_TOT (PREP_SEG0 + PREP_SEG1 + PREP_SEG2 + PREP_SEG3 + PREP_SEG4 + PREP_SEG5)
__global__ void prep1_kernel(
    const float* __restrict__ W_lout, const float* __restrict__ W_outproj,
    const float* __restrict__ A_log, const float* __restrict__ W_xproj,
    const float* __restrict__ W1, const float* __restrict__ x_param,
    unsigned short* __restrict__ Wlth, unsigned short* __restrict__ Wltl,
    unsigned short* __restrict__ Woph, unsigned short* __restrict__ Wopl,
    float* __restrict__ negA,
    unsigned short* __restrict__ Wxth, unsigned short* __restrict__ Wxtl,
    unsigned short* __restrict__ W1th, unsigned short* __restrict__ W1tl,
    unsigned short* __restrict__ xph, unsigned short* __restrict__ xpl) {
  int i = blockIdx.x * 256 + threadIdx.x;
  if (i < PREP_SEG0) {
    int k = i >> 9, n = i & 511;
    float v = W_lout[i];
    unsigned short h = f2bf(v);
    Wlth[(size_t)n * 512 + k] = h;
    Wltl[(size_t)n * 512 + k] = f2bf(v - bf2f(h));
    return;
  }
  i -= PREP_SEG0;
  if (i < PREP_SEG1) { split2(W_outproj[i], &Woph[i], &Wopl[i]); return; }
  i -= PREP_SEG1;
  if (i < PREP_SEG2) { negA[i] = -__expf(A_log[i]); return; }
  i -= PREP_SEG2;
  if (i < PREP_SEG3) {
    int k = i >> 6, n = i & 63;
    float v = W_xproj[i];
    unsigned short h = f2bf(v);
    Wxth[(size_t)n * 1024 + k] = h;
    Wxtl[(size_t)n * 1024 + k] = f2bf(v - bf2f(h));
    return;
  }
  i -= PREP_SEG3;
  if (i < PREP_SEG4) {
    int k = i >> 9, n = i & 511;
    float v = W1[i];
    unsigned short h = f2bf(v);
    W1th[(size_t)n * 128 + k] = h;
    W1tl[(size_t)n * 128 + k] = f2bf(v - bf2f(h));
    return;
  }
  i -= PREP_SEG4;
  if (i < PREP_SEG5) { split2(x_param[i], &xph[i], &xpl[i]); }
}

// ---------- tiled f32 GEMM (small shapes) ----------
template <int BM, int BN>
__global__ __launch_bounds__(256) void gemm_t(
    const float* __restrict__ A, int lda,
    const float* __restrict__ B, int ldb,
    float* __restrict__ C, int ldc,
    int M, int N, int K,
    const float* __restrict__ bias, int act) {
  constexpr int RR = BM / 64;
  constexpr int CR = BN / 64;
  __shared__ float As[16][BM + 4];
  __shared__ float Bs[16][BN + 4];
  const int tid = threadIdx.x;
  const int tx = tid & 15;
  const int ty = tid >> 4;
  const int brow = blockIdx.y * BM;
  const int bcol = blockIdx.x * BN;
  float acc[RR][CR][4][4] = {};
  for (int kt = 0; kt < K; kt += 16) {
#pragma unroll
    for (int p = 0; p < RR; ++p) {
      int c = tid + p * 256;
      int row = c >> 2, kc = c & 3;
      int gr = brow + row;
      float4 v = make_float4(0.f, 0.f, 0.f, 0.f);
      if (gr < M) v = *reinterpret_cast<const float4*>(A + (size_t)gr * lda + kt + kc * 4);
      As[kc * 4 + 0][row] = v.x;
      As[kc * 4 + 1][row] = v.y;
      As[kc * 4 + 2][row] = v.z;
      As[kc * 4 + 3][row] = v.w;
    }
#pragma unroll
    for (int p = 0; p < CR; ++p) {
      int c = tid + p * 256;
      int k = c / (BN / 4), c4 = c % (BN / 4);
      int gc = bcol + c4 * 4;
      float4 v = make_float4(0.f, 0.f, 0.f, 0.f);
      if (gc < N) v = *reinterpret_cast<const float4*>(B + (size_t)(kt + k) * ldb + gc);
      *reinterpret_cast<float4*>(&Bs[k][c4 * 4]) = v;
    }
    __syncthreads();
#pragma unroll
    for (int k = 0; k < 16; ++k) {
      float av[RR * 4], bv[CR * 4];
#pragma unroll
      for (int r = 0; r < RR; ++r) {
        float4 t = *reinterpret_cast<const float4*>(&As[k][r * 64 + ty * 4]);
        av[r * 4 + 0] = t.x; av[r * 4 + 1] = t.y; av[r * 4 + 2] = t.z; av[r * 4 + 3] = t.w;
      }
#pragma unroll
      for (int cq = 0; cq < CR; ++cq) {
        float4 t = *reinterpret_cast<const float4*>(&Bs[k][cq * 64 + tx * 4]);
        bv[cq * 4 + 0] = t.x; bv[cq * 4 + 1] = t.y; bv[cq * 4 + 2] = t.z; bv[cq * 4 + 3] = t.w;
      }
#pragma unroll
      for (int r = 0; r < RR; ++r)
#pragma unroll
        for (int cq = 0; cq < CR; ++cq)
#pragma unroll
          for (int i = 0; i < 4; ++i)
#pragma unroll
            for (int j = 0; j < 4; ++j)
              acc[r][cq][i][j] = fmaf(av[r * 4 + i], bv[cq * 4 + j], acc[r][cq][i][j]);
    }
    __syncthreads();
  }
#pragma unroll
  for (int r = 0; r < RR; ++r)
#pragma unroll
    for (int i = 0; i < 4; ++i) {
      int row = brow + r * 64 + ty * 4 + i;
      if (row >= M) continue;
#pragma unroll
      for (int cq = 0; cq < CR; ++cq) {
        int col = bcol + cq * 64 + tx * 4;
        if (col >= N) continue;
        float4 v;
        v.x = acc[r][cq][i][0]; v.y = acc[r][cq][i][1];
        v.z = acc[r][cq][i][2]; v.w = acc[r][cq][i][3];
        if (bias) {
          float4 bb = *reinterpret_cast<const float4*>(bias + col);
          v.x += bb.x; v.y += bb.y; v.z += bb.z; v.w += bb.w;
        }
        if (act == 1) {
          v.x = fmaxf(v.x, 0.f); v.y = fmaxf(v.y, 0.f);
          v.z = fmaxf(v.z, 0.f); v.w = fmaxf(v.w, 0.f);
        }
        *reinterpret_cast<float4*>(C + (size_t)row * ldc + col) = v;
      }
    }
}

// ---------- mamba: pad/scatter + fused counts+prefix ----------
__global__ void scatter_padded_kernel(const float* __restrict__ synapse,
                                      const int* __restrict__ sidx,
                                      float* __restrict__ padded) {
  int i = blockIdx.x * 256 + threadIdx.x;
  if (i >= NSYN) return;
  int e = sidx[i];
  int lo = lower_bound_dev(sidx, NSYN, e);
  int pos = i - lo;
  if (pos < LMAX) {
#pragma unroll
    for (int c = 0; c < 6; ++c) padded[((size_t)e * LMAX + pos) * 6 + c] = synapse[(size_t)i * 6 + c];
  }
}

// counts + exclusive prefix over clipped counts -> starts_c (one block, 256 threads x 8)
__global__ __launch_bounds__(256) void prefix_kernel(const int* __restrict__ sidx,
                                                     int* __restrict__ counts,
                                                     int* __restrict__ starts_c) {
  __shared__ int part[256];
  int t = threadIdx.x;
  int loc[8];
  int s = 0;
  int lo = lower_bound_dev(sidx, NSYN, t * 8);
#pragma unroll
  for (int i = 0; i < 8; ++i) {
    int hi = lower_bound_dev(sidx, NSYN, t * 8 + i + 1);
    int c = hi - lo;
    counts[t * 8 + i] = c;
    lo = hi;
    c = clip_cnt(c);
    loc[i] = s;
    s += c;
  }
  part[t] = s;
  __syncthreads();
  int mytot = s;
  for (int o = 1; o < 256; o <<= 1) {
    int add = (t >= o) ? part[t - o] : 0;
    __syncthreads();
    part[t] += add;
    __syncthreads();
  }
  int off = part[t] - mytot;
#pragma unroll
  for (int i = 0; i < 8; ++i) starts_c[t * 8 + i] = off + loc[i];
}

// ---------- mamba: compact xc = silu(conv(padded@W_eff)) -> bf16 h/l ----------
__global__ __launch_bounds__(256) void xc_compact_kernel(
    const float* __restrict__ padded,
    const float* __restrict__ W_eff, const float* __restrict__ b_eff,
    const float* __restrict__ conv_w, const float* __restrict__ conv_b,
    const int* __restrict__ counts, const int* __restrict__ starts_c,
    unsigned short* __restrict__ xch, unsigned short* __restrict__ xcl) {
  __shared__ float pads[LMAX * 6];
  int t = threadIdx.x;
  int d = blockIdx.x * 256 + t;
  int e = blockIdx.y;
  if (t < LMAX * 6) pads[t] = padded[(size_t)e * LMAX * 6 + t];
  __syncthreads();
  int cnt = clip_cnt(counts[e]);
  int sc = starts_c[e];
  float wef[6];
#pragma unroll
  for (int c = 0; c < 6; ++c) wef[c] = W_eff[c * 2048 + d];
  float cw0 = conv_w[d * 4 + 0], cw1 = conv_w[d * 4 + 1];
  float cw2 = conv_w[d * 4 + 2], cw3 = conv_w[d * 4 + 3];
  float cb = conv_b[d], be = b_eff[d];
  float x0 = 0.f, x1 = 0.f, x2 = 0.f;
  for (int l = 0; l < cnt; ++l) {
    float xm = be;
#pragma unroll
    for (int c = 0; c < 6; ++c) xm += pads[l * 6 + c] * wef[c];
    float s0 = cb + xm * cw3;
    if (l >= 1) s0 += x2 * cw2;
    if (l >= 2) s0 += x1 * cw1;
    if (l >= 3) s0 += x0 * cw0;
    float v = s0 * fsig(s0);
    size_t o = (size_t)(sc + l) * DI + d;
    split2(v, &xch[o], &xcl[o]);
    x0 = x1; x1 = x2; x2 = xm;
  }
}

// ---------- mamba: scan with LDS-staged xdb rows (broadcast reads) ----------
__global__ __launch_bounds__(256) void mamba_scan_pool_kernel(
    const float* __restrict__ xdb_c, const float* __restrict__ padded,
    const float* __restrict__ W_eff, const float* __restrict__ b_eff,
    const float* __restrict__ W_dt, const float* __restrict__ b_dt,
    const float* __restrict__ negA, const float* __restrict__ Dv,
    const float* __restrict__ conv_w, const float* __restrict__ conv_b,
    const int* __restrict__ counts, const int* __restrict__ starts_c,
    unsigned short* __restrict__ pooledh, unsigned short* __restrict__ pooledl) {
  __shared__ float pads[LMAX * 6];
  __shared__ float rows[LMAX * 64];  // staged xdb rows (2KB)
  int t = threadIdx.x;
  int d = blockIdx.x * 256 + t;
  int e = blockIdx.y;
  int cnt = clip_cnt(counts[e]);
  int sc = starts_c[e];
  if (t < LMAX * 6) pads[t] = padded[(size_t)e * LMAX * 6 + t];
  for (int i = t; i < cnt * 64; i += 256) rows[i] = xdb_c[(size_t)sc * 64 + i];
  float wdt[DTR];
#pragma unroll
  for (int k = 0; k < DTR; ++k) wdt[k] = W_dt[k * DI + d];
  float a[DSTATE];
#pragma unroll
  for (int n = 0; n < DSTATE; ++n) a[n] = negA[d * DSTATE + n];
  float h[DSTATE];
#pragma unroll
  for (int n = 0; n < DSTATE; ++n) h[n] = 0.0f;
  float wef[6], wez[6];
#pragma unroll
  for (int c = 0; c < 6; ++c) {
    wef[c] = W_eff[c * 2048 + d];
    wez[c] = W_eff[c * 2048 + DI + d];
  }
  float cw0 = conv_w[d * 4 + 0], cw1 = conv_w[d * 4 + 1];
  float cw2 = conv_w[d * 4 + 2], cw3 = conv_w[d * 4 + 3];
  float cb = conv_b[d];
  float bdt = b_dt[d], Dd = Dv[d], be = b_eff[d], bez = b_eff[DI + d];
  __syncthreads();
  float x0 = 0.f, x1 = 0.f, x2 = 0.f;
  float ssum = 0.0f;
  for (int l = 0; l < cnt; ++l) {
    float xm = be;
#pragma unroll
    for (int c = 0; c < 6; ++c) xm += pads[l * 6 + c] * wef[c];
    float s0 = cb + xm * cw3;
    if (l >= 1) s0 += x2 * cw2;
    if (l >= 2) s0 += x1 * cw1;
    if (l >= 3) s0 += x0 * cw0;
    float xt = s0 * fsig(s0);
    const float* __restrict__ xrow = &rows[l * 64];
    float acc = bdt;
#pragma unroll
    for (int k = 0; k < DTR; ++k) acc += xrow[k] * wdt[k];
    float dt = fsoftplus(acc);
    float dtx = dt * xt;
    float y = 0.0f;
#pragma unroll
    for (int n = 0; n < DSTATE; ++n) {
      float en = __expf(dt * a[n]);
      h[n] = en * h[n] + dtx * xrow[32 + n];
      y += h[n] * xrow[48 + n];
    }
    y += Dd * xt;
    float z = bez;
#pragma unroll
    for (int c = 0; c < 6; ++c) z += pads[l * 6 + c] * wez[c];
    ssum += y * z * fsig(z);
    x0 = x1; x1 = x2; x2 = xm;
  }
  float pv = ssum / (float)cnt;
  split2(pv, &pooledh[(size_t)e * DI + d], &pooledl[(size_t)e * DI + d]);
}

// ---------- GAT layer 1 ----------
__global__ void esed1_kernel(const float* __restrict__ xw1, const float* __restrict__ as1,
                             const float* __restrict__ ad1, float* __restrict__ es1,
                             float* __restrict__ ed1) {
  int idx = blockIdx.x * 256 + threadIdx.x;  // N_NODES*HEADS
  int n = idx >> 3, h = idx & 7;
  const float* xr = xw1 + (size_t)n * 512 + h * 64;
  const float* sr = as1 + h * 64;
  const float* dr = ad1 + h * 64;
  float es = 0.0f, ed = 0.0f;
#pragma unroll
  for (int c = 0; c < 64; ++c) { float v = xr[c]; es += v * sr[c]; ed += v * dr[c]; }
  es1[idx] = es; ed1[idx] = ed;
}

// fused edge score + exp (no max-subtraction: |e| <~ 0.2, exp exact in fp32)
__global__ void edgeexp1_kernel(const int* __restrict__ ei, const float* __restrict__ es1,
                                const float* __restrict__ ed1, float* __restrict__ e1,
                                float* __restrict__ denom1) {
  int idx = blockIdx.x * 256 + threadIdx.x;
  if (idx >= TOT_EDGES * HEADS) return;
  int i = idx >> 3, h = idx & 7;
  int s = src_of(ei, i), d = dst_of(ei, i);
  float v = es1[s * 8 + h] + ed1[d * 8 + h];
  v = v >= 0.0f ? v : 0.2f * v;
  float ex = expf(v);
  e1[idx] = ex;
  atomicAdd(denom1 + d * 8 + h, ex);
}

// init g1 with the self-loop contribution (replaces memset; self edge id = E_EDGES + n)
__global__ void selfinit1_kernel(const float* __restrict__ e1, const float* __restrict__ denom1,
                                 const float* __restrict__ xw1, float* __restrict__ g1) {
  int idx = blockIdx.x * 256 + threadIdx.x;  // N_NODES*512
  int n = idx >> 9, j = idx & 511;
  int h = j >> 6;
  float alpha = e1[(size_t)(E_EDGES + n) * 8 + h] / denom1[n * 8 + h];
  g1[idx] = alpha * xw1[idx];
}

__global__ __launch_bounds__(256) void agg1_kernel(const int* __restrict__ ei,
                                                   const float* __restrict__ e1,
                                                   const float* __restrict__ denom1,
                                                   const float* __restrict__ xw1,
                                                   float* __restrict__ g1) {
  int i = blockIdx.x;  // real edges only
  int s = ei[i], d = ei[E_EDGES + i];
  for (int j = threadIdx.x; j < 512; j += 256) {
    int h = j >> 6;
    float alpha = e1[i * 8 + h] / denom1[d * 8 + h];
    atomicAdd(g1 + (size_t)d * 512 + j, alpha * xw1[(size_t)s * 512 + j]);
  }
}

__global__ void elu_bias_split_kernel(const float* __restrict__ g1, const float* __restrict__ b1,
                                      unsigned short* __restrict__ g1h,
                                      unsigned short* __restrict__ g1l) {
  int idx = blockIdx.x * 256 + threadIdx.x;  // N_NODES*512
  int j = idx & 511;
  float v = g1[idx] + b1[j];
  v = v > 0.0f ? v : expm1f(v);
  split2(v, &g1h[idx], &g1l[idx]);
}

// ---------- GAT layer 2 ----------
__global__ __launch_bounds__(64) void esed2_kernel(const float* __restrict__ xw2,
                                                   const float* __restrict__ as2,
                                                   const float* __restrict__ ad2,
                                                   float* __restrict__ es2,
                                                   float* __restrict__ ed2) {
  int n = blockIdx.x, t = threadIdx.x;
  float es = 0.0f, ed = 0.0f;
  for (int c = t; c < 512; c += 64) {
    float v = xw2[(size_t)n * 512 + c];
    es += v * as2[c]; ed += v * ad2[c];
  }
#pragma unroll
  for (int o = 32; o > 0; o >>= 1) { es += __shfl_down(es, o, 64); ed += __shfl_down(ed, o, 64); }
  if (t == 0) { es2[n] = es; ed2[n] = ed; }
}

__global__ void edgeexp2_kernel(const int* __restrict__ ei, const float* __restrict__ es2,
                                const float* __restrict__ ed2, float* __restrict__ e2,
                                float* __restrict__ denom2) {
  int i = blockIdx.x * 256 + threadIdx.x;
  if (i >= TOT_EDGES) return;
  int s = src_of(ei, i), d = dst_of(ei, i);
  float v = es2[s] + ed2[d];
  v = v >= 0.0f ? v : 0.2f * v;
  float ex = expf(v);
  e2[i] = ex;
  atomicAdd(denom2 + d, ex);
}

__global__ void selfinit2_kernel(const float* __restrict__ e2, const float* __restrict__ denom2,
                                 const float* __restrict__ xw2, float* __restrict__ g2) {
  int idx = blockIdx.x * 256 + threadIdx.x;  // N_NODES*512
  int n = idx >> 9;
  float alpha = e2[E_EDGES + n] / denom2[n];
  g2[idx] = alpha * xw2[idx];
}

__global__ __launch_bounds__(256) void agg2_kernel(const int* __restrict__ ei,
                                                   const float* __restrict__ e2,
                                                   const float* __restrict__ denom2,
                                                   const float* __restrict__ xw2,
                                                   float* __restrict__ g2) {
  int i = blockIdx.x;  // real edges only
  int s = ei[i], d = ei[E_EDGES + i];
  float alpha = e2[i] / denom2[d];
  for (int j = threadIdx.x; j < 512; j += 256) {
    atomicAdd(g2 + (size_t)d * 512 + j, alpha * xw2[(size_t)s * 512 + j]);
  }
}

// ---------- scatter segment-max (adds b_lout bias on the fly) ----------
__global__ __launch_bounds__(256) void leftright_kernel(const int* __restrict__ ei,
                                                        const float* __restrict__ xp,
                                                        const float* __restrict__ b_lout,
                                                        unsigned* __restrict__ leftU,
                                                        unsigned* __restrict__ rightU,
                                                        int* __restrict__ flagL,
                                                        int* __restrict__ flagR) {
  int i = blockIdx.x;  // E_EDGES
  int s = ei[i], d = ei[E_EDGES + i];
  if (threadIdx.x == 0) { flagL[s] = 1; flagR[d] = 1; }
  for (int j = threadIdx.x; j < 512; j += 256) {
    unsigned v = mapf(xp[(size_t)i * 512 + j] + b_lout[j]);
    atomicMax(leftU + (size_t)s * 512 + j, v);
    atomicMax(rightU + (size_t)d * 512 + j, v);
  }
}

// ---------- feats = [g2+b2, left, right] -> bf16 h/l ----------
__global__ void concat_split_kernel(const float* __restrict__ g2, const float* __restrict__ b2,
                                    const unsigned* __restrict__ leftU,
                                    const unsigned* __restrict__ rightU,
                                    const int* __restrict__ flagL, const int* __restrict__ flagR,
                                    unsigned short* __restrict__ fh,
                                    unsigned short* __restrict__ fl) {
  int idx = blockIdx.x * 256 + threadIdx.x;  // N_NODES*512
  int n = idx >> 9, j = idx & 511;
  size_t base = (size_t)n * 1536 + j;
  split2(g2[idx] + b2[j], &fh[base], &fl[base]);
  split2(flagL[n] ? unmapf(leftU[idx]) : 0.0f, &fh[base + 512], &fl[base + 512]);
  split2(flagR[n] ? unmapf(rightU[idx]) : 0.0f, &fh[base + 1024], &fl[base + 1024]);
}

// ---------- launch ----------
extern "C" void kernel_launch(void* const* d_in, const int* in_sizes, int n_in,
                              void* d_out, int out_size, void* d_ws, size_t ws_size,
                              hipStream_t stream) {
  const float* synapse = (const float*)d_in[1];
  const float* x_param = (const float*)d_in[2];
  const float* W1 = (const float*)d_in[3];
  const float* as1 = (const float*)d_in[4];
  const float* ad1 = (const float*)d_in[5];
  const float* b1 = (const float*)d_in[6];
  const float* W2 = (const float*)d_in[7];
  const float* as2 = (const float*)d_in[8];
  const float* ad2 = (const float*)d_in[9];
  const float* b2 = (const float*)d_in[10];
  const float* W_in = (const float*)d_in[11];
  const float* b_in = (const float*)d_in[12];
  const float* W_inproj = (const float*)d_in[13];
  const float* conv_w = (const float*)d_in[14];
  const float* conv_b = (const float*)d_in[15];
  const float* W_xproj = (const float*)d_in[16];
  const float* W_dt = (const float*)d_in[17];
  const float* b_dt = (const float*)d_in[18];
  const float* A_log = (const float*)d_in[19];
  const float* Dv = (const float*)d_in[20];
  const float* W_outproj = (const float*)d_in[21];
  const float* W_lout = (const float*)d_in[22];
  const float* b_lout = (const float*)d_in[23];
  const float* Wc1 = (const float*)d_in[24];
  const float* bc1 = (const float*)d_in[25];
  const float* Wc2 = (const float*)d_in[26];
  const float* bc2 = (const float*)d_in[27];
  const int* edge_index = (const int*)d_in[28];
  const int* sidx = (const int*)d_in[29];
  float* out = (float*)d_out;

  // ----- static arena (phase-disjoint aliasing; ~107 MiB peak) -----
  const size_t MB = (size_t)1 << 20;
  const size_t KB = (size_t)1 << 10;
  char* ws = (char*)d_ws;
  unsigned short* xc_ch = (unsigned short*)(ws + 0);      // 12.6MB (mamba only)
  unsigned short* xc_cl = (unsigned short*)(ws + 16 * MB);// 12.6MB
  float* xw1 = (float*)(ws + 0);                          // 16MB
  float* g1 = (float*)(ws + 16 * MB);                     // 16MB
  unsigned short* g1h = (unsigned short*)(ws + 32 * MB);  // 8MB
  unsigned short* g1l = (unsigned short*)(ws + 40 * MB);  // 8MB
  unsigned short* xph = (unsigned short*)(ws + 48 * MB);  // 2MB
  unsigned short* xpl = (unsigned short*)(ws + 50 * MB);  // 2MB
  unsigned short* W1th = (unsigned short*)(ws + 52 * MB);            // 128KB
  unsigned short* W1tl = (unsigned short*)(ws + 52 * MB + 128 * KB); // 128KB
  float* xw2 = (float*)(ws + 48 * MB);                    // 16MB
  unsigned short* W2th = (unsigned short*)(ws + 0);               // 512KB (xw1 dead)
  unsigned short* W2tl = (unsigned short*)(ws + 512 * KB);        // 512KB
  float* g2 = (float*)(ws + 0);                           // 16MB
  unsigned short* featsh = (unsigned short*)(ws + 16 * MB);  // 24MB
  unsigned short* featsl = (unsigned short*)(ws + 40 * MB);  // 24MB
  float* hidden = (float*)(ws + 0);                       // 16MB (g2 dead after concat)
  float* xdb_c = (float*)(ws + 64 * MB);                  // 1.5MB (MC_CAP x 64)
  unsigned short* pooledh = (unsigned short*)(ws + 68 * MB);  // 4MB
  unsigned short* pooledl = (unsigned short*)(ws + 72 * MB);  // 4MB
  unsigned short* Wxth = (unsigned short*)(ws + 76 * MB);            // 128KB
  unsigned short* Wxtl = (unsigned short*)(ws + 76 * MB + 128 * KB); // 128KB
  float* WmixT = (float*)(ws + 77 * MB);                  // 2MB (512x1024 f32)
  unsigned short* Wmixth = (unsigned short*)(ws + 80 * MB);  // 1MB
  unsigned short* Wmixtl = (unsigned short*)(ws + 81 * MB);  // 1MB
  unsigned short* Wlth = (unsigned short*)(ws + 82 * MB);            // 512KB
  unsigned short* Wltl = (unsigned short*)(ws + 82 * MB + 512 * KB); // 512KB
  unsigned short* Woph = (unsigned short*)(ws + 83 * MB);            // 1MB
  unsigned short* Wopl = (unsigned short*)(ws + 84 * MB);            // 1MB
  float* negA = (float*)(ws + 85 * MB);                   // 64KB
  unsigned* leftU = (unsigned*)(ws + 64 * MB);            // 16MB (mamba dead)
  unsigned* rightU = (unsigned*)(ws + 80 * MB);           // 16MB
  float* x_point = (float*)(ws + 96 * MB);                // 4MB
  unsigned short* Wc1th = (unsigned short*)(ws + 96 * MB);             // 1.5MB (x_point dead)
  unsigned short* Wc1tl = (unsigned short*)(ws + 96 * MB + 1536 * KB); // 1.5MB
  unsigned short* Wc2th = (unsigned short*)(ws + 99 * MB);             // 32KB
  unsigned short* Wc2tl = (unsigned short*)(ws + 99 * MB + 64 * KB);   // 32KB
  char* sm = ws + 100 * MB;
  float* es1 = (float*)(sm + 0);                 // 256KB
  float* ed1 = (float*)(sm + 256 * KB);          // 256KB
  float* e1 = (float*)(sm + 512 * KB);           // 320KB
  float* denom1 = (float*)(sm + 1088 * KB);      // 256KB
  float* es2 = (float*)(sm + 1344 * KB);         // 32KB
  float* ed2 = (float*)(sm + 1376 * KB);         // 32KB
  float* e2 = (float*)(sm + 1408 * KB);          // 40KB
  float* denom2 = (float*)(sm + 1480 * KB);      // 32KB
  int* flagL = (int*)(sm + 1512 * KB);           // 32KB
  int* flagR = (int*)(sm + 1544 * KB);           // 32KB
  float* padded = (float*)(ws + 106 * MB);                   // 384KB
  int* counts = (int*)(ws + 106 * MB + 384 * KB);            // 8KB
  float* W_eff = (float*)(ws + 106 * MB + 400 * KB);         // 48KB
  float* b_eff = (float*)(ws + 106 * MB + 448 * KB);         // 8KB
  int* starts_c = (int*)(ws + 106 * MB + 456 * KB);          // 8KB

  auto g64 = [&](const float* A, int lda, const float* B, int ldb, float* C, int ldc,
                 int M, int N, int K, const float* bias, int act) {
    dim3 grid((N + 63) / 64, (M + 63) / 64);
    gemm_t<64, 64><<<grid, 256, 0, stream>>>(A, lda, B, ldb, C, ldc, M, N, K, bias, act);
  };
  auto gm2 = [&](const unsigned short* Ah, const unsigned short* Al,
                 const unsigned short* Bth, const unsigned short* Btl, float* C,
                 int M, int N, int K, const float* bias, int act) {
    gemm_mfma2<<<(N / 128) * (M / 128), 512, 0, stream>>>(Ah, Al, Bth, Btl, C, M, N, K, bias,
                                                          act);
  };
  auto tsplit = [&](const float* W, unsigned short* th, unsigned short* tl, int K, int N) {
    tsplit_kernel<<<(K * N + 255) / 256, 256, 0, stream>>>(W, th, tl, K, N);
  };
  auto split = [&](const float* x, unsigned short* h, unsigned short* l, int n) {
    split_kernel<<<(n + 255) / 256, 256, 0, stream>>>(x, h, l, n);
  };

  // ===== PRE: effective weights (one fused prep kernel + W_eff GEMMs) =====
  g64(W_in, DM, W_inproj, 2 * DI, W_eff, 2 * DI, 6, 2 * DI, DM, nullptr, 0);
  g64(b_in, DM, W_inproj, 2 * DI, b_eff, 2 * DI, 1, 2 * DI, DM, nullptr, 0);
  prep1_kernel<<<PREP_TOT / 256, 256, 0, stream>>>(
      W_lout, W_outproj, A_log, W_xproj, W1, x_param,
      Wlth, Wltl, Woph, Wopl, negA, Wxth, Wxtl, W1th, W1tl, xph, xpl);
  hipMemsetAsync(WmixT, 0, (size_t)DM * DI * 4, stream);
  gemm_mfma_sk<<<dim3(DI / 64, DM / 64, 4), 256, 0, stream>>>(Wlth, Wltl, Woph, Wopl, WmixT,
                                                              DM, DI, DM);
  split(WmixT, Wmixth, Wmixtl, DM * DI);

  // ===== Mamba encoder =====
  hipMemsetAsync(padded, 0, (size_t)ROWS * 6 * 4, stream);
  scatter_padded_kernel<<<(NSYN + 255) / 256, 256, 0, stream>>>(synapse, sidx, padded);
  prefix_kernel<<<1, 256, 0, stream>>>(sidx, counts, starts_c);
  xc_compact_kernel<<<dim3(DI / 256, E_EDGES), 256, 0, stream>>>(
      padded, W_eff, b_eff, conv_w, conv_b, counts, starts_c, xc_ch, xc_cl);
  hipMemsetAsync(xdb_c, 0, (size_t)MC_CAP * 64 * 4, stream);
  gemm_mfma_sk<<<dim3(1, MC_CAP / 64, 8), 256, 0, stream>>>(xc_ch, xc_cl, Wxth, Wxtl, xdb_c,
                                                            MC_CAP, 64, DI);
  mamba_scan_pool_kernel<<<dim3(DI / 256, E_EDGES), 256, 0, stream>>>(
      xdb_c, padded, W_eff, b_eff, W_dt, b_dt, negA, Dv, conv_w, conv_b, counts, starts_c,
      pooledh, pooledl);
  hipMemsetAsync(x_point, 0, (size_t)E_EDGES * DM * 4, stream);
  gemm_mfma_sk<<<dim3(DM / 64, E_EDGES / 64, 4), 256, 0, stream>>>(pooledh, pooledl, Wmixth,
                                                                   Wmixtl, x_point, E_EDGES,
                                                                   DM, DI);

  // ===== GAT layer 1 =====
  gm2(xph, xpl, W1th, W1tl, xw1, N_NODES, HEADS * HID, F_IN, nullptr, 0);
  esed1_kernel<<<(N_NODES * HEADS) / 256, 256, 0, stream>>>(xw1, as1, ad1, es1, ed1);
  hipMemsetAsync(denom1, 0, 256 * KB, stream);
  edgeexp1_kernel<<<(TOT_EDGES * HEADS + 255) / 256, 256, 0, stream>>>(edge_index, es1, ed1,
                                                                       e1, denom1);
  selfinit1_kernel<<<(N_NODES * 512) / 256, 256, 0, stream>>>(e1, denom1, xw1, g1);
  agg1_kernel<<<E_EDGES, 256, 0, stream>>>(edge_index, e1, denom1, xw1, g1);
  elu_bias_split_kernel<<<(N_NODES * 512) / 256, 256, 0, stream>>>(g1, b1, g1h, g1l);

  // ===== GAT layer 2 =====
  tsplit(W2, W2th, W2tl, HEADS * HID, REP);  // stays here: W2th aliases xw1 (dead after agg1)
  gm2(g1h, g1l, W2th, W2tl, xw2, N_NODES, REP, HEADS * HID, nullptr, 0);
  esed2_kernel<<<N_NODES, 64, 0, stream>>>(xw2, as2, ad2, es2, ed2);
  hipMemsetAsync(denom2, 0, 96 * KB, stream);  // denom2 + flagL + flagR
  edgeexp2_kernel<<<(TOT_EDGES + 255) / 256, 256, 0, stream>>>(edge_index, es2, ed2, e2,
                                                               denom2);
  selfinit2_kernel<<<(N_NODES * 512) / 256, 256, 0, stream>>>(e2, denom2, xw2, g2);
  agg2_kernel<<<E_EDGES, 256, 0, stream>>>(edge_index, e2, denom2, xw2, g2);

  // ===== left/right segment max =====
  hipMemsetAsync(leftU, 0, 32 * MB, stream);  // leftU + rightU (contiguous)
  leftright_kernel<<<E_EDGES, 256, 0, stream>>>(edge_index, x_point, b_lout, leftU, rightU,
                                                flagL, flagR);

  // ===== classifier =====
  concat_split_kernel<<<(N_NODES * 512) / 256, 256, 0, stream>>>(g2, b2, leftU, rightU, flagL,
                                                                 flagR, featsh, featsl);
  tsplit(Wc1, Wc1th, Wc1tl, REP + 2 * DM, 512);  // stays: aliases x_point (dead after leftright)
  tsplit(Wc2, Wc2th, Wc2tl, 512, NCLS);
  gm2(featsh, featsl, Wc1th, Wc1tl, hidden, N_NODES, 512, REP + 2 * DM, bc1, 1);
  gemm_thin32<0><<<N_NODES / 64, 256, 0, stream>>>(hidden, Wc2th, Wc2tl, out, N_NODES, bc2);
}

// Round 23
// 410.479 us; speedup vs baseline: 1.1069x; 1.0046x over previous
//
#include <hip/hip_runtime.h>

#define N_NODES 8192
#define F_IN 128
#define HID 64
#define HEADS 8
#define REP 512
#define NCLS 32
#define E_EDGES 2048
#define NSYN 4096
#define LMAX 8
#define DM 512
#define DI 1024
#define DSTATE 16
#define DCONV 4
#define DTR 32
#define TOT_EDGES (E_EDGES + N_NODES) /* 10240 */
#define ROWS (E_EDGES * LMAX)         /* 16384 */
#define MC_CAP 6144                   /* >= sum(min(max(cnt,1),8)) */

typedef short bf16x8 __attribute__((ext_vector_type(8)));
typedef float f32x4 __attribute__((ext_vector_type(4)));

// async global->LDS, 16B per lane; LDS dest is wave-uniform base + lane*16
#define GLOAD_LDS16(gp, lp)                                                   \
  __builtin_amdgcn_global_load_lds(                                           \
      (const __attribute__((address_space(1))) void*)(gp),                    \
      (__attribute__((address_space(3))) void*)(lp), 16, 0, 0)

// ---------- helpers ----------
__device__ __forceinline__ unsigned mapf(float f) {
  unsigned u = __float_as_uint(f);
  return (u & 0x80000000u) ? ~u : (u | 0x80000000u);
}
__device__ __forceinline__ float unmapf(unsigned u) {
  return __uint_as_float((u & 0x80000000u) ? (u ^ 0x80000000u) : ~u);
}
__device__ __forceinline__ float fsig(float x) {
  return __builtin_amdgcn_rcpf(1.0f + __expf(-x));
}
__device__ __forceinline__ float fsoftplus(float x) {
  return fmaxf(x, 0.0f) + __logf(1.0f + __expf(-fabsf(x)));
}
__device__ __forceinline__ unsigned short f2bf(float f) {
  unsigned u = __float_as_uint(f);
  unsigned r = (u + 0x7FFFu + ((u >> 16) & 1u)) >> 16;
  return (unsigned short)r;
}
__device__ __forceinline__ float bf2f(unsigned short h) {
  return __uint_as_float(((unsigned)h) << 16);
}
__device__ __forceinline__ void split2(float x, unsigned short* hh, unsigned short* ll) {
  unsigned short h = f2bf(x);
  *hh = h;
  *ll = f2bf(x - bf2f(h));
}
__device__ __forceinline__ int lower_bound_dev(const int* __restrict__ arr, int n, int v) {
  int lo = 0, hi = n;
  while (lo < hi) { int mid = (lo + hi) >> 1; if (arr[mid] < v) lo = mid + 1; else hi = mid; }
  return lo;
}
__device__ __forceinline__ int src_of(const int* __restrict__ ei, int i) {
  return i < E_EDGES ? ei[i] : i - E_EDGES;
}
__device__ __forceinline__ int dst_of(const int* __restrict__ ei, int i) {
  return i < E_EDGES ? ei[E_EDGES + i] : i - E_EDGES;
}
__device__ __forceinline__ int clip_cnt(int c) { return c < 1 ? 1 : (c > LMAX ? LMAX : c); }

// ---------- MFMA split-bf16 GEMM, 128x128 tile, 512 threads (8 waves, 2/SIMD) ----------
// global_load_lds staging (m97 scheme): double-buffered LINEAR LDS, 1 barrier per K-step.
// Each thread issues 4x 16B async loads straight to LDS (no VGPR round-trip).
__global__ __launch_bounds__(512) void gemm_mfma2(
    const unsigned short* __restrict__ Ah, const unsigned short* __restrict__ Al,
    const unsigned short* __restrict__ Bth, const unsigned short* __restrict__ Btl,
    float* __restrict__ C, int M, int N, int K,
    const float* __restrict__ bias, int act) {
  // [buf][mat: 0=Ah 1=Al 2=Bth 3=Btl][row][col] -- unpadded (gload_lds needs linear dest)
  __shared__ __align__(16) unsigned short S[2][4][128][32];
  const int tid = threadIdx.x;
  const int w = tid >> 6;
  const int lane = tid & 63;
  const int wr = w >> 2, wc = w & 3;  // 2x4 wave grid; wave tile 64x32
  const int mb = M >> 7;
  const int lin = blockIdx.x;
  const int bx = lin / mb;
  const int by = lin % mb;
  const int brow = by * 128;
  const int bcol = bx * 128;
  const int r0 = lane & 15;
  const int kg = lane >> 4;
  const int row0 = tid >> 2, kc0 = tid & 3;  // row0 = w*16 + (lane>>2): matches lane*16B dest
  const size_t a0 = (size_t)(brow + row0) * K + kc0 * 8;
  const size_t b0 = (size_t)(bcol + row0) * K + kc0 * 8;
  f32x4 acc[4][2] = {};

  auto stage = [&](int buf, int kt) {
    GLOAD_LDS16(Ah + a0 + kt, &S[buf][0][w * 16][0]);
    GLOAD_LDS16(Al + a0 + kt, &S[buf][1][w * 16][0]);
    GLOAD_LDS16(Bth + b0 + kt, &S[buf][2][w * 16][0]);
    GLOAD_LDS16(Btl + b0 + kt, &S[buf][3][w * 16][0]);
  };

  stage(0, 0);
  __syncthreads();  // vmcnt(0) drain before barrier -> buf0 visible to all waves
  const int nk = K >> 5;
  for (int i = 0; i < nk; ++i) {
    const int cur = i & 1;
    if (i + 1 < nk) stage(cur ^ 1, (i + 1) << 5);  // async prefetch into spare buffer
    bf16x8 bhv[2], blv[2];
#pragma unroll
    for (int cf = 0; cf < 2; ++cf) {
      bhv[cf] = *(const bf16x8*)(&S[cur][2][wc * 32 + cf * 16 + r0][kg * 8]);
      blv[cf] = *(const bf16x8*)(&S[cur][3][wc * 32 + cf * 16 + r0][kg * 8]);
    }
#pragma unroll
    for (int rf = 0; rf < 4; ++rf) {
      bf16x8 ah = *(const bf16x8*)(&S[cur][0][wr * 64 + rf * 16 + r0][kg * 8]);
      bf16x8 al = *(const bf16x8*)(&S[cur][1][wr * 64 + rf * 16 + r0][kg * 8]);
#pragma unroll
      for (int cf = 0; cf < 2; ++cf) {
        acc[rf][cf] = __builtin_amdgcn_mfma_f32_16x16x32_bf16(ah, bhv[cf], acc[rf][cf], 0, 0, 0);
        acc[rf][cf] = __builtin_amdgcn_mfma_f32_16x16x32_bf16(ah, blv[cf], acc[rf][cf], 0, 0, 0);
        acc[rf][cf] = __builtin_amdgcn_mfma_f32_16x16x32_bf16(al, bhv[cf], acc[rf][cf], 0, 0, 0);
      }
    }
    __syncthreads();  // all waves done reading buf[cur]; prefetch into buf[cur^1] landed
  }
#pragma unroll
  for (int rf = 0; rf < 4; ++rf)
#pragma unroll
    for (int cf = 0; cf < 2; ++cf) {
      int col = bcol + wc * 32 + cf * 16 + r0;
      float bb = bias ? bias[col] : 0.0f;
#pragma unroll
      for (int j = 0; j < 4; ++j) {
        int row = brow + wr * 64 + rf * 16 + kg * 4 + j;
        float v = acc[rf][cf][j] + bb;
        if (act == 1) v = fmaxf(v, 0.0f);
        C[(size_t)row * N + col] = v;
      }
    }
}

// ---------- split-K variant (64x64): partial K range per blockIdx.z, atomicAdd output ----------
__global__ __launch_bounds__(256) void gemm_mfma_sk(
    const unsigned short* __restrict__ Ah, const unsigned short* __restrict__ Al,
    const unsigned short* __restrict__ Bth, const unsigned short* __restrict__ Btl,
    float* __restrict__ C, int M, int N, int K) {
  __shared__ __align__(16) unsigned short As[2][64][40];
  const int tid = threadIdx.x;
  const int w = tid >> 6;
  const int lane = tid & 63;
  const int brow = blockIdx.y * 64;
  const int bcol = blockIdx.x * 64;
  const int srow = tid >> 2;
  const int skc = tid & 3;
  const int r0 = lane & 15;
  const int kg = lane >> 4;
  const int kchunk = K / gridDim.z;
  const int k0 = blockIdx.z * kchunk;
  f32x4 acc[4] = {};
  const size_t aoff = (size_t)(brow + srow) * K;
  const size_t boff = (size_t)(bcol + w * 16 + r0) * K + kg * 8;
  for (int kt = k0; kt < k0 + kchunk; kt += 32) {
    bf16x8 bh = *(const bf16x8*)(Bth + boff + kt);
    bf16x8 bl = *(const bf16x8*)(Btl + boff + kt);
    *(bf16x8*)(&As[0][srow][skc * 8]) = *(const bf16x8*)(Ah + aoff + kt + skc * 8);
    *(bf16x8*)(&As[1][srow][skc * 8]) = *(const bf16x8*)(Al + aoff + kt + skc * 8);
    __syncthreads();
#pragma unroll
    for (int r = 0; r < 4; ++r) {
      bf16x8 ah = *(const bf16x8*)(&As[0][r * 16 + r0][kg * 8]);
      bf16x8 al = *(const bf16x8*)(&As[1][r * 16 + r0][kg * 8]);
      acc[r] = __builtin_amdgcn_mfma_f32_16x16x32_bf16(ah, bh, acc[r], 0, 0, 0);
      acc[r] = __builtin_amdgcn_mfma_f32_16x16x32_bf16(ah, bl, acc[r], 0, 0, 0);
      acc[r] = __builtin_amdgcn_mfma_f32_16x16x32_bf16(al, bh, acc[r], 0, 0, 0);
    }
    __syncthreads();
  }
  const int col = bcol + w * 16 + r0;
#pragma unroll
  for (int r = 0; r < 4; ++r) {
#pragma unroll
    for (int j = 0; j < 4; ++j) {
      int row = brow + r * 16 + kg * 4 + j;
      atomicAdd(&C[(size_t)row * N + col], acc[r][j]);
    }
  }
}

// ---------- thin MFMA GEMM: C(Mx32) = relu(A32)(Mx512) @ Bt(32x512)^T + bias ----------
template <int APPLY_RELU>
__global__ __launch_bounds__(256) void gemm_thin32(
    const float* __restrict__ A32,
    const unsigned short* __restrict__ Bth, const unsigned short* __restrict__ Btl,
    float* __restrict__ C, int M, const float* __restrict__ bias) {
  const int tid = threadIdx.x;
  const int w = tid >> 6;
  const int lane = tid & 63;
  const int r0 = lane & 15;
  const int kg = lane >> 4;
  const int rowbase = blockIdx.x * 64 + w * 16;
  f32x4 acc[2] = {};
  const float* arow = A32 + (size_t)(rowbase + r0) * 512 + kg * 8;
  for (int kt = 0; kt < 512; kt += 32) {
    float4 f0 = *(const float4*)(arow + kt);
    float4 f1 = *(const float4*)(arow + kt + 4);
    float v[8] = {f0.x, f0.y, f0.z, f0.w, f1.x, f1.y, f1.z, f1.w};
    bf16x8 ah, al;
#pragma unroll
    for (int j = 0; j < 8; ++j) {
      float vv = APPLY_RELU ? fmaxf(v[j], 0.0f) : v[j];
      unsigned short hh, ll;
      split2(vv, &hh, &ll);
      ah[j] = (short)hh;
      al[j] = (short)ll;
    }
#pragma unroll
    for (int cf = 0; cf < 2; ++cf) {
      bf16x8 bh = *(const bf16x8*)(Bth + (size_t)(cf * 16 + r0) * 512 + kt + kg * 8);
      bf16x8 bl = *(const bf16x8*)(Btl + (size_t)(cf * 16 + r0) * 512 + kt + kg * 8);
      acc[cf] = __builtin_amdgcn_mfma_f32_16x16x32_bf16(ah, bh, acc[cf], 0, 0, 0);
      acc[cf] = __builtin_amdgcn_mfma_f32_16x16x32_bf16(ah, bl, acc[cf], 0, 0, 0);
      acc[cf] = __builtin_amdgcn_mfma_f32_16x16x32_bf16(al, bh, acc[cf], 0, 0, 0);
    }
  }
#pragma unroll
  for (int cf = 0; cf < 2; ++cf) {
    int col = cf * 16 + r0;
    float bb = bias[col];
#pragma unroll
    for (int j = 0; j < 4; ++j) {
      int row = rowbase + kg * 4 + j;
      C[(size_t)row * 32 + col] = acc[cf][j] + bb;
    }
  }
}

// ---------- split / transpose-split ----------
__global__ void split_kernel(const float* __restrict__ x, unsigned short* __restrict__ h,
                             unsigned short* __restrict__ l, int n) {
  int i = blockIdx.x * 256 + threadIdx.x;
  if (i >= n) return;
  split2(x[i], &h[i], &l[i]);
}

__global__ void tsplit_kernel(const float* __restrict__ W, unsigned short* __restrict__ Wth,
                              unsigned short* __restrict__ Wtl, int K, int N) {
  int i = blockIdx.x * 256 + threadIdx.x;
  if (i >= K * N) return;
  int k = i / N, n = i - k * N;
  float v = W[i];
  unsigned short h = f2bf(v);
  Wth[(size_t)n * K + k] = h;
  Wtl[(size_t)n * K + k] = f2bf(v - bf2f(h));
}

// ---------- fused weight-prep: tsplit Wl / split Wop / negA / tsplit Wx / tsplit W1 / split xp ----------
#define PREP_SEG0 262144   /* tsplit W_lout 512x512 */
#define PREP_SEG1 524288   /* split W_outproj */
#define PREP_SEG2 16384    /* negA */
#define PREP_SEG3 65536    /* tsplit W_xproj 1024x64 */
#define PREP_SEG4 65536    /* tsplit W1 128x512 */
#define PREP_SEG5 1048576  /* split x_param */
#define PREP_TOT (PREP_SEG0 + PREP_SEG1 + PREP_SEG2 + PREP_SEG3 + PREP_SEG4 + PREP_SEG5)
__global__ void prep1_kernel(
    const float* __restrict__ W_lout, const float* __restrict__ W_outproj,
    const float* __restrict__ A_log, const float* __restrict__ W_xproj,
    const float* __restrict__ W1, const float* __restrict__ x_param,
    unsigned short* __restrict__ Wlth, unsigned short* __restrict__ Wltl,
    unsigned short* __restrict__ Woph, unsigned short* __restrict__ Wopl,
    float* __restrict__ negA,
    unsigned short* __restrict__ Wxth, unsigned short* __restrict__ Wxtl,
    unsigned short* __restrict__ W1th, unsigned short* __restrict__ W1tl,
    unsigned short* __restrict__ xph, unsigned short* __restrict__ xpl) {
  int i = blockIdx.x * 256 + threadIdx.x;
  if (i < PREP_SEG0) {
    int k = i >> 9, n = i & 511;
    float v = W_lout[i];
    unsigned short h = f2bf(v);
    Wlth[(size_t)n * 512 + k] = h;
    Wltl[(size_t)n * 512 + k] = f2bf(v - bf2f(h));
    return;
  }
  i -= PREP_SEG0;
  if (i < PREP_SEG1) { split2(W_outproj[i], &Woph[i], &Wopl[i]); return; }
  i -= PREP_SEG1;
  if (i < PREP_SEG2) { negA[i] = -__expf(A_log[i]); return; }
  i -= PREP_SEG2;
  if (i < PREP_SEG3) {
    int k = i >> 6, n = i & 63;
    float v = W_xproj[i];
    unsigned short h = f2bf(v);
    Wxth[(size_t)n * 1024 + k] = h;
    Wxtl[(size_t)n * 1024 + k] = f2bf(v - bf2f(h));
    return;
  }
  i -= PREP_SEG3;
  if (i < PREP_SEG4) {
    int k = i >> 9, n = i & 511;
    float v = W1[i];
    unsigned short h = f2bf(v);
    W1th[(size_t)n * 128 + k] = h;
    W1tl[(size_t)n * 128 + k] = f2bf(v - bf2f(h));
    return;
  }
  i -= PREP_SEG4;
  if (i < PREP_SEG5) { split2(x_param[i], &xph[i], &xpl[i]); }
}

// ---------- tiled f32 GEMM (small shapes) ----------
template <int BM, int BN>
__global__ __launch_bounds__(256) void gemm_t(
    const float* __restrict__ A, int lda,
    const float* __restrict__ B, int ldb,
    float* __restrict__ C, int ldc,
    int M, int N, int K,
    const float* __restrict__ bias, int act) {
  constexpr int RR = BM / 64;
  constexpr int CR = BN / 64;
  __shared__ float As[16][BM + 4];
  __shared__ float Bs[16][BN + 4];
  const int tid = threadIdx.x;
  const int tx = tid & 15;
  const int ty = tid >> 4;
  const int brow = blockIdx.y * BM;
  const int bcol = blockIdx.x * BN;
  float acc[RR][CR][4][4] = {};
  for (int kt = 0; kt < K; kt += 16) {
#pragma unroll
    for (int p = 0; p < RR; ++p) {
      int c = tid + p * 256;
      int row = c >> 2, kc = c & 3;
      int gr = brow + row;
      float4 v = make_float4(0.f, 0.f, 0.f, 0.f);
      if (gr < M) v = *reinterpret_cast<const float4*>(A + (size_t)gr * lda + kt + kc * 4);
      As[kc * 4 + 0][row] = v.x;
      As[kc * 4 + 1][row] = v.y;
      As[kc * 4 + 2][row] = v.z;
      As[kc * 4 + 3][row] = v.w;
    }
#pragma unroll
    for (int p = 0; p < CR; ++p) {
      int c = tid + p * 256;
      int k = c / (BN / 4), c4 = c % (BN / 4);
      int gc = bcol + c4 * 4;
      float4 v = make_float4(0.f, 0.f, 0.f, 0.f);
      if (gc < N) v = *reinterpret_cast<const float4*>(B + (size_t)(kt + k) * ldb + gc);
      *reinterpret_cast<float4*>(&Bs[k][c4 * 4]) = v;
    }
    __syncthreads();
#pragma unroll
    for (int k = 0; k < 16; ++k) {
      float av[RR * 4], bv[CR * 4];
#pragma unroll
      for (int r = 0; r < RR; ++r) {
        float4 t = *reinterpret_cast<const float4*>(&As[k][r * 64 + ty * 4]);
        av[r * 4 + 0] = t.x; av[r * 4 + 1] = t.y; av[r * 4 + 2] = t.z; av[r * 4 + 3] = t.w;
      }
#pragma unroll
      for (int cq = 0; cq < CR; ++cq) {
        float4 t = *reinterpret_cast<const float4*>(&Bs[k][cq * 64 + tx * 4]);
        bv[cq * 4 + 0] = t.x; bv[cq * 4 + 1] = t.y; bv[cq * 4 + 2] = t.z; bv[cq * 4 + 3] = t.w;
      }
#pragma unroll
      for (int r = 0; r < RR; ++r)
#pragma unroll
        for (int cq = 0; cq < CR; ++cq)
#pragma unroll
          for (int i = 0; i < 4; ++i)
#pragma unroll
            for (int j = 0; j < 4; ++j)
              acc[r][cq][i][j] = fmaf(av[r * 4 + i], bv[cq * 4 + j], acc[r][cq][i][j]);
    }
    __syncthreads();
  }
#pragma unroll
  for (int r = 0; r < RR; ++r)
#pragma unroll
    for (int i = 0; i < 4; ++i) {
      int row = brow + r * 64 + ty * 4 + i;
      if (row >= M) continue;
#pragma unroll
      for (int cq = 0; cq < CR; ++cq) {
        int col = bcol + cq * 64 + tx * 4;
        if (col >= N) continue;
        float4 v;
        v.x = acc[r][cq][i][0]; v.y = acc[r][cq][i][1];
        v.z = acc[r][cq][i][2]; v.w = acc[r][cq][i][3];
        if (bias) {
          float4 bb = *reinterpret_cast<const float4*>(bias + col);
          v.x += bb.x; v.y += bb.y; v.z += bb.z; v.w += bb.w;
        }
        if (act == 1) {
          v.x = fmaxf(v.x, 0.f); v.y = fmaxf(v.y, 0.f);
          v.z = fmaxf(v.z, 0.f); v.w = fmaxf(v.w, 0.f);
        }
        *reinterpret_cast<float4*>(C + (size_t)row * ldc + col) = v;
      }
    }
}

// ---------- mamba: pad/scatter + fused counts+prefix ----------
__global__ void scatter_padded_kernel(const float* __restrict__ synapse,
                                      const int* __restrict__ sidx,
                                      float* __restrict__ padded) {
  int i = blockIdx.x * 256 + threadIdx.x;
  if (i >= NSYN) return;
  int e = sidx[i];
  int lo = lower_bound_dev(sidx, NSYN, e);
  int pos = i - lo;
  if (pos < LMAX) {
#pragma unroll
    for (int c = 0; c < 6; ++c) padded[((size_t)e * LMAX + pos) * 6 + c] = synapse[(size_t)i * 6 + c];
  }
}

// counts + exclusive prefix over clipped counts -> starts_c (one block, 256 threads x 8)
__global__ __launch_bounds__(256) void prefix_kernel(const int* __restrict__ sidx,
                                                     int* __restrict__ counts,
                                                     int* __restrict__ starts_c) {
  __shared__ int part[256];
  int t = threadIdx.x;
  int loc[8];
  int s = 0;
  int lo = lower_bound_dev(sidx, NSYN, t * 8);
#pragma unroll
  for (int i = 0; i < 8; ++i) {
    int hi = lower_bound_dev(sidx, NSYN, t * 8 + i + 1);
    int c = hi - lo;
    counts[t * 8 + i] = c;
    lo = hi;
    c = clip_cnt(c);
    loc[i] = s;
    s += c;
  }
  part[t] = s;
  __syncthreads();
  int mytot = s;
  for (int o = 1; o < 256; o <<= 1) {
    int add = (t >= o) ? part[t - o] : 0;
    __syncthreads();
    part[t] += add;
    __syncthreads();
  }
  int off = part[t] - mytot;
#pragma unroll
  for (int i = 0; i < 8; ++i) starts_c[t * 8 + i] = off + loc[i];
}

// ---------- mamba: compact xc = silu(conv(padded@W_eff)) -> bf16 h/l ----------
__global__ __launch_bounds__(256) void xc_compact_kernel(
    const float* __restrict__ padded,
    const float* __restrict__ W_eff, const float* __restrict__ b_eff,
    const float* __restrict__ conv_w, const float* __restrict__ conv_b,
    const int* __restrict__ counts, const int* __restrict__ starts_c,
    unsigned short* __restrict__ xch, unsigned short* __restrict__ xcl) {
  __shared__ float pads[LMAX * 6];
  int t = threadIdx.x;
  int d = blockIdx.x * 256 + t;
  int e = blockIdx.y;
  if (t < LMAX * 6) pads[t] = padded[(size_t)e * LMAX * 6 + t];
  __syncthreads();
  int cnt = clip_cnt(counts[e]);
  int sc = starts_c[e];
  float wef[6];
#pragma unroll
  for (int c = 0; c < 6; ++c) wef[c] = W_eff[c * 2048 + d];
  float cw0 = conv_w[d * 4 + 0], cw1 = conv_w[d * 4 + 1];
  float cw2 = conv_w[d * 4 + 2], cw3 = conv_w[d * 4 + 3];
  float cb = conv_b[d], be = b_eff[d];
  float x0 = 0.f, x1 = 0.f, x2 = 0.f;
  for (int l = 0; l < cnt; ++l) {
    float xm = be;
#pragma unroll
    for (int c = 0; c < 6; ++c) xm += pads[l * 6 + c] * wef[c];
    float s0 = cb + xm * cw3;
    if (l >= 1) s0 += x2 * cw2;
    if (l >= 2) s0 += x1 * cw1;
    if (l >= 3) s0 += x0 * cw0;
    float v = s0 * fsig(s0);
    size_t o = (size_t)(sc + l) * DI + d;
    split2(v, &xch[o], &xcl[o]);
    x0 = x1; x1 = x2; x2 = xm;
  }
}

// ---------- mamba: scan with LDS-staged xdb rows (broadcast reads) ----------
__global__ __launch_bounds__(256) void mamba_scan_pool_kernel(
    const float* __restrict__ xdb_c, const float* __restrict__ padded,
    const float* __restrict__ W_eff, const float* __restrict__ b_eff,
    const float* __restrict__ W_dt, const float* __restrict__ b_dt,
    const float* __restrict__ negA, const float* __restrict__ Dv,
    const float* __restrict__ conv_w, const float* __restrict__ conv_b,
    const int* __restrict__ counts, const int* __restrict__ starts_c,
    unsigned short* __restrict__ pooledh, unsigned short* __restrict__ pooledl) {
  __shared__ float pads[LMAX * 6];
  __shared__ float rows[LMAX * 64];  // staged xdb rows (2KB)
  int t = threadIdx.x;
  int d = blockIdx.x * 256 + t;
  int e = blockIdx.y;
  int cnt = clip_cnt(counts[e]);
  int sc = starts_c[e];
  if (t < LMAX * 6) pads[t] = padded[(size_t)e * LMAX * 6 + t];
  for (int i = t; i < cnt * 64; i += 256) rows[i] = xdb_c[(size_t)sc * 64 + i];
  float wdt[DTR];
#pragma unroll
  for (int k = 0; k < DTR; ++k) wdt[k] = W_dt[k * DI + d];
  float a[DSTATE];
#pragma unroll
  for (int n = 0; n < DSTATE; ++n) a[n] = negA[d * DSTATE + n];
  float h[DSTATE];
#pragma unroll
  for (int n = 0; n < DSTATE; ++n) h[n] = 0.0f;
  float wef[6], wez[6];
#pragma unroll
  for (int c = 0; c < 6; ++c) {
    wef[c] = W_eff[c * 2048 + d];
    wez[c] = W_eff[c * 2048 + DI + d];
  }
  float cw0 = conv_w[d * 4 + 0], cw1 = conv_w[d * 4 + 1];
  float cw2 = conv_w[d * 4 + 2], cw3 = conv_w[d * 4 + 3];
  float cb = conv_b[d];
  float bdt = b_dt[d], Dd = Dv[d], be = b_eff[d], bez = b_eff[DI + d];
  __syncthreads();
  float x0 = 0.f, x1 = 0.f, x2 = 0.f;
  float ssum = 0.0f;
  for (int l = 0; l < cnt; ++l) {
    float xm = be;
#pragma unroll
    for (int c = 0; c < 6; ++c) xm += pads[l * 6 + c] * wef[c];
    float s0 = cb + xm * cw3;
    if (l >= 1) s0 += x2 * cw2;
    if (l >= 2) s0 += x1 * cw1;
    if (l >= 3) s0 += x0 * cw0;
    float xt = s0 * fsig(s0);
    const float* __restrict__ xrow = &rows[l * 64];
    float acc = bdt;
#pragma unroll
    for (int k = 0; k < DTR; ++k) acc += xrow[k] * wdt[k];
    float dt = fsoftplus(acc);
    float dtx = dt * xt;
    float y = 0.0f;
#pragma unroll
    for (int n = 0; n < DSTATE; ++n) {
      float en = __expf(dt * a[n]);
      h[n] = en * h[n] + dtx * xrow[32 + n];
      y += h[n] * xrow[48 + n];
    }
    y += Dd * xt;
    float z = bez;
#pragma unroll
    for (int c = 0; c < 6; ++c) z += pads[l * 6 + c] * wez[c];
    ssum += y * z * fsig(z);
    x0 = x1; x1 = x2; x2 = xm;
  }
  float pv = ssum / (float)cnt;
  split2(pv, &pooledh[(size_t)e * DI + d], &pooledl[(size_t)e * DI + d]);
}

// ---------- GAT layer 1 ----------
__global__ void esed1_kernel(const float* __restrict__ xw1, const float* __restrict__ as1,
                             const float* __restrict__ ad1, float* __restrict__ es1,
                             float* __restrict__ ed1) {
  int idx = blockIdx.x * 256 + threadIdx.x;  // N_NODES*HEADS
  int n = idx >> 3, h = idx & 7;
  const float* xr = xw1 + (size_t)n * 512 + h * 64;
  const float* sr = as1 + h * 64;
  const float* dr = ad1 + h * 64;
  float es = 0.0f, ed = 0.0f;
#pragma unroll
  for (int c = 0; c < 64; ++c) { float v = xr[c]; es += v * sr[c]; ed += v * dr[c]; }
  es1[idx] = es; ed1[idx] = ed;
}

// fused edge score + exp (no max-subtraction: |e| <~ 0.2, exp exact in fp32)
__global__ void edgeexp1_kernel(const int* __restrict__ ei, const float* __restrict__ es1,
                                const float* __restrict__ ed1, float* __restrict__ e1,
                                float* __restrict__ denom1) {
  int idx = blockIdx.x * 256 + threadIdx.x;
  if (idx >= TOT_EDGES * HEADS) return;
  int i = idx >> 3, h = idx & 7;
  int s = src_of(ei, i), d = dst_of(ei, i);
  float v = es1[s * 8 + h] + ed1[d * 8 + h];
  v = v >= 0.0f ? v : 0.2f * v;
  float ex = expf(v);
  e1[idx] = ex;
  atomicAdd(denom1 + d * 8 + h, ex);
}

// init g1 with the self-loop contribution (replaces memset; self edge id = E_EDGES + n)
__global__ void selfinit1_kernel(const float* __restrict__ e1, const float* __restrict__ denom1,
                                 const float* __restrict__ xw1, float* __restrict__ g1) {
  int idx = blockIdx.x * 256 + threadIdx.x;  // N_NODES*512
  int n = idx >> 9, j = idx & 511;
  int h = j >> 6;
  float alpha = e1[(size_t)(E_EDGES + n) * 8 + h] / denom1[n * 8 + h];
  g1[idx] = alpha * xw1[idx];
}

__global__ __launch_bounds__(256) void agg1_kernel(const int* __restrict__ ei,
                                                   const float* __restrict__ e1,
                                                   const float* __restrict__ denom1,
                                                   const float* __restrict__ xw1,
                                                   float* __restrict__ g1) {
  int i = blockIdx.x;  // real edges only
  int s = ei[i], d = ei[E_EDGES + i];
  for (int j = threadIdx.x; j < 512; j += 256) {
    int h = j >> 6;
    float alpha = e1[i * 8 + h] / denom1[d * 8 + h];
    atomicAdd(g1 + (size_t)d * 512 + j, alpha * xw1[(size_t)s * 512 + j]);
  }
}

__global__ void elu_bias_split_kernel(const float* __restrict__ g1, const float* __restrict__ b1,
                                      unsigned short* __restrict__ g1h,
                                      unsigned short* __restrict__ g1l) {
  int idx = blockIdx.x * 256 + threadIdx.x;  // N_NODES*512
  int j = idx & 511;
  float v = g1[idx] + b1[j];
  v = v > 0.0f ? v : expm1f(v);
  split2(v, &g1h[idx], &g1l[idx]);
}

// ---------- GAT layer 2 ----------
__global__ __launch_bounds__(64) void esed2_kernel(const float* __restrict__ xw2,
                                                   const float* __restrict__ as2,
                                                   const float* __restrict__ ad2,
                                                   float* __restrict__ es2,
                                                   float* __restrict__ ed2) {
  int n = blockIdx.x, t = threadIdx.x;
  float es = 0.0f, ed = 0.0f;
  for (int c = t; c < 512; c += 64) {
    float v = xw2[(size_t)n * 512 + c];
    es += v * as2[c]; ed += v * ad2[c];
  }
#pragma unroll
  for (int o = 32; o > 0; o >>= 1) { es += __shfl_down(es, o, 64); ed += __shfl_down(ed, o, 64); }
  if (t == 0) { es2[n] = es; ed2[n] = ed; }
}

__global__ void edgeexp2_kernel(const int* __restrict__ ei, const float* __restrict__ es2,
                                const float* __restrict__ ed2, float* __restrict__ e2,
                                float* __restrict__ denom2) {
  int i = blockIdx.x * 256 + threadIdx.x;
  if (i >= TOT_EDGES) return;
  int s = src_of(ei, i), d = dst_of(ei, i);
  float v = es2[s] + ed2[d];
  v = v >= 0.0f ? v : 0.2f * v;
  float ex = expf(v);
  e2[i] = ex;
  atomicAdd(denom2 + d, ex);
}

__global__ void selfinit2_kernel(const float* __restrict__ e2, const float* __restrict__ denom2,
                                 const float* __restrict__ xw2, float* __restrict__ g2) {
  int idx = blockIdx.x * 256 + threadIdx.x;  // N_NODES*512
  int n = idx >> 9;
  float alpha = e2[E_EDGES + n] / denom2[n];
  g2[idx] = alpha * xw2[idx];
}

__global__ __launch_bounds__(256) void agg2_kernel(const int* __restrict__ ei,
                                                   const float* __restrict__ e2,
                                                   const float* __restrict__ denom2,
                                                   const float* __restrict__ xw2,
                                                   float* __restrict__ g2) {
  int i = blockIdx.x;  // real edges only
  int s = ei[i], d = ei[E_EDGES + i];
  float alpha = e2[i] / denom2[d];
  for (int j = threadIdx.x; j < 512; j += 256) {
    atomicAdd(g2 + (size_t)d * 512 + j, alpha * xw2[(size_t)s * 512 + j]);
  }
}

// ---------- scatter segment-max (adds b_lout bias on the fly) ----------
__global__ __launch_bounds__(256) void leftright_kernel(const int* __restrict__ ei,
                                                        const float* __restrict__ xp,
                                                        const float* __restrict__ b_lout,
                                                        unsigned* __restrict__ leftU,
                                                        unsigned* __restrict__ rightU,
                                                        int* __restrict__ flagL,
                                                        int* __restrict__ flagR) {
  int i = blockIdx.x;  // E_EDGES
  int s = ei[i], d = ei[E_EDGES + i];
  if (threadIdx.x == 0) { flagL[s] = 1; flagR[d] = 1; }
  for (int j = threadIdx.x; j < 512; j += 256) {
    unsigned v = mapf(xp[(size_t)i * 512 + j] + b_lout[j]);
    atomicMax(leftU + (size_t)s * 512 + j, v);
    atomicMax(rightU + (size_t)d * 512 + j, v);
  }
}

// ---------- feats = [g2+b2, left, right] -> bf16 h/l ----------
__global__ void concat_split_kernel(const float* __restrict__ g2, const float* __restrict__ b2,
                                    const unsigned* __restrict__ leftU,
                                    const unsigned* __restrict__ rightU,
                                    const int* __restrict__ flagL, const int* __restrict__ flagR,
                                    unsigned short* __restrict__ fh,
                                    unsigned short* __restrict__ fl) {
  int idx = blockIdx.x * 256 + threadIdx.x;  // N_NODES*512
  int n = idx >> 9, j = idx & 511;
  size_t base = (size_t)n * 1536 + j;
  split2(g2[idx] + b2[j], &fh[base], &fl[base]);
  split2(flagL[n] ? unmapf(leftU[idx]) : 0.0f, &fh[base + 512], &fl[base + 512]);
  split2(flagR[n] ? unmapf(rightU[idx]) : 0.0f, &fh[base + 1024], &fl[base + 1024]);
}

// ---------- launch ----------
extern "C" void kernel_launch(void* const* d_in, const int* in_sizes, int n_in,
                              void* d_out, int out_size, void* d_ws, size_t ws_size,
                              hipStream_t stream) {
  const float* synapse = (const float*)d_in[1];
  const float* x_param = (const float*)d_in[2];
  const float* W1 = (const float*)d_in[3];
  const float* as1 = (const float*)d_in[4];
  const float* ad1 = (const float*)d_in[5];
  const float* b1 = (const float*)d_in[6];
  const float* W2 = (const float*)d_in[7];
  const float* as2 = (const float*)d_in[8];
  const float* ad2 = (const float*)d_in[9];
  const float* b2 = (const float*)d_in[10];
  const float* W_in = (const float*)d_in[11];
  const float* b_in = (const float*)d_in[12];
  const float* W_inproj = (const float*)d_in[13];
  const float* conv_w = (const float*)d_in[14];
  const float* conv_b = (const float*)d_in[15];
  const float* W_xproj = (const float*)d_in[16];
  const float* W_dt = (const float*)d_in[17];
  const float* b_dt = (const float*)d_in[18];
  const float* A_log = (const float*)d_in[19];
  const float* Dv = (const float*)d_in[20];
  const float* W_outproj = (const float*)d_in[21];
  const float* W_lout = (const float*)d_in[22];
  const float* b_lout = (const float*)d_in[23];
  const float* Wc1 = (const float*)d_in[24];
  const float* bc1 = (const float*)d_in[25];
  const float* Wc2 = (const float*)d_in[26];
  const float* bc2 = (const float*)d_in[27];
  const int* edge_index = (const int*)d_in[28];
  const int* sidx = (const int*)d_in[29];
  float* out = (float*)d_out;

  // ----- static arena (phase-disjoint aliasing; ~107 MiB peak) -----
  const size_t MB = (size_t)1 << 20;
  const size_t KB = (size_t)1 << 10;
  char* ws = (char*)d_ws;
  unsigned short* xc_ch = (unsigned short*)(ws + 0);      // 12.6MB (mamba only)
  unsigned short* xc_cl = (unsigned short*)(ws + 16 * MB);// 12.6MB
  float* xw1 = (float*)(ws + 0);                          // 16MB
  float* g1 = (float*)(ws + 16 * MB);                     // 16MB
  unsigned short* g1h = (unsigned short*)(ws + 32 * MB);  // 8MB
  unsigned short* g1l = (unsigned short*)(ws + 40 * MB);  // 8MB
  unsigned short* xph = (unsigned short*)(ws + 48 * MB);  // 2MB
  unsigned short* xpl = (unsigned short*)(ws + 50 * MB);  // 2MB
  unsigned short* W1th = (unsigned short*)(ws + 52 * MB);            // 128KB
  unsigned short* W1tl = (unsigned short*)(ws + 52 * MB + 128 * KB); // 128KB
  float* xw2 = (float*)(ws + 48 * MB);                    // 16MB
  unsigned short* W2th = (unsigned short*)(ws + 0);               // 512KB (xw1 dead)
  unsigned short* W2tl = (unsigned short*)(ws + 512 * KB);        // 512KB
  float* g2 = (float*)(ws + 0);                           // 16MB
  unsigned short* featsh = (unsigned short*)(ws + 16 * MB);  // 24MB
  unsigned short* featsl = (unsigned short*)(ws + 40 * MB);  // 24MB
  float* hidden = (float*)(ws + 0);                       // 16MB (g2 dead after concat)
  float* xdb_c = (float*)(ws + 64 * MB);                  // 1.5MB (MC_CAP x 64)
  unsigned short* pooledh = (unsigned short*)(ws + 68 * MB);  // 4MB
  unsigned short* pooledl = (unsigned short*)(ws + 72 * MB);  // 4MB
  unsigned short* Wxth = (unsigned short*)(ws + 76 * MB);            // 128KB
  unsigned short* Wxtl = (unsigned short*)(ws + 76 * MB + 128 * KB); // 128KB
  float* WmixT = (float*)(ws + 77 * MB);                  // 2MB (512x1024 f32)
  unsigned short* Wmixth = (unsigned short*)(ws + 80 * MB);  // 1MB
  unsigned short* Wmixtl = (unsigned short*)(ws + 81 * MB);  // 1MB
  unsigned short* Wlth = (unsigned short*)(ws + 82 * MB);            // 512KB
  unsigned short* Wltl = (unsigned short*)(ws + 82 * MB + 512 * KB); // 512KB
  unsigned short* Woph = (unsigned short*)(ws + 83 * MB);            // 1MB
  unsigned short* Wopl = (unsigned short*)(ws + 84 * MB);            // 1MB
  float* negA = (float*)(ws + 85 * MB);                   // 64KB
  unsigned* leftU = (unsigned*)(ws + 64 * MB);            // 16MB (mamba dead)
  unsigned* rightU = (unsigned*)(ws + 80 * MB);           // 16MB
  float* x_point = (float*)(ws + 96 * MB);                // 4MB
  unsigned short* Wc1th = (unsigned short*)(ws + 96 * MB);             // 1.5MB (x_point dead)
  unsigned short* Wc1tl = (unsigned short*)(ws + 96 * MB + 1536 * KB); // 1.5MB
  unsigned short* Wc2th = (unsigned short*)(ws + 99 * MB);             // 32KB
  unsigned short* Wc2tl = (unsigned short*)(ws + 99 * MB + 64 * KB);   // 32KB
  char* sm = ws + 100 * MB;
  float* es1 = (float*)(sm + 0);                 // 256KB
  float* ed1 = (float*)(sm + 256 * KB);          // 256KB
  float* e1 = (float*)(sm + 512 * KB);           // 320KB
  float* denom1 = (float*)(sm + 1088 * KB);      // 256KB
  float* es2 = (float*)(sm + 1344 * KB);         // 32KB
  float* ed2 = (float*)(sm + 1376 * KB);         // 32KB
  float* e2 = (float*)(sm + 1408 * KB);          // 40KB
  float* denom2 = (float*)(sm + 1480 * KB);      // 32KB
  int* flagL = (int*)(sm + 1512 * KB);           // 32KB
  int* flagR = (int*)(sm + 1544 * KB);           // 32KB
  float* padded = (float*)(ws + 106 * MB);                   // 384KB
  int* counts = (int*)(ws + 106 * MB + 384 * KB);            // 8KB
  float* W_eff = (float*)(ws + 106 * MB + 400 * KB);         // 48KB
  float* b_eff = (float*)(ws + 106 * MB + 448 * KB);         // 8KB
  int* starts_c = (int*)(ws + 106 * MB + 456 * KB);          // 8KB

  auto g64 = [&](const float* A, int lda, const float* B, int ldb, float* C, int ldc,
                 int M, int N, int K, const float* bias, int act) {
    dim3 grid((N + 63) / 64, (M + 63) / 64);
    gemm_t<64, 64><<<grid, 256, 0, stream>>>(A, lda, B, ldb, C, ldc, M, N, K, bias, act);
  };
  auto gm2 = [&](const unsigned short* Ah, const unsigned short* Al,
                 const unsigned short* Bth, const unsigned short* Btl, float* C,
                 int M, int N, int K, const float* bias, int act) {
    gemm_mfma2<<<(N / 128) * (M / 128), 512, 0, stream>>>(Ah, Al, Bth, Btl, C, M, N, K, bias,
                                                          act);
  };
  auto tsplit = [&](const float* W, unsigned short* th, unsigned short* tl, int K, int N) {
    tsplit_kernel<<<(K * N + 255) / 256, 256, 0, stream>>>(W, th, tl, K, N);
  };
  auto split = [&](const float* x, unsigned short* h, unsigned short* l, int n) {
    split_kernel<<<(n + 255) / 256, 256, 0, stream>>>(x, h, l, n);
  };

  // ===== PRE: effective weights (one fused prep kernel + W_eff GEMMs) =====
  g64(W_in, DM, W_inproj, 2 * DI, W_eff, 2 * DI, 6, 2 * DI, DM, nullptr, 0);
  g64(b_in, DM, W_inproj, 2 * DI, b_eff, 2 * DI, 1, 2 * DI, DM, nullptr, 0);
  prep1_kernel<<<PREP_TOT / 256, 256, 0, stream>>>(
      W_lout, W_outproj, A_log, W_xproj, W1, x_param,
      Wlth, Wltl, Woph, Wopl, negA, Wxth, Wxtl, W1th, W1tl, xph, xpl);
  hipMemsetAsync(WmixT, 0, (size_t)DM * DI * 4, stream);
  gemm_mfma_sk<<<dim3(DI / 64, DM / 64, 4), 256, 0, stream>>>(Wlth, Wltl, Woph, Wopl, WmixT,
                                                              DM, DI, DM);
  split(WmixT, Wmixth, Wmixtl, DM * DI);

  // ===== Mamba encoder =====
  hipMemsetAsync(padded, 0, (size_t)ROWS * 6 * 4, stream);
  scatter_padded_kernel<<<(NSYN + 255) / 256, 256, 0, stream>>>(synapse, sidx, padded);
  prefix_kernel<<<1, 256, 0, stream>>>(sidx, counts, starts_c);
  xc_compact_kernel<<<dim3(DI / 256, E_EDGES), 256, 0, stream>>>(
      padded, W_eff, b_eff, conv_w, conv_b, counts, starts_c, xc_ch, xc_cl);
  hipMemsetAsync(xdb_c, 0, (size_t)MC_CAP * 64 * 4, stream);
  gemm_mfma_sk<<<dim3(1, MC_CAP / 64, 8), 256, 0, stream>>>(xc_ch, xc_cl, Wxth, Wxtl, xdb_c,
                                                            MC_CAP, 64, DI);
  mamba_scan_pool_kernel<<<dim3(DI / 256, E_EDGES), 256, 0, stream>>>(
      xdb_c, padded, W_eff, b_eff, W_dt, b_dt, negA, Dv, conv_w, conv_b, counts, starts_c,
      pooledh, pooledl);
  hipMemsetAsync(x_point, 0, (size_t)E_EDGES * DM * 4, stream);
  gemm_mfma_sk<<<dim3(DM / 64, E_EDGES / 64, 4), 256, 0, stream>>>(pooledh, pooledl, Wmixth,
                                                                   Wmixtl, x_point, E_EDGES,
                                                                   DM, DI);

  // ===== GAT layer 1 =====
  gm2(xph, xpl, W1th, W1tl, xw1, N_NODES, HEADS * HID, F_IN, nullptr, 0);
  esed1_kernel<<<(N_NODES * HEADS) / 256, 256, 0, stream>>>(xw1, as1, ad1, es1, ed1);
  hipMemsetAsync(denom1, 0, 256 * KB, stream);
  edgeexp1_kernel<<<(TOT_EDGES * HEADS + 255) / 256, 256, 0, stream>>>(edge_index, es1, ed1,
                                                                       e1, denom1);
  selfinit1_kernel<<<(N_NODES * 512) / 256, 256, 0, stream>>>(e1, denom1, xw1, g1);
  agg1_kernel<<<E_EDGES, 256, 0, stream>>>(edge_index, e1, denom1, xw1, g1);
  elu_bias_split_kernel<<<(N_NODES * 512) / 256, 256, 0, stream>>>(g1, b1, g1h, g1l);

  // ===== GAT layer 2 =====
  tsplit(W2, W2th, W2tl, HEADS * HID, REP);  // stays here: W2th aliases xw1 (dead after agg1)
  gm2(g1h, g1l, W2th, W2tl, xw2, N_NODES, REP, HEADS * HID, nullptr, 0);
  esed2_kernel<<<N_NODES, 64, 0, stream>>>(xw2, as2, ad2, es2, ed2);
  hipMemsetAsync(denom2, 0, 96 * KB, stream);  // denom2 + flagL + flagR
  edgeexp2_kernel<<<(TOT_EDGES + 255) / 256, 256, 0, stream>>>(edge_index, es2, ed2, e2,
                                                               denom2);
  selfinit2_kernel<<<(N_NODES * 512) / 256, 256, 0, stream>>>(e2, denom2, xw2, g2);
  agg2_kernel<<<E_EDGES, 256, 0, stream>>>(edge_index, e2, denom2, xw2, g2);

  // ===== left/right segment max =====
  hipMemsetAsync(leftU, 0, 32 * MB, stream);  // leftU + rightU (contiguous)
  leftright_kernel<<<E_EDGES, 256, 0, stream>>>(edge_index, x_point, b_lout, leftU, rightU,
                                                flagL, flagR);

  // ===== classifier =====
  concat_split_kernel<<<(N_NODES * 512) / 256, 256, 0, stream>>>(g2, b2, leftU, rightU, flagL,
                                                                 flagR, featsh, featsl);
  tsplit(Wc1, Wc1th, Wc1tl, REP + 2 * DM, 512);  // stays: aliases x_point (dead after leftright)
  tsplit(Wc2, Wc2th, Wc2tl, 512, NCLS);
  gm2(featsh, featsl, Wc1th, Wc1tl, hidden, N_NODES, 512, REP + 2 * DM, bc1, 1);
  gemm_thin32<0><<<N_NODES / 64, 256, 0, stream>>>(hidden, Wc2th, Wc2tl, out, N_NODES, bc2);
}